// Round 12
// baseline (221.953 us; speedup 1.0000x reference)
//
#include <hip/hip_runtime.h>
#include <math.h>

// Problem constants (match reference file)
#define NN 8000
#define EE 96000
#define HH 4
#define NBASIS 256
#define ECH 48
#define FFNH 128
#define CUTOFF_R 0.0792f
#define PI_F 3.14159265358979323846f
#define SPACING (CUTOFF_R/255.0f)
#define INV_STD (256.0f/CUTOFF_R)
#define MAXDEG 48

typedef __bf16 bf16x8 __attribute__((ext_vector_type(8)));
typedef __bf16 bf16x4 __attribute__((ext_vector_type(4)));
typedef __bf16 bf16x2 __attribute__((ext_vector_type(2)));
typedef float  f32x4  __attribute__((ext_vector_type(4)));

__device__ __forceinline__ float silu_f(float x){ return x/(1.0f+expf(-x)); }

// ---------- fused weights: wsv = W_src@W_v, wdv = W_dst@W_v, bf16 out (grid 32x256) ----------
__global__ void k_fusew(const float* __restrict__ Wsrc, const float* __restrict__ Wdst,
                        const float* __restrict__ Wv,
                        __bf16* __restrict__ wsv, __bf16* __restrict__ wdv){
  int gid = blockIdx.x*256 + threadIdx.x;
  int which = gid >> 12;
  int idx = gid & 4095;
  int r = idx >> 6, c = idx & 63;
  const float* A = which ? Wdst : Wsrc;
  float acc = 0.0f;
  #pragma unroll
  for (int k=0;k<64;k++) acc += A[r*64+k]*Wv[k*64+c];
  (which ? wdv : wsv)[idx] = (__bf16)acc;
}

// ---------- fused pre: rms + xs0/xd0 + vs/vd MFMA. 4 nodes/block, grid 2000x256 ----------
__global__ void __launch_bounds__(256) k_pre(const float* __restrict__ x,
                        const float* __restrict__ Wsrc, const float* __restrict__ Wdst,
                        const __bf16* __restrict__ wsv, const __bf16* __restrict__ wdv,
                        float* __restrict__ xs0, float* __restrict__ xd0,
                        __bf16* __restrict__ vs, __bf16* __restrict__ vd){
  __shared__ __bf16 xbuf[64*72];   // 4 nodes x 16 l rows, rms-scaled bf16
  __shared__ float  xl0[4][64];    // fp32 l=0 rows (unscaled)
  __shared__ __bf16 wsb[64*72];    // wsvT [c][k]
  __shared__ __bf16 wdb[64*72];
  __shared__ float  red[16];       // [wave][q]
  int tid = threadIdx.x;
  int w = tid>>6, l = tid&63, lr = l&15, lg = l>>4;
  int n0 = blockIdx.x*4;
  const float4* xp = (const float4*)(x + (size_t)n0*1024);

  float4 v[4]; float ssq[4];
  #pragma unroll
  for (int q=0;q<4;q++){
    v[q] = xp[tid + q*256];
    ssq[q] = v[q].x*v[q].x + v[q].y*v[q].y + v[q].z*v[q].z + v[q].w*v[q].w;
  }
  #pragma unroll
  for (int q=0;q<4;q++){
    #pragma unroll
    for (int m=32;m>=1;m>>=1) ssq[q] += __shfl_xor(ssq[q], m);
  }
  if (l==0){
    #pragma unroll
    for (int q=0;q<4;q++) red[w*4+q] = ssq[q];
  }
  for (int i=tid;i<4096;i+=256){
    int k=i>>6, c=i&63;
    wsb[c*72+k] = wsv[i];
    wdb[c*72+k] = wdv[i];
  }
  if (tid < 16){
    #pragma unroll
    for (int q=0;q<4;q++){
      float4 t = v[q];
      float* p = &xl0[q][(tid&15)*4];
      p[0]=t.x; p[1]=t.y; p[2]=t.z; p[3]=t.w;
    }
  }
  __syncthreads();
  float scl[4];
  #pragma unroll
  for (int q=0;q<4;q++)
    scl[q] = 1.0f/sqrtf((red[q]+red[4+q]+red[8+q]+red[12+q])*(1.0f/1024.0f)+1e-6f);
  {
    int r = tid>>4, k4 = (tid&15)*4;
    #pragma unroll
    for (int q=0;q<4;q++){
      float s = scl[q];
      bf16x4 t = {(__bf16)(v[q].x*s),(__bf16)(v[q].y*s),(__bf16)(v[q].z*s),(__bf16)(v[q].w*s)};
      *(bf16x4*)&xbuf[(q*16+r)*72 + k4] = t;
    }
  }
  __syncthreads();

  {
    int nd = w, c = l;
    float s = scl[nd];
    float as=0.f, ad=0.f;
    #pragma unroll 8
    for (int k=0;k<64;k++){
      float xv = xl0[nd][k]*s;
      as += xv*Wsrc[k*64+c];
      ad += xv*Wdst[k*64+c];
    }
    xs0[(size_t)(n0+nd)*64 + c] = as;
    xd0[(size_t)(n0+nd)*64 + c] = ad;
  }

  {
    bf16x8 a0 = *(const bf16x8*)&xbuf[(w*16+lr)*72 + lg*8];
    bf16x8 a1 = *(const bf16x8*)&xbuf[(w*16+lr)*72 + 32 + lg*8];
    #pragma unroll
    for (int nt=0;nt<4;nt++){
      f32x4 os = (f32x4){0.f,0.f,0.f,0.f};
      f32x4 od = (f32x4){0.f,0.f,0.f,0.f};
      bf16x8 bs0 = *(const bf16x8*)&wsb[(nt*16+lr)*72 + lg*8];
      bf16x8 bs1 = *(const bf16x8*)&wsb[(nt*16+lr)*72 + 32 + lg*8];
      bf16x8 bd0 = *(const bf16x8*)&wdb[(nt*16+lr)*72 + lg*8];
      bf16x8 bd1 = *(const bf16x8*)&wdb[(nt*16+lr)*72 + 32 + lg*8];
      os = __builtin_amdgcn_mfma_f32_16x16x32_bf16(a0, bs0, os, 0, 0, 0);
      os = __builtin_amdgcn_mfma_f32_16x16x32_bf16(a1, bs1, os, 0, 0, 0);
      od = __builtin_amdgcn_mfma_f32_16x16x32_bf16(a0, bd0, od, 0, 0, 0);
      od = __builtin_amdgcn_mfma_f32_16x16x32_bf16(a1, bd1, od, 0, 0, 0);
      #pragma unroll
      for (int r=0;r<4;r++){
        size_t row = (size_t)(n0+w)*16 + lg*4 + r;
        vs[row*64 + nt*16 + lr] = (__bf16)os[r];
        vd[row*64 + nt*16 + lr] = (__bf16)od[r];
      }
    }
  }
}

// ---------- edge RBF + 2-layer MLP via MFMA: 64 edges/block, grid 1500x256 ----------
__global__ void __launch_bounds__(256) k_edgeA(const float* __restrict__ pos, const int* __restrict__ ei,
                        const float* __restrict__ W1, const float* __restrict__ b1,
                        const float* __restrict__ W2, const float* __restrict__ b2,
                        __bf16* __restrict__ e2g){
  __shared__ __bf16 W1T[48*264];   // [j][k] stride 264
  __shared__ __bf16 W2T[64*72];    // [j][k] stride 72 (k>=48 zero)
  __shared__ __bf16 e1s[64*72];    // [edge][k] stride 72 (k>=48 zeroed)
  __shared__ float dl[64], envl[64];
  int tid = threadIdx.x;
  int w = tid>>6, l = tid&63, lr = l&15, lg = l>>4;
  int eb = blockIdx.x*64;

  if (tid < 64){
    int s = ei[eb+tid], t = ei[EE+eb+tid];
    float dx = pos[3*s]-pos[3*t], dy = pos[3*s+1]-pos[3*t+1], dz = pos[3*s+2]-pos[3*t+2];
    float d = sqrtf(dx*dx+dy*dy+dz*dz+1e-12f);
    dl[tid] = d;
    envl[tid] = 0.5f*(cosf(PI_F*fminf(d*(1.0f/CUTOFF_R),1.0f))+1.0f);
  }
  for (int i=tid;i<48*128;i+=256){
    int kp = i/48, j = i - kp*48;
    bf16x2 p = {(__bf16)W1[(size_t)(2*kp)*48 + j], (__bf16)W1[(size_t)(2*kp+1)*48 + j]};
    *(bf16x2*)&W1T[j*264 + 2*kp] = p;
  }
  for (int i=tid;i<4096;i+=256){
    int k=i>>6, j=i&63;
    W2T[j*72+k] = (j<ECH && k<ECH) ? (__bf16)W2[(size_t)k*ECH+j] : (__bf16)0.f;
  }
  for (int i=tid;i<1024;i+=256){
    int r=i>>4, c=48+(i&15);
    e1s[r*72+c] = (__bf16)0.f;
  }
  __syncthreads();

  float d  = dl[w*16+lr];
  float ev = envl[w*16+lr];
  f32x4 acc[3];
  #pragma unroll
  for (int nt=0;nt<3;nt++) acc[nt] = (f32x4){0.f,0.f,0.f,0.f};
  #pragma unroll
  for (int c=0;c<8;c++){
    bf16x8 af;
    #pragma unroll
    for (int j=0;j<8;j++){
      float kk = (float)(c*32 + lg*8 + j);
      float del = (d - kk*SPACING)*INV_STD;
      af[j] = (__bf16)(exp2f(-0.72134752f*del*del)*ev);
    }
    #pragma unroll
    for (int nt=0;nt<3;nt++){
      bf16x8 bf_ = *(const bf16x8*)&W1T[(nt*16+lr)*264 + c*32 + lg*8];
      acc[nt] = __builtin_amdgcn_mfma_f32_16x16x32_bf16(af, bf_, acc[nt], 0, 0, 0);
    }
  }
  #pragma unroll
  for (int nt=0;nt<3;nt++){
    int col = nt*16+lr;
    float bb = b1[col];
    #pragma unroll
    for (int r=0;r<4;r++){
      int row = w*16 + lg*4 + r;
      e1s[row*72+col] = (__bf16)silu_f(acc[nt][r] + bb);
    }
  }
  __syncthreads();

  bf16x8 a0 = *(const bf16x8*)&e1s[(w*16+lr)*72 + lg*8];
  bf16x8 a1 = *(const bf16x8*)&e1s[(w*16+lr)*72 + 32 + lg*8];
  #pragma unroll
  for (int nt=0;nt<3;nt++){
    f32x4 o = (f32x4){0.f,0.f,0.f,0.f};
    bf16x8 b0 = *(const bf16x8*)&W2T[(nt*16+lr)*72 + lg*8];
    bf16x8 b1f= *(const bf16x8*)&W2T[(nt*16+lr)*72 + 32 + lg*8];
    o = __builtin_amdgcn_mfma_f32_16x16x32_bf16(a0, b0, o, 0, 0, 0);
    o = __builtin_amdgcn_mfma_f32_16x16x32_bf16(a1, b1f, o, 0, 0, 0);
    int col = nt*16+lr;
    float bb = b2[col];
    #pragma unroll
    for (int r=0;r<4;r++){
      int row = w*16 + lg*4 + r;
      e2g[(size_t)(eb+row)*ECH + col] = (__bf16)silu_f(o[r] + bb);
    }
  }
}

// ---------- CSR build ----------
__global__ void k_hist(const int* __restrict__ ei, int* __restrict__ deg){
  int e = blockIdx.x*256 + threadIdx.x;
  atomicAdd(&deg[ei[EE+e]], 1);
}

__global__ void __launch_bounds__(1024) k_scan(const int* __restrict__ deg, int* __restrict__ off){
  __shared__ int sums[1024];
  int t = threadIdx.x;
  int base = t*8;
  int loc[8]; int s=0;
  #pragma unroll
  for (int i=0;i<8;i++){ int idx=base+i; int v = (idx<NN)? deg[idx]:0; loc[i]=v; s+=v; }
  sums[t]=s;
  __syncthreads();
  for (int d=1; d<1024; d<<=1){
    int v = (t>=d)? sums[t-d]:0;
    __syncthreads();
    sums[t] += v;
    __syncthreads();
  }
  int run = sums[t]-s;
  #pragma unroll
  for (int i=0;i<8;i++){ int idx=base+i; if (idx<NN) off[idx]=run; run+=loc[i]; }
  if (t==1023) off[NN]=sums[1023];
}

__global__ void k_fill(const int* __restrict__ ei, const int* __restrict__ off,
                       int* __restrict__ cursor, int* __restrict__ csr){
  int e = blockIdx.x*256 + threadIdx.x;
  int d = ei[EE+e];
  int slot = off[d] + atomicAdd(&cursor[d],1);
  csr[slot]=e;
}

// ---------- per-edge MFMA: s0 = (e2@We)*(xs0[s]+xd0[d]); logits = lrelu(s0@Wa)·va; v0 = s0@Wv
// 64 edges/block, 4 waves. grid 1500x256
__global__ void __launch_bounds__(256) k_edgeB(const __bf16* __restrict__ e2g, const int* __restrict__ ei,
                        const float* __restrict__ xs0, const float* __restrict__ xd0,
                        const float* __restrict__ W_edge, const float* __restrict__ W_alpha,
                        const float* __restrict__ v_alpha, const float* __restrict__ Wv,
                        float* __restrict__ logits_g, __bf16* __restrict__ v0g){
  __shared__ __bf16 e2s[64*72];
  __shared__ __bf16 s0s[64*72];
  __shared__ __bf16 wbuf[128*72];
  __shared__ float  va_l[256];
  __shared__ int    srcd[128];
  int tid = threadIdx.x;
  int w = tid >> 6, l = tid & 63;
  int lr = l & 15, lg = l >> 4;
  int eb = blockIdx.x * 64;

  for (int i=tid;i<4096;i+=256){
    int r=i>>6, k=i&63;
    e2s[r*72+k] = (k<ECH) ? e2g[(size_t)(eb+r)*ECH+k] : (__bf16)0.f;
  }
  for (int i=tid;i<4096;i+=256){
    int k=i>>6, c=i&63;
    wbuf[c*72+k] = (k<ECH) ? (__bf16)W_edge[(size_t)k*64+c] : (__bf16)0.f;
  }
  va_l[tid] = v_alpha[tid];
  if (tid<64){ srcd[tid]=ei[eb+tid]; srcd[64+tid]=ei[EE+eb+tid]; }
  __syncthreads();

  bf16x8 ea0 = *(const bf16x8*)&e2s[(w*16+lr)*72 + lg*8];
  bf16x8 ea1 = *(const bf16x8*)&e2s[(w*16+lr)*72 + 32 + lg*8];
  f32x4 sacc[4];
  #pragma unroll
  for (int nt=0;nt<4;nt++){
    sacc[nt] = (f32x4){0.f,0.f,0.f,0.f};
    bf16x8 b0 = *(const bf16x8*)&wbuf[(nt*16+lr)*72 + lg*8];
    bf16x8 b1 = *(const bf16x8*)&wbuf[(nt*16+lr)*72 + 32 + lg*8];
    sacc[nt] = __builtin_amdgcn_mfma_f32_16x16x32_bf16(ea0, b0, sacc[nt], 0, 0, 0);
    sacc[nt] = __builtin_amdgcn_mfma_f32_16x16x32_bf16(ea1, b1, sacc[nt], 0, 0, 0);
  }
  #pragma unroll
  for (int reg=0;reg<4;reg++){
    int localrow = w*16 + lg*4 + reg;
    int sI = srcd[localrow], dI = srcd[64+localrow];
    #pragma unroll
    for (int nt=0;nt<4;nt++){
      int col = nt*16 + lr;
      float m = xs0[(size_t)sI*64+col] + xd0[(size_t)dI*64+col];
      s0s[localrow*72+col] = (__bf16)(sacc[nt][reg]*m);
    }
  }
  __syncthreads();

  bf16x8 sa0 = *(const bf16x8*)&s0s[(w*16+lr)*72 + lg*8];
  bf16x8 sa1 = *(const bf16x8*)&s0s[(w*16+lr)*72 + 32 + lg*8];

  #pragma unroll
  for (int half=0;half<2;half++){
    for (int i=tid;i<8192;i+=256){
      int k=i>>7, j=i&127;
      wbuf[j*72+k] = (__bf16)W_alpha[(size_t)k*256 + half*128 + j];
    }
    __syncthreads();
    float lg0[4]={0.f,0.f,0.f,0.f}, lg1[4]={0.f,0.f,0.f,0.f};
    #pragma unroll
    for (int nt=0;nt<8;nt++){
      f32x4 tacc = (f32x4){0.f,0.f,0.f,0.f};
      bf16x8 b0 = *(const bf16x8*)&wbuf[(nt*16+lr)*72 + lg*8];
      bf16x8 b1 = *(const bf16x8*)&wbuf[(nt*16+lr)*72 + 32 + lg*8];
      tacc = __builtin_amdgcn_mfma_f32_16x16x32_bf16(sa0, b0, tacc, 0, 0, 0);
      tacc = __builtin_amdgcn_mfma_f32_16x16x32_bf16(sa1, b1, tacc, 0, 0, 0);
      int gj = half*128 + nt*16 + lr;
      float vaj = va_l[gj];
      #pragma unroll
      for (int reg=0;reg<4;reg++){
        float t = tacc[reg];
        t = (t>0.0f) ? t : 0.2f*t;
        if (nt<4) lg0[reg] += t*vaj; else lg1[reg] += t*vaj;
      }
    }
    #pragma unroll
    for (int reg=0;reg<4;reg++){
      #pragma unroll
      for (int m=1;m<16;m<<=1){
        lg0[reg] += __shfl_xor(lg0[reg], m);
        lg1[reg] += __shfl_xor(lg1[reg], m);
      }
    }
    if (lr==0){
      #pragma unroll
      for (int reg=0;reg<4;reg++){
        int e = eb + w*16 + lg*4 + reg;
        logits_g[(size_t)e*4 + half*2 + 0] = lg0[reg];
        logits_g[(size_t)e*4 + half*2 + 1] = lg1[reg];
      }
    }
    __syncthreads();
  }

  for (int i=tid;i<4096;i+=256){
    int k=i>>6, c=i&63;
    wbuf[c*72+k] = (__bf16)Wv[(size_t)k*64+c];
  }
  __syncthreads();
  #pragma unroll
  for (int nt=0;nt<4;nt++){
    f32x4 vacc = (f32x4){0.f,0.f,0.f,0.f};
    bf16x8 b0 = *(const bf16x8*)&wbuf[(nt*16+lr)*72 + lg*8];
    bf16x8 b1 = *(const bf16x8*)&wbuf[(nt*16+lr)*72 + 32 + lg*8];
    vacc = __builtin_amdgcn_mfma_f32_16x16x32_bf16(sa0, b0, vacc, 0, 0, 0);
    vacc = __builtin_amdgcn_mfma_f32_16x16x32_bf16(sa1, b1, vacc, 0, 0, 0);
    #pragma unroll
    for (int reg=0;reg<4;reg++){
      int e = eb + w*16 + lg*4 + reg;
      v0g[(size_t)e*64 + nt*16 + lr] = (__bf16)vacc[reg];
    }
  }
}

// ---------- gather-only: softmax + bf16 gather -> agg (1 node/block, grid 8000) ----------
__global__ void __launch_bounds__(256) k_gather(const int* __restrict__ off, const int* __restrict__ csr,
                       const int* __restrict__ ei,
                       const float* __restrict__ logits_g, const __bf16* __restrict__ v0g,
                       const __bf16* __restrict__ vs, const __bf16* __restrict__ vd,
                       __bf16* __restrict__ agg){
  __shared__ float alph[MAXDEG*HH];
  __shared__ int   eidl[MAXDEG];
  __shared__ int   srcl[MAXDEG];
  __shared__ float salpha[HH];
  int tid = threadIdx.x;
  int n = blockIdx.x;
  int o0 = off[n];
  int deg = off[n+1]-o0;
  if (deg > MAXDEG) deg = MAXDEG;
  if (tid < deg){
    int e = csr[o0+tid];
    eidl[tid]=e;
    srcl[tid]=ei[e];
    float4 lgv = *(const float4*)(logits_g + (size_t)e*4);
    float* ap = &alph[tid*4];
    ap[0]=lgv.x; ap[1]=lgv.y; ap[2]=lgv.z; ap[3]=lgv.w;
  }
  __syncthreads();
  if (tid < 64){
    int h = tid>>4, i0 = tid&15;
    float m = -1e30f;
    for (int i=i0;i<deg;i+=16) m = fmaxf(m, alph[i*4+h]);
    #pragma unroll
    for (int s=1;s<16;s<<=1) m = fmaxf(m, __shfl_xor(m, s));
    float ds = 0.0f;
    for (int i=i0;i<deg;i+=16){
      float wv = expf(alph[i*4+h]-m);
      alph[i*4+h]=wv; ds += wv;
    }
    #pragma unroll
    for (int s=1;s<16;s<<=1) ds += __shfl_xor(ds, s);
    float inv = 1.0f/(ds+1e-9f);
    for (int i=i0;i<deg;i+=16) alph[i*4+h] *= inv;
    if (i0==0) salpha[h] = ds*inv;
  }
  __syncthreads();
  {
    int l = tid>>4, quad = tid&15;
    int h = quad>>2;
    float a0=0.f,a1=0.f,a2=0.f,a3=0.f;
    if (l==0){
      int i=0;
      for (;i+1<deg;i+=2){
        float aA = alph[i*4+h], aB = alph[(i+1)*4+h];
        bf16x4 vA = *(const bf16x4*)(v0g + (size_t)eidl[i]*64 + quad*4);
        bf16x4 vB = *(const bf16x4*)(v0g + (size_t)eidl[i+1]*64 + quad*4);
        a0 += aA*(float)vA[0] + aB*(float)vB[0];
        a1 += aA*(float)vA[1] + aB*(float)vB[1];
        a2 += aA*(float)vA[2] + aB*(float)vB[2];
        a3 += aA*(float)vA[3] + aB*(float)vB[3];
      }
      if (i<deg){
        float a = alph[i*4+h];
        bf16x4 vv = *(const bf16x4*)(v0g + (size_t)eidl[i]*64 + quad*4);
        a0 += a*(float)vv[0]; a1 += a*(float)vv[1]; a2 += a*(float)vv[2]; a3 += a*(float)vv[3];
      }
    } else {
      int i=0;
      for (;i+1<deg;i+=2){
        float aA = alph[i*4+h], aB = alph[(i+1)*4+h];
        bf16x4 vA = *(const bf16x4*)(vs + (size_t)srcl[i]*1024 + tid*4);
        bf16x4 vB = *(const bf16x4*)(vs + (size_t)srcl[i+1]*1024 + tid*4);
        a0 += aA*(float)vA[0] + aB*(float)vB[0];
        a1 += aA*(float)vA[1] + aB*(float)vB[1];
        a2 += aA*(float)vA[2] + aB*(float)vB[2];
        a3 += aA*(float)vA[3] + aB*(float)vB[3];
      }
      if (i<deg){
        float a = alph[i*4+h];
        bf16x4 vv = *(const bf16x4*)(vs + (size_t)srcl[i]*1024 + tid*4);
        a0 += a*(float)vv[0]; a1 += a*(float)vv[1]; a2 += a*(float)vv[2]; a3 += a*(float)vv[3];
      }
      float sa = salpha[h];
      bf16x4 vv = *(const bf16x4*)(vd + (size_t)n*1024 + tid*4);
      a0 += sa*(float)vv[0]; a1 += sa*(float)vv[1]; a2 += sa*(float)vv[2]; a3 += sa*(float)vv[3];
    }
    bf16x4 t = {(__bf16)a0,(__bf16)a1,(__bf16)a2,(__bf16)a3};
    *(bf16x4*)(agg + (size_t)n*1024 + tid*4) = t;
  }
}

// ---------- Wo + residual + rms + gated FFN + out (4 nodes/block, grid 2000) ----------
// single staging pass, 5 barriers (round-6 k_ffn structure + Wo prologue). LDS ~73.7KB.
__global__ void __launch_bounds__(256) k_woffn(const __bf16* __restrict__ agg,
                       const float* __restrict__ x, const float* __restrict__ Wo,
                       const float* __restrict__ Wg, const float* __restrict__ Wh,
                       const float* __restrict__ Wf, float* __restrict__ out){
  __shared__ __bf16 WoT[64*72];     // 9216B  [c][k]
  __shared__ __bf16 WhT[128*72];    // 18432B [n][k]
  __shared__ __bf16 WfT[64*136];    // 17408B [n][k]
  __shared__ __bf16 aggyb[64*72];   // 9216B: agg -> ybuf
  __shared__ __bf16 Hbuf[64*136];   // 17408B
  __shared__ float  gl[512];        // 2048B
  int tid = threadIdx.x;
  int w = tid>>6, lane = tid&63, lr = lane&15, lg = lane>>4;
  int n0 = blockIdx.x*4;

  // ---- phase 1: stage ALL weights (paired-k b32 writes) + agg tile ----
  for (int i=tid;i<2048;i+=256){
    int kp=i>>6, c=i&63;
    bf16x2 p = {(__bf16)Wo[(size_t)(2*kp)*64 + c], (__bf16)Wo[(size_t)(2*kp+1)*64 + c]};
    *(bf16x2*)&WoT[c*72 + 2*kp] = p;
  }
  for (int i=tid;i<4096;i+=256){
    int kp=i>>7, nn=i&127;
    bf16x2 p = {(__bf16)Wh[(size_t)(2*kp)*128 + nn], (__bf16)Wh[(size_t)(2*kp+1)*128 + nn]};
    *(bf16x2*)&WhT[nn*72 + 2*kp] = p;
  }
  for (int i=tid;i<4096;i+=256){
    int kp=i>>6, j=i&63;
    bf16x2 p = {(__bf16)Wf[(size_t)(2*kp)*64 + j], (__bf16)Wf[(size_t)(2*kp+1)*64 + j]};
    *(bf16x2*)&WfT[j*136 + 2*kp] = p;
  }
  for (int i=tid;i<512;i+=256){
    bf16x8 v = *(const bf16x8*)(agg + (size_t)n0*1024 + i*8);
    *(bf16x8*)&aggyb[(i>>3)*72 + (i&7)*8] = v;
  }
  __syncthreads();

  // ---- phase 2: x1 = x + agg@Wo (regs), wave w = node w; rms (wave-local) ----
  f32x4 x1r[4];
  float scl_w;
  {
    bf16x8 a0 = *(const bf16x8*)&aggyb[(w*16+lr)*72 + lg*8];
    bf16x8 a1 = *(const bf16x8*)&aggyb[(w*16+lr)*72 + 32 + lg*8];
    const float* xr = x + (size_t)(n0+w)*1024;
    float ss = 0.0f;
    #pragma unroll
    for (int nt=0;nt<4;nt++){
      f32x4 o = (f32x4){0.f,0.f,0.f,0.f};
      bf16x8 b0 = *(const bf16x8*)&WoT[(nt*16+lr)*72 + lg*8];
      bf16x8 b1 = *(const bf16x8*)&WoT[(nt*16+lr)*72 + 32 + lg*8];
      o = __builtin_amdgcn_mfma_f32_16x16x32_bf16(a0, b0, o, 0, 0, 0);
      o = __builtin_amdgcn_mfma_f32_16x16x32_bf16(a1, b1, o, 0, 0, 0);
      #pragma unroll
      for (int r=0;r<4;r++){
        float xv = xr[(lg*4+r)*64 + nt*16 + lr] + o[r];
        o[r] = xv;
        ss += xv*xv;
      }
      x1r[nt] = o;
    }
    #pragma unroll
    for (int m=32;m>=1;m>>=1) ss += __shfl_xor(ss, m);
    scl_w = 1.0f/sqrtf(ss*(1.0f/1024.0f)+1e-6f);
  }
  __syncthreads();   // aggyb (agg) fully consumed

  // ---- phase 3: ybuf = bf16(x1*scl) into aggyb ----
  #pragma unroll
  for (int nt=0;nt<4;nt++){
    #pragma unroll
    for (int r=0;r<4;r++){
      aggyb[(w*16+lg*4+r)*72 + nt*16+lr] = (__bf16)(x1r[nt][r]*scl_w);
    }
  }
  __syncthreads();

  // ---- phase 3b: gate ----
  {
    int c = tid&127, half = tid>>7;
    #pragma unroll
    for (int q=0;q<2;q++){
      int nd = half*2+q;
      float acc = 0.0f;
      #pragma unroll 8
      for (int k=0;k<64;k++) acc += (float)aggyb[(nd*16)*72 + k] * Wg[k*128+c];
      gl[nd*128+c] = silu_f(acc);
    }
  }
  __syncthreads();

  // ---- phase 4: H[64,128] = y @ Wh, gated -> Hbuf ----
  {
    bf16x8 a0 = *(const bf16x8*)&aggyb[(w*16+lr)*72 + lg*8];
    bf16x8 a1 = *(const bf16x8*)&aggyb[(w*16+lr)*72 + 32 + lg*8];
    #pragma unroll
    for (int nt=0;nt<8;nt++){
      f32x4 o = (f32x4){0.f,0.f,0.f,0.f};
      bf16x8 b0 = *(const bf16x8*)&WhT[(nt*16+lr)*72 + lg*8];
      bf16x8 b1 = *(const bf16x8*)&WhT[(nt*16+lr)*72 + 32 + lg*8];
      o = __builtin_amdgcn_mfma_f32_16x16x32_bf16(a0, b0, o, 0, 0, 0);
      o = __builtin_amdgcn_mfma_f32_16x16x32_bf16(a1, b1, o, 0, 0, 0);
      int col = nt*16+lr;
      float g = gl[w*128+col];
      #pragma unroll
      for (int r=0;r<4;r++){
        Hbuf[(w*16+lg*4+r)*136 + col] = (__bf16)(o[r]*g);
      }
    }
  }
  __syncthreads();

  // ---- phase 5: out = x1 + H@Wf (K=128) ----
  {
    f32x4 o2[4];
    #pragma unroll
    for (int nt=0;nt<4;nt++) o2[nt] = (f32x4){0.f,0.f,0.f,0.f};
    #pragma unroll
    for (int kc=0;kc<4;kc++){
      bf16x8 a = *(const bf16x8*)&Hbuf[(w*16+lr)*136 + kc*32 + lg*8];
      #pragma unroll
      for (int nt=0;nt<4;nt++){
        bf16x8 b = *(const bf16x8*)&WfT[(nt*16+lr)*136 + kc*32 + lg*8];
        o2[nt] = __builtin_amdgcn_mfma_f32_16x16x32_bf16(a, b, o2[nt], 0, 0, 0);
      }
    }
    float* outr = out + (size_t)(n0+w)*1024;
    #pragma unroll
    for (int nt=0;nt<4;nt++){
      #pragma unroll
      for (int r=0;r<4;r++){
        outr[(lg*4+r)*64 + nt*16+lr] = x1r[nt][r] + o2[nt][r];
      }
    }
  }
}

extern "C" void kernel_launch(void* const* d_in, const int* in_sizes, int n_in,
                              void* d_out, int out_size, void* d_ws, size_t ws_size,
                              hipStream_t stream) {
  (void)in_sizes; (void)n_in; (void)out_size; (void)ws_size;
  const float* pos = (const float*)d_in[0];
  const float* x   = (const float*)d_in[1];
  const float* Wsrc= (const float*)d_in[2];
  const float* Wdst= (const float*)d_in[3];
  const float* W1  = (const float*)d_in[4];
  const float* b1  = (const float*)d_in[5];
  const float* W2  = (const float*)d_in[6];
  const float* b2  = (const float*)d_in[7];
  const float* We  = (const float*)d_in[8];
  const float* Wa  = (const float*)d_in[9];
  const float* va  = (const float*)d_in[10];
  const float* Wv  = (const float*)d_in[11];
  const float* Wo  = (const float*)d_in[12];
  const float* Wg  = (const float*)d_in[13];
  const float* Wh  = (const float*)d_in[14];
  const float* Wf  = (const float*)d_in[15];
  const int*   ei  = (const int*)d_in[16];
  float* out = (float*)d_out;

  char* wp = (char*)d_ws;
  auto alloc = [&](size_t bytes)->char*{
    char* p = wp;
    wp += ((bytes + 255)/256)*256;
    return p;
  };
  __bf16* wsv = (__bf16*)alloc(4096*2);
  __bf16* wdv = (__bf16*)alloc(4096*2);
  float* xs0  = (float*)alloc((size_t)NN*64*4);
  float* xd0  = (float*)alloc((size_t)NN*64*4);
  __bf16* vs  = (__bf16*)alloc((size_t)NN*1024*2);
  __bf16* vd  = (__bf16*)alloc((size_t)NN*1024*2);
  __bf16* agg = (__bf16*)alloc((size_t)NN*1024*2);
  __bf16* e2g = (__bf16*)alloc((size_t)EE*ECH*2);
  __bf16* v0g = (__bf16*)alloc((size_t)EE*64*2);
  float* lgts = (float*)alloc((size_t)EE*HH*4);
  int* deg    = (int*)alloc((size_t)NN*4);
  int* cursor = (int*)alloc((size_t)NN*4);
  int* off    = (int*)alloc((size_t)(NN+1)*4);
  int* csr    = (int*)alloc((size_t)EE*4);

  hipMemsetAsync(deg, 0, NN*sizeof(int), stream);
  hipMemsetAsync(cursor, 0, NN*sizeof(int), stream);

  k_fusew<<<32,256,0,stream>>>(Wsrc,Wdst,Wv,wsv,wdv);
  k_pre<<<NN/4,256,0,stream>>>(x,Wsrc,Wdst,wsv,wdv,xs0,xd0,vs,vd);
  k_edgeA<<<EE/64,256,0,stream>>>(pos,ei,W1,b1,W2,b2,e2g);
  k_hist<<<EE/256,256,0,stream>>>(ei,deg);
  k_scan<<<1,1024,0,stream>>>(deg,off);
  k_fill<<<EE/256,256,0,stream>>>(ei,off,cursor,csr);
  k_edgeB<<<EE/64,256,0,stream>>>(e2g,ei,xs0,xd0,We,Wa,va,Wv,lgts,v0g);
  k_gather<<<NN,256,0,stream>>>(off,csr,ei,lgts,v0g,vs,vd,agg);
  k_woffn<<<NN/4,256,0,stream>>>(agg,x,Wo,Wg,Wh,Wf,out);
}

// Round 13
// 201.346 us; speedup vs baseline: 1.1023x; 1.1023x over previous
//
#include <hip/hip_runtime.h>
#include <math.h>

// Problem constants (match reference file)
#define NN 8000
#define EE 96000
#define HH 4
#define NBASIS 256
#define ECH 48
#define FFNH 128
#define CUTOFF_R 0.0792f
#define PI_F 3.14159265358979323846f
#define SPACING (CUTOFF_R/255.0f)
#define INV_STD (256.0f/CUTOFF_R)
#define MAXDEG 48

typedef __bf16 bf16x8 __attribute__((ext_vector_type(8)));
typedef __bf16 bf16x4 __attribute__((ext_vector_type(4)));
typedef __bf16 bf16x2 __attribute__((ext_vector_type(2)));
typedef float  f32x4  __attribute__((ext_vector_type(4)));

__device__ __forceinline__ float silu_f(float x){ return x/(1.0f+expf(-x)); }

// ---------- fused weights: wsv = W_src@W_v, wdv = W_dst@W_v, bf16 out (grid 32x256) ----------
__global__ void k_fusew(const float* __restrict__ Wsrc, const float* __restrict__ Wdst,
                        const float* __restrict__ Wv,
                        __bf16* __restrict__ wsv, __bf16* __restrict__ wdv){
  int gid = blockIdx.x*256 + threadIdx.x;
  int which = gid >> 12;
  int idx = gid & 4095;
  int r = idx >> 6, c = idx & 63;
  const float* A = which ? Wdst : Wsrc;
  float acc = 0.0f;
  #pragma unroll
  for (int k=0;k<64;k++) acc += A[r*64+k]*Wv[k*64+c];
  (which ? wdv : wsv)[idx] = (__bf16)acc;
}

// ---------- fused pre: rms + xs0/xd0 + vs/vd MFMA. 4 nodes/block, grid 2000x256 ----------
__global__ void __launch_bounds__(256) k_pre(const float* __restrict__ x,
                        const float* __restrict__ Wsrc, const float* __restrict__ Wdst,
                        const __bf16* __restrict__ wsv, const __bf16* __restrict__ wdv,
                        float* __restrict__ xs0, float* __restrict__ xd0,
                        __bf16* __restrict__ vs, __bf16* __restrict__ vd){
  __shared__ __bf16 xbuf[64*72];   // 4 nodes x 16 l rows, rms-scaled bf16
  __shared__ float  xl0[4][64];    // fp32 l=0 rows (unscaled)
  __shared__ __bf16 wsb[64*72];    // wsvT [c][k]
  __shared__ __bf16 wdb[64*72];
  __shared__ float  red[16];       // [wave][q]
  int tid = threadIdx.x;
  int w = tid>>6, l = tid&63, lr = l&15, lg = l>>4;
  int n0 = blockIdx.x*4;
  const float4* xp = (const float4*)(x + (size_t)n0*1024);

  float4 v[4]; float ssq[4];
  #pragma unroll
  for (int q=0;q<4;q++){
    v[q] = xp[tid + q*256];
    ssq[q] = v[q].x*v[q].x + v[q].y*v[q].y + v[q].z*v[q].z + v[q].w*v[q].w;
  }
  #pragma unroll
  for (int q=0;q<4;q++){
    #pragma unroll
    for (int m=32;m>=1;m>>=1) ssq[q] += __shfl_xor(ssq[q], m);
  }
  if (l==0){
    #pragma unroll
    for (int q=0;q<4;q++) red[w*4+q] = ssq[q];
  }
  for (int i=tid;i<4096;i+=256){
    int k=i>>6, c=i&63;
    wsb[c*72+k] = wsv[i];
    wdb[c*72+k] = wdv[i];
  }
  if (tid < 16){
    #pragma unroll
    for (int q=0;q<4;q++){
      float4 t = v[q];
      float* p = &xl0[q][(tid&15)*4];
      p[0]=t.x; p[1]=t.y; p[2]=t.z; p[3]=t.w;
    }
  }
  __syncthreads();
  float scl[4];
  #pragma unroll
  for (int q=0;q<4;q++)
    scl[q] = 1.0f/sqrtf((red[q]+red[4+q]+red[8+q]+red[12+q])*(1.0f/1024.0f)+1e-6f);
  {
    int r = tid>>4, k4 = (tid&15)*4;
    #pragma unroll
    for (int q=0;q<4;q++){
      float s = scl[q];
      bf16x4 t = {(__bf16)(v[q].x*s),(__bf16)(v[q].y*s),(__bf16)(v[q].z*s),(__bf16)(v[q].w*s)};
      *(bf16x4*)&xbuf[(q*16+r)*72 + k4] = t;
    }
  }
  __syncthreads();

  {
    int nd = w, c = l;
    float s = scl[nd];
    float as=0.f, ad=0.f;
    #pragma unroll 8
    for (int k=0;k<64;k++){
      float xv = xl0[nd][k]*s;
      as += xv*Wsrc[k*64+c];
      ad += xv*Wdst[k*64+c];
    }
    xs0[(size_t)(n0+nd)*64 + c] = as;
    xd0[(size_t)(n0+nd)*64 + c] = ad;
  }

  {
    bf16x8 a0 = *(const bf16x8*)&xbuf[(w*16+lr)*72 + lg*8];
    bf16x8 a1 = *(const bf16x8*)&xbuf[(w*16+lr)*72 + 32 + lg*8];
    #pragma unroll
    for (int nt=0;nt<4;nt++){
      f32x4 os = (f32x4){0.f,0.f,0.f,0.f};
      f32x4 od = (f32x4){0.f,0.f,0.f,0.f};
      bf16x8 bs0 = *(const bf16x8*)&wsb[(nt*16+lr)*72 + lg*8];
      bf16x8 bs1 = *(const bf16x8*)&wsb[(nt*16+lr)*72 + 32 + lg*8];
      bf16x8 bd0 = *(const bf16x8*)&wdb[(nt*16+lr)*72 + lg*8];
      bf16x8 bd1 = *(const bf16x8*)&wdb[(nt*16+lr)*72 + 32 + lg*8];
      os = __builtin_amdgcn_mfma_f32_16x16x32_bf16(a0, bs0, os, 0, 0, 0);
      os = __builtin_amdgcn_mfma_f32_16x16x32_bf16(a1, bs1, os, 0, 0, 0);
      od = __builtin_amdgcn_mfma_f32_16x16x32_bf16(a0, bd0, od, 0, 0, 0);
      od = __builtin_amdgcn_mfma_f32_16x16x32_bf16(a1, bd1, od, 0, 0, 0);
      #pragma unroll
      for (int r=0;r<4;r++){
        size_t row = (size_t)(n0+w)*16 + lg*4 + r;
        vs[row*64 + nt*16 + lr] = (__bf16)os[r];
        vd[row*64 + nt*16 + lr] = (__bf16)od[r];
      }
    }
  }
}

// ---------- edge RBF + 2-layer MLP via MFMA: 64 edges/block, grid 1500x256 ----------
__global__ void __launch_bounds__(256) k_edgeA(const float* __restrict__ pos, const int* __restrict__ ei,
                        const float* __restrict__ W1, const float* __restrict__ b1,
                        const float* __restrict__ W2, const float* __restrict__ b2,
                        __bf16* __restrict__ e2g){
  __shared__ __bf16 W1T[48*264];   // [j][k] stride 264
  __shared__ __bf16 W2T[64*72];    // [j][k] stride 72 (k>=48 zero)
  __shared__ __bf16 e1s[64*72];    // [edge][k] stride 72 (k>=48 zeroed)
  __shared__ float dl[64], envl[64];
  int tid = threadIdx.x;
  int w = tid>>6, l = tid&63, lr = l&15, lg = l>>4;
  int eb = blockIdx.x*64;

  if (tid < 64){
    int s = ei[eb+tid], t = ei[EE+eb+tid];
    float dx = pos[3*s]-pos[3*t], dy = pos[3*s+1]-pos[3*t+1], dz = pos[3*s+2]-pos[3*t+2];
    float d = sqrtf(dx*dx+dy*dy+dz*dz+1e-12f);
    dl[tid] = d;
    envl[tid] = 0.5f*(cosf(PI_F*fminf(d*(1.0f/CUTOFF_R),1.0f))+1.0f);
  }
  for (int i=tid;i<48*128;i+=256){
    int kp = i/48, j = i - kp*48;
    bf16x2 p = {(__bf16)W1[(size_t)(2*kp)*48 + j], (__bf16)W1[(size_t)(2*kp+1)*48 + j]};
    *(bf16x2*)&W1T[j*264 + 2*kp] = p;
  }
  for (int i=tid;i<4096;i+=256){
    int k=i>>6, j=i&63;
    W2T[j*72+k] = (j<ECH && k<ECH) ? (__bf16)W2[(size_t)k*ECH+j] : (__bf16)0.f;
  }
  for (int i=tid;i<1024;i+=256){
    int r=i>>4, c=48+(i&15);
    e1s[r*72+c] = (__bf16)0.f;
  }
  __syncthreads();

  float d  = dl[w*16+lr];
  float ev = envl[w*16+lr];
  f32x4 acc[3];
  #pragma unroll
  for (int nt=0;nt<3;nt++) acc[nt] = (f32x4){0.f,0.f,0.f,0.f};
  #pragma unroll
  for (int c=0;c<8;c++){
    bf16x8 af;
    #pragma unroll
    for (int j=0;j<8;j++){
      float kk = (float)(c*32 + lg*8 + j);
      float del = (d - kk*SPACING)*INV_STD;
      af[j] = (__bf16)(exp2f(-0.72134752f*del*del)*ev);
    }
    #pragma unroll
    for (int nt=0;nt<3;nt++){
      bf16x8 bf_ = *(const bf16x8*)&W1T[(nt*16+lr)*264 + c*32 + lg*8];
      acc[nt] = __builtin_amdgcn_mfma_f32_16x16x32_bf16(af, bf_, acc[nt], 0, 0, 0);
    }
  }
  #pragma unroll
  for (int nt=0;nt<3;nt++){
    int col = nt*16+lr;
    float bb = b1[col];
    #pragma unroll
    for (int r=0;r<4;r++){
      int row = w*16 + lg*4 + r;
      e1s[row*72+col] = (__bf16)silu_f(acc[nt][r] + bb);
    }
  }
  __syncthreads();

  bf16x8 a0 = *(const bf16x8*)&e1s[(w*16+lr)*72 + lg*8];
  bf16x8 a1 = *(const bf16x8*)&e1s[(w*16+lr)*72 + 32 + lg*8];
  #pragma unroll
  for (int nt=0;nt<3;nt++){
    f32x4 o = (f32x4){0.f,0.f,0.f,0.f};
    bf16x8 b0 = *(const bf16x8*)&W2T[(nt*16+lr)*72 + lg*8];
    bf16x8 b1f= *(const bf16x8*)&W2T[(nt*16+lr)*72 + 32 + lg*8];
    o = __builtin_amdgcn_mfma_f32_16x16x32_bf16(a0, b0, o, 0, 0, 0);
    o = __builtin_amdgcn_mfma_f32_16x16x32_bf16(a1, b1f, o, 0, 0, 0);
    int col = nt*16+lr;
    float bb = b2[col];
    #pragma unroll
    for (int r=0;r<4;r++){
      int row = w*16 + lg*4 + r;
      e2g[(size_t)(eb+row)*ECH + col] = (__bf16)silu_f(o[r] + bb);
    }
  }
}

// ---------- CSR build ----------
__global__ void k_hist(const int* __restrict__ ei, int* __restrict__ deg){
  int e = blockIdx.x*256 + threadIdx.x;
  atomicAdd(&deg[ei[EE+e]], 1);
}

__global__ void __launch_bounds__(1024) k_scan(const int* __restrict__ deg, int* __restrict__ off){
  __shared__ int sums[1024];
  int t = threadIdx.x;
  int base = t*8;
  int loc[8]; int s=0;
  #pragma unroll
  for (int i=0;i<8;i++){ int idx=base+i; int v = (idx<NN)? deg[idx]:0; loc[i]=v; s+=v; }
  sums[t]=s;
  __syncthreads();
  for (int d=1; d<1024; d<<=1){
    int v = (t>=d)? sums[t-d]:0;
    __syncthreads();
    sums[t] += v;
    __syncthreads();
  }
  int run = sums[t]-s;
  #pragma unroll
  for (int i=0;i<8;i++){ int idx=base+i; if (idx<NN) off[idx]=run; run+=loc[i]; }
  if (t==1023) off[NN]=sums[1023];
}

__global__ void k_fill(const int* __restrict__ ei, const int* __restrict__ off,
                       int* __restrict__ cursor, int* __restrict__ csr){
  int e = blockIdx.x*256 + threadIdx.x;
  int d = ei[EE+e];
  int slot = off[d] + atomicAdd(&cursor[d],1);
  csr[slot]=e;
}

// ---------- per-edge MFMA: s0 = (e2@We)*(xs0[s]+xd0[d]); logits = lrelu(s0@Wa)·va; v0 = s0@Wv
// 64 edges/block, 4 waves. grid 1500x256
__global__ void __launch_bounds__(256) k_edgeB(const __bf16* __restrict__ e2g, const int* __restrict__ ei,
                        const float* __restrict__ xs0, const float* __restrict__ xd0,
                        const float* __restrict__ W_edge, const float* __restrict__ W_alpha,
                        const float* __restrict__ v_alpha, const float* __restrict__ Wv,
                        float* __restrict__ logits_g, __bf16* __restrict__ v0g){
  __shared__ __bf16 e2s[64*72];
  __shared__ __bf16 s0s[64*72];
  __shared__ __bf16 wbuf[128*72];
  __shared__ float  va_l[256];
  __shared__ int    srcd[128];
  int tid = threadIdx.x;
  int w = tid >> 6, l = tid & 63;
  int lr = l & 15, lg = l >> 4;
  int eb = blockIdx.x * 64;

  for (int i=tid;i<4096;i+=256){
    int r=i>>6, k=i&63;
    e2s[r*72+k] = (k<ECH) ? e2g[(size_t)(eb+r)*ECH+k] : (__bf16)0.f;
  }
  for (int i=tid;i<4096;i+=256){
    int k=i>>6, c=i&63;
    wbuf[c*72+k] = (k<ECH) ? (__bf16)W_edge[(size_t)k*64+c] : (__bf16)0.f;
  }
  va_l[tid] = v_alpha[tid];
  if (tid<64){ srcd[tid]=ei[eb+tid]; srcd[64+tid]=ei[EE+eb+tid]; }
  __syncthreads();

  bf16x8 ea0 = *(const bf16x8*)&e2s[(w*16+lr)*72 + lg*8];
  bf16x8 ea1 = *(const bf16x8*)&e2s[(w*16+lr)*72 + 32 + lg*8];
  f32x4 sacc[4];
  #pragma unroll
  for (int nt=0;nt<4;nt++){
    sacc[nt] = (f32x4){0.f,0.f,0.f,0.f};
    bf16x8 b0 = *(const bf16x8*)&wbuf[(nt*16+lr)*72 + lg*8];
    bf16x8 b1 = *(const bf16x8*)&wbuf[(nt*16+lr)*72 + 32 + lg*8];
    sacc[nt] = __builtin_amdgcn_mfma_f32_16x16x32_bf16(ea0, b0, sacc[nt], 0, 0, 0);
    sacc[nt] = __builtin_amdgcn_mfma_f32_16x16x32_bf16(ea1, b1, sacc[nt], 0, 0, 0);
  }
  #pragma unroll
  for (int reg=0;reg<4;reg++){
    int localrow = w*16 + lg*4 + reg;
    int sI = srcd[localrow], dI = srcd[64+localrow];
    #pragma unroll
    for (int nt=0;nt<4;nt++){
      int col = nt*16 + lr;
      float m = xs0[(size_t)sI*64+col] + xd0[(size_t)dI*64+col];
      s0s[localrow*72+col] = (__bf16)(sacc[nt][reg]*m);
    }
  }
  __syncthreads();

  bf16x8 sa0 = *(const bf16x8*)&s0s[(w*16+lr)*72 + lg*8];
  bf16x8 sa1 = *(const bf16x8*)&s0s[(w*16+lr)*72 + 32 + lg*8];

  #pragma unroll
  for (int half=0;half<2;half++){
    for (int i=tid;i<8192;i+=256){
      int k=i>>7, j=i&127;
      wbuf[j*72+k] = (__bf16)W_alpha[(size_t)k*256 + half*128 + j];
    }
    __syncthreads();
    float lg0[4]={0.f,0.f,0.f,0.f}, lg1[4]={0.f,0.f,0.f,0.f};
    #pragma unroll
    for (int nt=0;nt<8;nt++){
      f32x4 tacc = (f32x4){0.f,0.f,0.f,0.f};
      bf16x8 b0 = *(const bf16x8*)&wbuf[(nt*16+lr)*72 + lg*8];
      bf16x8 b1 = *(const bf16x8*)&wbuf[(nt*16+lr)*72 + 32 + lg*8];
      tacc = __builtin_amdgcn_mfma_f32_16x16x32_bf16(sa0, b0, tacc, 0, 0, 0);
      tacc = __builtin_amdgcn_mfma_f32_16x16x32_bf16(sa1, b1, tacc, 0, 0, 0);
      int gj = half*128 + nt*16 + lr;
      float vaj = va_l[gj];
      #pragma unroll
      for (int reg=0;reg<4;reg++){
        float t = tacc[reg];
        t = (t>0.0f) ? t : 0.2f*t;
        if (nt<4) lg0[reg] += t*vaj; else lg1[reg] += t*vaj;
      }
    }
    #pragma unroll
    for (int reg=0;reg<4;reg++){
      #pragma unroll
      for (int m=1;m<16;m<<=1){
        lg0[reg] += __shfl_xor(lg0[reg], m);
        lg1[reg] += __shfl_xor(lg1[reg], m);
      }
    }
    if (lr==0){
      #pragma unroll
      for (int reg=0;reg<4;reg++){
        int e = eb + w*16 + lg*4 + reg;
        logits_g[(size_t)e*4 + half*2 + 0] = lg0[reg];
        logits_g[(size_t)e*4 + half*2 + 1] = lg1[reg];
      }
    }
    __syncthreads();
  }

  for (int i=tid;i<4096;i+=256){
    int k=i>>6, c=i&63;
    wbuf[c*72+k] = (__bf16)Wv[(size_t)k*64+c];
  }
  __syncthreads();
  #pragma unroll
  for (int nt=0;nt<4;nt++){
    f32x4 vacc = (f32x4){0.f,0.f,0.f,0.f};
    bf16x8 b0 = *(const bf16x8*)&wbuf[(nt*16+lr)*72 + lg*8];
    bf16x8 b1 = *(const bf16x8*)&wbuf[(nt*16+lr)*72 + 32 + lg*8];
    vacc = __builtin_amdgcn_mfma_f32_16x16x32_bf16(sa0, b0, vacc, 0, 0, 0);
    vacc = __builtin_amdgcn_mfma_f32_16x16x32_bf16(sa1, b1, vacc, 0, 0, 0);
    #pragma unroll
    for (int reg=0;reg<4;reg++){
      int e = eb + w*16 + lg*4 + reg;
      v0g[(size_t)e*64 + nt*16 + lr] = (__bf16)vacc[reg];
    }
  }
}

// ---------- gather-only: softmax + bf16 gather -> agg (1 node/block, grid 8000) ----------
__global__ void __launch_bounds__(256) k_gather(const int* __restrict__ off, const int* __restrict__ csr,
                       const int* __restrict__ ei,
                       const float* __restrict__ logits_g, const __bf16* __restrict__ v0g,
                       const __bf16* __restrict__ vs, const __bf16* __restrict__ vd,
                       __bf16* __restrict__ agg){
  __shared__ float alph[MAXDEG*HH];
  __shared__ int   eidl[MAXDEG];
  __shared__ int   srcl[MAXDEG];
  __shared__ float salpha[HH];
  int tid = threadIdx.x;
  int n = blockIdx.x;
  int o0 = off[n];
  int deg = off[n+1]-o0;
  if (deg > MAXDEG) deg = MAXDEG;
  if (tid < deg){
    int e = csr[o0+tid];
    eidl[tid]=e;
    srcl[tid]=ei[e];
    float4 lgv = *(const float4*)(logits_g + (size_t)e*4);
    float* ap = &alph[tid*4];
    ap[0]=lgv.x; ap[1]=lgv.y; ap[2]=lgv.z; ap[3]=lgv.w;
  }
  __syncthreads();
  if (tid < 64){
    int h = tid>>4, i0 = tid&15;
    float m = -1e30f;
    for (int i=i0;i<deg;i+=16) m = fmaxf(m, alph[i*4+h]);
    #pragma unroll
    for (int s=1;s<16;s<<=1) m = fmaxf(m, __shfl_xor(m, s));
    float ds = 0.0f;
    for (int i=i0;i<deg;i+=16){
      float wv = expf(alph[i*4+h]-m);
      alph[i*4+h]=wv; ds += wv;
    }
    #pragma unroll
    for (int s=1;s<16;s<<=1) ds += __shfl_xor(ds, s);
    float inv = 1.0f/(ds+1e-9f);
    for (int i=i0;i<deg;i+=16) alph[i*4+h] *= inv;
    if (i0==0) salpha[h] = ds*inv;
  }
  __syncthreads();
  {
    int l = tid>>4, quad = tid&15;
    int h = quad>>2;
    float a0=0.f,a1=0.f,a2=0.f,a3=0.f;
    if (l==0){
      int i=0;
      for (;i+1<deg;i+=2){
        float aA = alph[i*4+h], aB = alph[(i+1)*4+h];
        bf16x4 vA = *(const bf16x4*)(v0g + (size_t)eidl[i]*64 + quad*4);
        bf16x4 vB = *(const bf16x4*)(v0g + (size_t)eidl[i+1]*64 + quad*4);
        a0 += aA*(float)vA[0] + aB*(float)vB[0];
        a1 += aA*(float)vA[1] + aB*(float)vB[1];
        a2 += aA*(float)vA[2] + aB*(float)vB[2];
        a3 += aA*(float)vA[3] + aB*(float)vB[3];
      }
      if (i<deg){
        float a = alph[i*4+h];
        bf16x4 vv = *(const bf16x4*)(v0g + (size_t)eidl[i]*64 + quad*4);
        a0 += a*(float)vv[0]; a1 += a*(float)vv[1]; a2 += a*(float)vv[2]; a3 += a*(float)vv[3];
      }
    } else {
      int i=0;
      for (;i+1<deg;i+=2){
        float aA = alph[i*4+h], aB = alph[(i+1)*4+h];
        bf16x4 vA = *(const bf16x4*)(vs + (size_t)srcl[i]*1024 + tid*4);
        bf16x4 vB = *(const bf16x4*)(vs + (size_t)srcl[i+1]*1024 + tid*4);
        a0 += aA*(float)vA[0] + aB*(float)vB[0];
        a1 += aA*(float)vA[1] + aB*(float)vB[1];
        a2 += aA*(float)vA[2] + aB*(float)vB[2];
        a3 += aA*(float)vA[3] + aB*(float)vB[3];
      }
      if (i<deg){
        float a = alph[i*4+h];
        bf16x4 vv = *(const bf16x4*)(vs + (size_t)srcl[i]*1024 + tid*4);
        a0 += a*(float)vv[0]; a1 += a*(float)vv[1]; a2 += a*(float)vv[2]; a3 += a*(float)vv[3];
      }
      float sa = salpha[h];
      bf16x4 vv = *(const bf16x4*)(vd + (size_t)n*1024 + tid*4);
      a0 += sa*(float)vv[0]; a1 += sa*(float)vv[1]; a2 += sa*(float)vv[2]; a3 += sa*(float)vv[3];
    }
    bf16x4 t = {(__bf16)a0,(__bf16)a1,(__bf16)a2,(__bf16)a3};
    *(bf16x4*)(agg + (size_t)n*1024 + tid*4) = t;
  }
}

// ---------- Wo + residual + rms + gated FFN + out. 8 nodes/block, 512 thr, grid 1000 ----------
// Half-tiled weights (rotating 9.2KB wbuf), LDS ~50.2KB -> 3 blocks/CU (24 waves, 75%).
__global__ void __launch_bounds__(512) k_woffn(const __bf16* __restrict__ agg,
                       const float* __restrict__ x, const float* __restrict__ Wo,
                       const float* __restrict__ Wg, const float* __restrict__ Wh,
                       const float* __restrict__ Wf, float* __restrict__ out){
  __shared__ __bf16 wbuf[64*72];         // 9216B: WoT -> WhT.h -> WfT.h (rotating)
  __shared__ __bf16 aggyb[128*72];       // 18432B: agg -> ybuf (8 nodes x 16 rows)
  __shared__ __bf16 hbuf[128*72];        // 18432B
  __shared__ float  gl[1024];            // 4096B (8 nodes x 128)
  int tid = threadIdx.x;
  int w = tid>>6, lane = tid&63, lr = lane&15, lg = lane>>4;
  int n0 = blockIdx.x*8;

  // ---- phase 1: stage WoT + load agg tile (8 nodes) ----
  for (int i=tid;i<4096;i+=512){
    int k=i>>6, c=i&63;
    wbuf[c*72+k] = (__bf16)Wo[i];
  }
  for (int i=tid;i<1024;i+=512){
    bf16x8 v = *(const bf16x8*)(agg + (size_t)n0*1024 + i*8);
    *(bf16x8*)&aggyb[(i>>3)*72 + (i&7)*8] = v;
  }
  __syncthreads();

  // ---- phase 2: x1 = x + agg@Wo (regs), wave w = node w (w in 0..7); rms (wave-local) ----
  f32x4 x1r[4];
  float scl_w;
  {
    bf16x8 a0 = *(const bf16x8*)&aggyb[(w*16+lr)*72 + lg*8];
    bf16x8 a1 = *(const bf16x8*)&aggyb[(w*16+lr)*72 + 32 + lg*8];
    const float* xr = x + (size_t)(n0+w)*1024;
    float ss = 0.0f;
    #pragma unroll
    for (int nt=0;nt<4;nt++){
      f32x4 o = (f32x4){0.f,0.f,0.f,0.f};
      bf16x8 b0 = *(const bf16x8*)&wbuf[(nt*16+lr)*72 + lg*8];
      bf16x8 b1 = *(const bf16x8*)&wbuf[(nt*16+lr)*72 + 32 + lg*8];
      o = __builtin_amdgcn_mfma_f32_16x16x32_bf16(a0, b0, o, 0, 0, 0);
      o = __builtin_amdgcn_mfma_f32_16x16x32_bf16(a1, b1, o, 0, 0, 0);
      #pragma unroll
      for (int r=0;r<4;r++){
        float xv = xr[(lg*4+r)*64 + nt*16 + lr] + o[r];
        o[r] = xv;
        ss += xv*xv;
      }
      x1r[nt] = o;
    }
    #pragma unroll
    for (int m=32;m>=1;m>>=1) ss += __shfl_xor(ss, m);
    scl_w = 1.0f/sqrtf(ss*(1.0f/1024.0f)+1e-6f);
  }
  __syncthreads();   // aggyb + wbuf consumed

  // ---- phase 3: ybuf = bf16(x1*scl) into aggyb ----
  #pragma unroll
  for (int nt=0;nt<4;nt++){
    #pragma unroll
    for (int r=0;r<4;r++){
      aggyb[(w*16+lg*4+r)*72 + nt*16+lr] = (__bf16)(x1r[nt][r]*scl_w);
    }
  }
  __syncthreads();

  // ---- phase 3b: gate (8 nodes x 128 cols, 2 per thread) ----
  {
    int c = tid&127, grp = tid>>7;   // grp 0..3
    #pragma unroll
    for (int q=0;q<2;q++){
      int nd = grp*2+q;
      float acc = 0.0f;
      #pragma unroll 8
      for (int k=0;k<64;k++) acc += (float)aggyb[(nd*16)*72 + k] * Wg[k*128+c];
      gl[nd*128+c] = silu_f(acc);
    }
  }

  // ---- phases 4-5: FFN in two halves ----
  f32x4 o2[4];
  #pragma unroll
  for (int nt=0;nt<4;nt++) o2[nt] = (f32x4){0.f,0.f,0.f,0.f};
  #pragma unroll
  for (int hf=0; hf<2; hf++){
    __syncthreads();   // gl ready (hf=0) / prior wbuf reads done (hf=1)
    for (int i=tid;i<4096;i+=512){
      int k=i>>6, j=i&63;
      wbuf[j*72+k] = (__bf16)Wh[(size_t)k*128 + hf*64 + j];
    }
    __syncthreads();
    {
      bf16x8 a0 = *(const bf16x8*)&aggyb[(w*16+lr)*72 + lg*8];
      bf16x8 a1 = *(const bf16x8*)&aggyb[(w*16+lr)*72 + 32 + lg*8];
      #pragma unroll
      for (int nt=0;nt<4;nt++){
        f32x4 o = (f32x4){0.f,0.f,0.f,0.f};
        bf16x8 b0 = *(const bf16x8*)&wbuf[(nt*16+lr)*72 + lg*8];
        bf16x8 b1 = *(const bf16x8*)&wbuf[(nt*16+lr)*72 + 32 + lg*8];
        o = __builtin_amdgcn_mfma_f32_16x16x32_bf16(a0, b0, o, 0, 0, 0);
        o = __builtin_amdgcn_mfma_f32_16x16x32_bf16(a1, b1, o, 0, 0, 0);
        int col = nt*16+lr;
        float g = gl[w*128 + hf*64 + col];
        #pragma unroll
        for (int r=0;r<4;r++){
          hbuf[(w*16+lg*4+r)*72 + col] = (__bf16)(o[r]*g);
        }
      }
    }
    __syncthreads();
    for (int i=tid;i<4096;i+=512){
      int k=i>>6, j=i&63;
      wbuf[j*72+k] = (__bf16)Wf[(size_t)(hf*64+k)*64 + j];
    }
    __syncthreads();
    {
      bf16x8 a0 = *(const bf16x8*)&hbuf[(w*16+lr)*72 + lg*8];
      bf16x8 a1 = *(const bf16x8*)&hbuf[(w*16+lr)*72 + 32 + lg*8];
      #pragma unroll
      for (int nt=0;nt<4;nt++){
        bf16x8 b0 = *(const bf16x8*)&wbuf[(nt*16+lr)*72 + lg*8];
        bf16x8 b1 = *(const bf16x8*)&wbuf[(nt*16+lr)*72 + 32 + lg*8];
        o2[nt] = __builtin_amdgcn_mfma_f32_16x16x32_bf16(a0, b0, o2[nt], 0, 0, 0);
        o2[nt] = __builtin_amdgcn_mfma_f32_16x16x32_bf16(a1, b1, o2[nt], 0, 0, 0);
      }
    }
  }

  // ---- final store: out = x1 + o2 ----
  {
    float* outr = out + (size_t)(n0+w)*1024;
    #pragma unroll
    for (int nt=0;nt<4;nt++){
      #pragma unroll
      for (int r=0;r<4;r++){
        outr[(lg*4+r)*64 + nt*16+lr] = x1r[nt][r] + o2[nt][r];
      }
    }
  }
}

extern "C" void kernel_launch(void* const* d_in, const int* in_sizes, int n_in,
                              void* d_out, int out_size, void* d_ws, size_t ws_size,
                              hipStream_t stream) {
  (void)in_sizes; (void)n_in; (void)out_size; (void)ws_size;
  const float* pos = (const float*)d_in[0];
  const float* x   = (const float*)d_in[1];
  const float* Wsrc= (const float*)d_in[2];
  const float* Wdst= (const float*)d_in[3];
  const float* W1  = (const float*)d_in[4];
  const float* b1  = (const float*)d_in[5];
  const float* W2  = (const float*)d_in[6];
  const float* b2  = (const float*)d_in[7];
  const float* We  = (const float*)d_in[8];
  const float* Wa  = (const float*)d_in[9];
  const float* va  = (const float*)d_in[10];
  const float* Wv  = (const float*)d_in[11];
  const float* Wo  = (const float*)d_in[12];
  const float* Wg  = (const float*)d_in[13];
  const float* Wh  = (const float*)d_in[14];
  const float* Wf  = (const float*)d_in[15];
  const int*   ei  = (const int*)d_in[16];
  float* out = (float*)d_out;

  char* wp = (char*)d_ws;
  auto alloc = [&](size_t bytes)->char*{
    char* p = wp;
    wp += ((bytes + 255)/256)*256;
    return p;
  };
  __bf16* wsv = (__bf16*)alloc(4096*2);
  __bf16* wdv = (__bf16*)alloc(4096*2);
  float* xs0  = (float*)alloc((size_t)NN*64*4);
  float* xd0  = (float*)alloc((size_t)NN*64*4);
  __bf16* vs  = (__bf16*)alloc((size_t)NN*1024*2);
  __bf16* vd  = (__bf16*)alloc((size_t)NN*1024*2);
  __bf16* agg = (__bf16*)alloc((size_t)NN*1024*2);
  __bf16* e2g = (__bf16*)alloc((size_t)EE*ECH*2);
  __bf16* v0g = (__bf16*)alloc((size_t)EE*64*2);
  float* lgts = (float*)alloc((size_t)EE*HH*4);
  int* deg    = (int*)alloc((size_t)NN*4);
  int* cursor = (int*)alloc((size_t)NN*4);
  int* off    = (int*)alloc((size_t)(NN+1)*4);
  int* csr    = (int*)alloc((size_t)EE*4);

  hipMemsetAsync(deg, 0, NN*sizeof(int), stream);
  hipMemsetAsync(cursor, 0, NN*sizeof(int), stream);

  k_fusew<<<32,256,0,stream>>>(Wsrc,Wdst,Wv,wsv,wdv);
  k_pre<<<NN/4,256,0,stream>>>(x,Wsrc,Wdst,wsv,wdv,xs0,xd0,vs,vd);
  k_edgeA<<<EE/64,256,0,stream>>>(pos,ei,W1,b1,W2,b2,e2g);
  k_hist<<<EE/256,256,0,stream>>>(ei,deg);
  k_scan<<<1,1024,0,stream>>>(deg,off);
  k_fill<<<EE/256,256,0,stream>>>(ei,off,cursor,csr);
  k_edgeB<<<EE/64,256,0,stream>>>(e2g,ei,xs0,xd0,We,Wa,va,Wv,lgts,v0g);
  k_gather<<<NN,256,0,stream>>>(off,csr,ei,lgts,v0g,vs,vd,agg);
  k_woffn<<<NN/8,512,0,stream>>>(agg,x,Wo,Wg,Wh,Wf,out);
}

// Round 14
// 184.574 us; speedup vs baseline: 1.2025x; 1.0909x over previous
//
#include <hip/hip_runtime.h>
#include <math.h>

// Problem constants (match reference file)
#define NN 8000
#define EE 96000
#define HH 4
#define NBASIS 256
#define ECH 48
#define FFNH 128
#define CUTOFF_R 0.0792f
#define PI_F 3.14159265358979323846f
#define SPACING (CUTOFF_R/255.0f)
#define INV_STD (256.0f/CUTOFF_R)
#define MAXDEG 48

typedef __bf16 bf16x8 __attribute__((ext_vector_type(8)));
typedef __bf16 bf16x4 __attribute__((ext_vector_type(4)));
typedef __bf16 bf16x2 __attribute__((ext_vector_type(2)));
typedef float  f32x4  __attribute__((ext_vector_type(4)));

__device__ __forceinline__ float silu_f(float x){ return x/(1.0f+expf(-x)); }

// ---------- fused weights: wsv = W_src@W_v, wdv = W_dst@W_v, bf16 out (grid 32x256) ----------
__global__ void k_fusew(const float* __restrict__ Wsrc, const float* __restrict__ Wdst,
                        const float* __restrict__ Wv,
                        __bf16* __restrict__ wsv, __bf16* __restrict__ wdv){
  int gid = blockIdx.x*256 + threadIdx.x;
  int which = gid >> 12;
  int idx = gid & 4095;
  int r = idx >> 6, c = idx & 63;
  const float* A = which ? Wdst : Wsrc;
  float acc = 0.0f;
  #pragma unroll
  for (int k=0;k<64;k++) acc += A[r*64+k]*Wv[k*64+c];
  (which ? wdv : wsv)[idx] = (__bf16)acc;
}

// ---------- fused pre: rms + xs0/xd0 + vs/vd MFMA. 4 nodes/block, grid 2000x256 ----------
__global__ void __launch_bounds__(256) k_pre(const float* __restrict__ x,
                        const float* __restrict__ Wsrc, const float* __restrict__ Wdst,
                        const __bf16* __restrict__ wsv, const __bf16* __restrict__ wdv,
                        float* __restrict__ xs0, float* __restrict__ xd0,
                        __bf16* __restrict__ vs, __bf16* __restrict__ vd){
  __shared__ __bf16 xbuf[64*72];   // 4 nodes x 16 l rows, rms-scaled bf16
  __shared__ float  xl0[4][64];    // fp32 l=0 rows (unscaled)
  __shared__ __bf16 wsb[64*72];    // wsvT [c][k]
  __shared__ __bf16 wdb[64*72];
  __shared__ float  red[16];       // [wave][q]
  int tid = threadIdx.x;
  int w = tid>>6, l = tid&63, lr = l&15, lg = l>>4;
  int n0 = blockIdx.x*4;
  const float4* xp = (const float4*)(x + (size_t)n0*1024);

  float4 v[4]; float ssq[4];
  #pragma unroll
  for (int q=0;q<4;q++){
    v[q] = xp[tid + q*256];
    ssq[q] = v[q].x*v[q].x + v[q].y*v[q].y + v[q].z*v[q].z + v[q].w*v[q].w;
  }
  #pragma unroll
  for (int q=0;q<4;q++){
    #pragma unroll
    for (int m=32;m>=1;m>>=1) ssq[q] += __shfl_xor(ssq[q], m);
  }
  if (l==0){
    #pragma unroll
    for (int q=0;q<4;q++) red[w*4+q] = ssq[q];
  }
  for (int i=tid;i<4096;i+=256){
    int k=i>>6, c=i&63;
    wsb[c*72+k] = wsv[i];
    wdb[c*72+k] = wdv[i];
  }
  if (tid < 16){
    #pragma unroll
    for (int q=0;q<4;q++){
      float4 t = v[q];
      float* p = &xl0[q][(tid&15)*4];
      p[0]=t.x; p[1]=t.y; p[2]=t.z; p[3]=t.w;
    }
  }
  __syncthreads();
  float scl[4];
  #pragma unroll
  for (int q=0;q<4;q++)
    scl[q] = 1.0f/sqrtf((red[q]+red[4+q]+red[8+q]+red[12+q])*(1.0f/1024.0f)+1e-6f);
  {
    int r = tid>>4, k4 = (tid&15)*4;
    #pragma unroll
    for (int q=0;q<4;q++){
      float s = scl[q];
      bf16x4 t = {(__bf16)(v[q].x*s),(__bf16)(v[q].y*s),(__bf16)(v[q].z*s),(__bf16)(v[q].w*s)};
      *(bf16x4*)&xbuf[(q*16+r)*72 + k4] = t;
    }
  }
  __syncthreads();

  {
    int nd = w, c = l;
    float s = scl[nd];
    float as=0.f, ad=0.f;
    #pragma unroll 8
    for (int k=0;k<64;k++){
      float xv = xl0[nd][k]*s;
      as += xv*Wsrc[k*64+c];
      ad += xv*Wdst[k*64+c];
    }
    xs0[(size_t)(n0+nd)*64 + c] = as;
    xd0[(size_t)(n0+nd)*64 + c] = ad;
  }

  {
    bf16x8 a0 = *(const bf16x8*)&xbuf[(w*16+lr)*72 + lg*8];
    bf16x8 a1 = *(const bf16x8*)&xbuf[(w*16+lr)*72 + 32 + lg*8];
    #pragma unroll
    for (int nt=0;nt<4;nt++){
      f32x4 os = (f32x4){0.f,0.f,0.f,0.f};
      f32x4 od = (f32x4){0.f,0.f,0.f,0.f};
      bf16x8 bs0 = *(const bf16x8*)&wsb[(nt*16+lr)*72 + lg*8];
      bf16x8 bs1 = *(const bf16x8*)&wsb[(nt*16+lr)*72 + 32 + lg*8];
      bf16x8 bd0 = *(const bf16x8*)&wdb[(nt*16+lr)*72 + lg*8];
      bf16x8 bd1 = *(const bf16x8*)&wdb[(nt*16+lr)*72 + 32 + lg*8];
      os = __builtin_amdgcn_mfma_f32_16x16x32_bf16(a0, bs0, os, 0, 0, 0);
      os = __builtin_amdgcn_mfma_f32_16x16x32_bf16(a1, bs1, os, 0, 0, 0);
      od = __builtin_amdgcn_mfma_f32_16x16x32_bf16(a0, bd0, od, 0, 0, 0);
      od = __builtin_amdgcn_mfma_f32_16x16x32_bf16(a1, bd1, od, 0, 0, 0);
      #pragma unroll
      for (int r=0;r<4;r++){
        size_t row = (size_t)(n0+w)*16 + lg*4 + r;
        vs[row*64 + nt*16 + lr] = (__bf16)os[r];
        vd[row*64 + nt*16 + lr] = (__bf16)od[r];
      }
    }
  }
}

// ---------- edge RBF + 2-layer MLP via MFMA: 128 edges/block, 512 thr, grid 750 ----------
__global__ void __launch_bounds__(512) k_edgeA(const float* __restrict__ pos, const int* __restrict__ ei,
                        const float* __restrict__ W1, const float* __restrict__ b1,
                        const float* __restrict__ W2, const float* __restrict__ b2,
                        __bf16* __restrict__ e2g){
  __shared__ __bf16 W1T[48*264];   // 25344B [j][k] stride 264
  __shared__ __bf16 W2T[64*72];    // 9216B  [j][k] stride 72 (k>=48 zero)
  __shared__ __bf16 e1s[128*72];   // 18432B [edge][k] stride 72 (k>=48 zeroed)
  __shared__ float dl[128], envl[128];
  int tid = threadIdx.x;
  int w = tid>>6, l = tid&63, lr = l&15, lg = l>>4;
  int eb = blockIdx.x*128;

  if (tid < 128){
    int s = ei[eb+tid], t = ei[EE+eb+tid];
    float dx = pos[3*s]-pos[3*t], dy = pos[3*s+1]-pos[3*t+1], dz = pos[3*s+2]-pos[3*t+2];
    float d = sqrtf(dx*dx+dy*dy+dz*dz+1e-12f);
    dl[tid] = d;
    envl[tid] = 0.5f*(cosf(PI_F*fminf(d*(1.0f/CUTOFF_R),1.0f))+1.0f);
  }
  for (int i=tid;i<48*128;i+=512){
    int kp = i/48, j = i - kp*48;
    bf16x2 p = {(__bf16)W1[(size_t)(2*kp)*48 + j], (__bf16)W1[(size_t)(2*kp+1)*48 + j]};
    *(bf16x2*)&W1T[j*264 + 2*kp] = p;
  }
  for (int i=tid;i<4096;i+=512){
    int k=i>>6, j=i&63;
    W2T[j*72+k] = (j<ECH && k<ECH) ? (__bf16)W2[(size_t)k*ECH+j] : (__bf16)0.f;
  }
  for (int i=tid;i<2048;i+=512){
    int r=i>>4, c=48+(i&15);
    e1s[r*72+c] = (__bf16)0.f;
  }
  __syncthreads();

  float d  = dl[w*16+lr];
  float ev = envl[w*16+lr];
  f32x4 acc[3];
  #pragma unroll
  for (int nt=0;nt<3;nt++) acc[nt] = (f32x4){0.f,0.f,0.f,0.f};
  #pragma unroll
  for (int c=0;c<8;c++){
    bf16x8 af;
    #pragma unroll
    for (int j=0;j<8;j++){
      float kk = (float)(c*32 + lg*8 + j);
      float del = (d - kk*SPACING)*INV_STD;
      af[j] = (__bf16)(exp2f(-0.72134752f*del*del)*ev);
    }
    #pragma unroll
    for (int nt=0;nt<3;nt++){
      bf16x8 bf_ = *(const bf16x8*)&W1T[(nt*16+lr)*264 + c*32 + lg*8];
      acc[nt] = __builtin_amdgcn_mfma_f32_16x16x32_bf16(af, bf_, acc[nt], 0, 0, 0);
    }
  }
  #pragma unroll
  for (int nt=0;nt<3;nt++){
    int col = nt*16+lr;
    float bb = b1[col];
    #pragma unroll
    for (int r=0;r<4;r++){
      int row = w*16 + lg*4 + r;
      e1s[row*72+col] = (__bf16)silu_f(acc[nt][r] + bb);
    }
  }
  __syncthreads();

  bf16x8 a0 = *(const bf16x8*)&e1s[(w*16+lr)*72 + lg*8];
  bf16x8 a1 = *(const bf16x8*)&e1s[(w*16+lr)*72 + 32 + lg*8];
  #pragma unroll
  for (int nt=0;nt<3;nt++){
    f32x4 o = (f32x4){0.f,0.f,0.f,0.f};
    bf16x8 b0 = *(const bf16x8*)&W2T[(nt*16+lr)*72 + lg*8];
    bf16x8 b1f= *(const bf16x8*)&W2T[(nt*16+lr)*72 + 32 + lg*8];
    o = __builtin_amdgcn_mfma_f32_16x16x32_bf16(a0, b0, o, 0, 0, 0);
    o = __builtin_amdgcn_mfma_f32_16x16x32_bf16(a1, b1f, o, 0, 0, 0);
    int col = nt*16+lr;
    float bb = b2[col];
    #pragma unroll
    for (int r=0;r<4;r++){
      int row = w*16 + lg*4 + r;
      e2g[(size_t)(eb+row)*ECH + col] = (__bf16)silu_f(o[r] + bb);
    }
  }
}

// ---------- CSR build ----------
__global__ void k_hist(const int* __restrict__ ei, int* __restrict__ deg){
  int e = blockIdx.x*256 + threadIdx.x;
  atomicAdd(&deg[ei[EE+e]], 1);
}

__global__ void __launch_bounds__(1024) k_scan(const int* __restrict__ deg, int* __restrict__ off){
  __shared__ int sums[1024];
  int t = threadIdx.x;
  int base = t*8;
  int loc[8]; int s=0;
  #pragma unroll
  for (int i=0;i<8;i++){ int idx=base+i; int v = (idx<NN)? deg[idx]:0; loc[i]=v; s+=v; }
  sums[t]=s;
  __syncthreads();
  for (int d=1; d<1024; d<<=1){
    int v = (t>=d)? sums[t-d]:0;
    __syncthreads();
    sums[t] += v;
    __syncthreads();
  }
  int run = sums[t]-s;
  #pragma unroll
  for (int i=0;i<8;i++){ int idx=base+i; if (idx<NN) off[idx]=run; run+=loc[i]; }
  if (t==1023) off[NN]=sums[1023];
}

__global__ void k_fill(const int* __restrict__ ei, const int* __restrict__ off,
                       int* __restrict__ cursor, int* __restrict__ csr){
  int e = blockIdx.x*256 + threadIdx.x;
  int d = ei[EE+e];
  int slot = off[d] + atomicAdd(&cursor[d],1);
  csr[slot]=e;
}

// ---------- per-edge MFMA: 128 edges/block, 512 thr, grid 750 ----------
__global__ void __launch_bounds__(512) k_edgeB(const __bf16* __restrict__ e2g, const int* __restrict__ ei,
                        const float* __restrict__ xs0, const float* __restrict__ xd0,
                        const float* __restrict__ W_edge, const float* __restrict__ W_alpha,
                        const float* __restrict__ v_alpha, const float* __restrict__ Wv,
                        float* __restrict__ logits_g, __bf16* __restrict__ v0g){
  __shared__ __bf16 e2s[128*72];   // 18432B
  __shared__ __bf16 s0s[128*72];   // 18432B
  __shared__ __bf16 wbuf[128*72];  // 18432B: We -> Wa.h0 -> Wa.h1 -> Wv
  __shared__ float  va_l[256];
  __shared__ int    srcd[256];     // [0:128) src, [128:256) dst
  int tid = threadIdx.x;
  int w = tid >> 6, l = tid & 63;
  int lr = l & 15, lg = l >> 4;
  int eb = blockIdx.x * 128;

  for (int i=tid;i<8192;i+=512){
    int r=i>>6, k=i&63;
    e2s[r*72+k] = (k<ECH) ? e2g[(size_t)(eb+r)*ECH+k] : (__bf16)0.f;
  }
  for (int i=tid;i<4096;i+=512){
    int k=i>>6, c=i&63;
    wbuf[c*72+k] = (k<ECH) ? (__bf16)W_edge[(size_t)k*64+c] : (__bf16)0.f;
  }
  if (tid<256) va_l[tid] = v_alpha[tid];
  if (tid<128){ srcd[tid]=ei[eb+tid]; srcd[128+tid]=ei[EE+eb+tid]; }
  __syncthreads();

  bf16x8 ea0 = *(const bf16x8*)&e2s[(w*16+lr)*72 + lg*8];
  bf16x8 ea1 = *(const bf16x8*)&e2s[(w*16+lr)*72 + 32 + lg*8];
  f32x4 sacc[4];
  #pragma unroll
  for (int nt=0;nt<4;nt++){
    sacc[nt] = (f32x4){0.f,0.f,0.f,0.f};
    bf16x8 b0 = *(const bf16x8*)&wbuf[(nt*16+lr)*72 + lg*8];
    bf16x8 b1 = *(const bf16x8*)&wbuf[(nt*16+lr)*72 + 32 + lg*8];
    sacc[nt] = __builtin_amdgcn_mfma_f32_16x16x32_bf16(ea0, b0, sacc[nt], 0, 0, 0);
    sacc[nt] = __builtin_amdgcn_mfma_f32_16x16x32_bf16(ea1, b1, sacc[nt], 0, 0, 0);
  }
  #pragma unroll
  for (int reg=0;reg<4;reg++){
    int localrow = w*16 + lg*4 + reg;
    int sI = srcd[localrow], dI = srcd[128+localrow];
    #pragma unroll
    for (int nt=0;nt<4;nt++){
      int col = nt*16 + lr;
      float m = xs0[(size_t)sI*64+col] + xd0[(size_t)dI*64+col];
      s0s[localrow*72+col] = (__bf16)(sacc[nt][reg]*m);
    }
  }
  __syncthreads();

  bf16x8 sa0 = *(const bf16x8*)&s0s[(w*16+lr)*72 + lg*8];
  bf16x8 sa1 = *(const bf16x8*)&s0s[(w*16+lr)*72 + 32 + lg*8];

  #pragma unroll
  for (int half=0;half<2;half++){
    for (int i=tid;i<8192;i+=512){
      int k=i>>7, j=i&127;
      wbuf[j*72+k] = (__bf16)W_alpha[(size_t)k*256 + half*128 + j];
    }
    __syncthreads();
    float lg0[4]={0.f,0.f,0.f,0.f}, lg1[4]={0.f,0.f,0.f,0.f};
    #pragma unroll
    for (int nt=0;nt<8;nt++){
      f32x4 tacc = (f32x4){0.f,0.f,0.f,0.f};
      bf16x8 b0 = *(const bf16x8*)&wbuf[(nt*16+lr)*72 + lg*8];
      bf16x8 b1 = *(const bf16x8*)&wbuf[(nt*16+lr)*72 + 32 + lg*8];
      tacc = __builtin_amdgcn_mfma_f32_16x16x32_bf16(sa0, b0, tacc, 0, 0, 0);
      tacc = __builtin_amdgcn_mfma_f32_16x16x32_bf16(sa1, b1, tacc, 0, 0, 0);
      int gj = half*128 + nt*16 + lr;
      float vaj = va_l[gj];
      #pragma unroll
      for (int reg=0;reg<4;reg++){
        float t = tacc[reg];
        t = (t>0.0f) ? t : 0.2f*t;
        if (nt<4) lg0[reg] += t*vaj; else lg1[reg] += t*vaj;
      }
    }
    #pragma unroll
    for (int reg=0;reg<4;reg++){
      #pragma unroll
      for (int m=1;m<16;m<<=1){
        lg0[reg] += __shfl_xor(lg0[reg], m);
        lg1[reg] += __shfl_xor(lg1[reg], m);
      }
    }
    if (lr==0){
      #pragma unroll
      for (int reg=0;reg<4;reg++){
        int e = eb + w*16 + lg*4 + reg;
        logits_g[(size_t)e*4 + half*2 + 0] = lg0[reg];
        logits_g[(size_t)e*4 + half*2 + 1] = lg1[reg];
      }
    }
    __syncthreads();
  }

  for (int i=tid;i<4096;i+=512){
    int k=i>>6, c=i&63;
    wbuf[c*72+k] = (__bf16)Wv[(size_t)k*64+c];
  }
  __syncthreads();
  #pragma unroll
  for (int nt=0;nt<4;nt++){
    f32x4 vacc = (f32x4){0.f,0.f,0.f,0.f};
    bf16x8 b0 = *(const bf16x8*)&wbuf[(nt*16+lr)*72 + lg*8];
    bf16x8 b1 = *(const bf16x8*)&wbuf[(nt*16+lr)*72 + 32 + lg*8];
    vacc = __builtin_amdgcn_mfma_f32_16x16x32_bf16(sa0, b0, vacc, 0, 0, 0);
    vacc = __builtin_amdgcn_mfma_f32_16x16x32_bf16(sa1, b1, vacc, 0, 0, 0);
    #pragma unroll
    for (int reg=0;reg<4;reg++){
      int e = eb + w*16 + lg*4 + reg;
      v0g[(size_t)e*64 + nt*16 + lr] = (__bf16)vacc[reg];
    }
  }
}

// ---------- gather-only: softmax + bf16 gather -> agg (1 node/block, grid 8000) ----------
__global__ void __launch_bounds__(256) k_gather(const int* __restrict__ off, const int* __restrict__ csr,
                       const int* __restrict__ ei,
                       const float* __restrict__ logits_g, const __bf16* __restrict__ v0g,
                       const __bf16* __restrict__ vs, const __bf16* __restrict__ vd,
                       __bf16* __restrict__ agg){
  __shared__ float alph[MAXDEG*HH];
  __shared__ int   eidl[MAXDEG];
  __shared__ int   srcl[MAXDEG];
  __shared__ float salpha[HH];
  int tid = threadIdx.x;
  int n = blockIdx.x;
  int o0 = off[n];
  int deg = off[n+1]-o0;
  if (deg > MAXDEG) deg = MAXDEG;
  if (tid < deg){
    int e = csr[o0+tid];
    eidl[tid]=e;
    srcl[tid]=ei[e];
    float4 lgv = *(const float4*)(logits_g + (size_t)e*4);
    float* ap = &alph[tid*4];
    ap[0]=lgv.x; ap[1]=lgv.y; ap[2]=lgv.z; ap[3]=lgv.w;
  }
  __syncthreads();
  if (tid < 64){
    int h = tid>>4, i0 = tid&15;
    float m = -1e30f;
    for (int i=i0;i<deg;i+=16) m = fmaxf(m, alph[i*4+h]);
    #pragma unroll
    for (int s=1;s<16;s<<=1) m = fmaxf(m, __shfl_xor(m, s));
    float ds = 0.0f;
    for (int i=i0;i<deg;i+=16){
      float wv = expf(alph[i*4+h]-m);
      alph[i*4+h]=wv; ds += wv;
    }
    #pragma unroll
    for (int s=1;s<16;s<<=1) ds += __shfl_xor(ds, s);
    float inv = 1.0f/(ds+1e-9f);
    for (int i=i0;i<deg;i+=16) alph[i*4+h] *= inv;
    if (i0==0) salpha[h] = ds*inv;
  }
  __syncthreads();
  {
    int l = tid>>4, quad = tid&15;
    int h = quad>>2;
    float a0=0.f,a1=0.f,a2=0.f,a3=0.f;
    if (l==0){
      int i=0;
      for (;i+1<deg;i+=2){
        float aA = alph[i*4+h], aB = alph[(i+1)*4+h];
        bf16x4 vA = *(const bf16x4*)(v0g + (size_t)eidl[i]*64 + quad*4);
        bf16x4 vB = *(const bf16x4*)(v0g + (size_t)eidl[i+1]*64 + quad*4);
        a0 += aA*(float)vA[0] + aB*(float)vB[0];
        a1 += aA*(float)vA[1] + aB*(float)vB[1];
        a2 += aA*(float)vA[2] + aB*(float)vB[2];
        a3 += aA*(float)vA[3] + aB*(float)vB[3];
      }
      if (i<deg){
        float a = alph[i*4+h];
        bf16x4 vv = *(const bf16x4*)(v0g + (size_t)eidl[i]*64 + quad*4);
        a0 += a*(float)vv[0]; a1 += a*(float)vv[1]; a2 += a*(float)vv[2]; a3 += a*(float)vv[3];
      }
    } else {
      int i=0;
      for (;i+1<deg;i+=2){
        float aA = alph[i*4+h], aB = alph[(i+1)*4+h];
        bf16x4 vA = *(const bf16x4*)(vs + (size_t)srcl[i]*1024 + tid*4);
        bf16x4 vB = *(const bf16x4*)(vs + (size_t)srcl[i+1]*1024 + tid*4);
        a0 += aA*(float)vA[0] + aB*(float)vB[0];
        a1 += aA*(float)vA[1] + aB*(float)vB[1];
        a2 += aA*(float)vA[2] + aB*(float)vB[2];
        a3 += aA*(float)vA[3] + aB*(float)vB[3];
      }
      if (i<deg){
        float a = alph[i*4+h];
        bf16x4 vv = *(const bf16x4*)(vs + (size_t)srcl[i]*1024 + tid*4);
        a0 += a*(float)vv[0]; a1 += a*(float)vv[1]; a2 += a*(float)vv[2]; a3 += a*(float)vv[3];
      }
      float sa = salpha[h];
      bf16x4 vv = *(const bf16x4*)(vd + (size_t)n*1024 + tid*4);
      a0 += sa*(float)vv[0]; a1 += sa*(float)vv[1]; a2 += sa*(float)vv[2]; a3 += sa*(float)vv[3];
    }
    bf16x4 t = {(__bf16)a0,(__bf16)a1,(__bf16)a2,(__bf16)a3};
    *(bf16x4*)(agg + (size_t)n*1024 + tid*4) = t;
  }
}

// ---------- Wo + residual + rms + gated FFN + out. 8 nodes/block, 512 thr, grid 1000 ----------
__global__ void __launch_bounds__(512) k_woffn(const __bf16* __restrict__ agg,
                       const float* __restrict__ x, const float* __restrict__ Wo,
                       const float* __restrict__ Wg, const float* __restrict__ Wh,
                       const float* __restrict__ Wf, float* __restrict__ out){
  __shared__ __bf16 wbuf[64*72];         // 9216B: WoT -> WhT.h -> WfT.h (rotating)
  __shared__ __bf16 aggyb[128*72];       // 18432B: agg -> ybuf (8 nodes x 16 rows)
  __shared__ __bf16 hbuf[128*72];        // 18432B
  __shared__ float  gl[1024];            // 4096B (8 nodes x 128)
  int tid = threadIdx.x;
  int w = tid>>6, lane = tid&63, lr = lane&15, lg = lane>>4;
  int n0 = blockIdx.x*8;

  // ---- phase 1: stage WoT + load agg tile (8 nodes) ----
  for (int i=tid;i<4096;i+=512){
    int k=i>>6, c=i&63;
    wbuf[c*72+k] = (__bf16)Wo[i];
  }
  for (int i=tid;i<1024;i+=512){
    bf16x8 v = *(const bf16x8*)(agg + (size_t)n0*1024 + i*8);
    *(bf16x8*)&aggyb[(i>>3)*72 + (i&7)*8] = v;
  }
  __syncthreads();

  // ---- phase 2: x1 = x + agg@Wo (regs), wave w = node w (w in 0..7); rms (wave-local) ----
  f32x4 x1r[4];
  float scl_w;
  {
    bf16x8 a0 = *(const bf16x8*)&aggyb[(w*16+lr)*72 + lg*8];
    bf16x8 a1 = *(const bf16x8*)&aggyb[(w*16+lr)*72 + 32 + lg*8];
    const float* xr = x + (size_t)(n0+w)*1024;
    float ss = 0.0f;
    #pragma unroll
    for (int nt=0;nt<4;nt++){
      f32x4 o = (f32x4){0.f,0.f,0.f,0.f};
      bf16x8 b0 = *(const bf16x8*)&wbuf[(nt*16+lr)*72 + lg*8];
      bf16x8 b1 = *(const bf16x8*)&wbuf[(nt*16+lr)*72 + 32 + lg*8];
      o = __builtin_amdgcn_mfma_f32_16x16x32_bf16(a0, b0, o, 0, 0, 0);
      o = __builtin_amdgcn_mfma_f32_16x16x32_bf16(a1, b1, o, 0, 0, 0);
      #pragma unroll
      for (int r=0;r<4;r++){
        float xv = xr[(lg*4+r)*64 + nt*16 + lr] + o[r];
        o[r] = xv;
        ss += xv*xv;
      }
      x1r[nt] = o;
    }
    #pragma unroll
    for (int m=32;m>=1;m>>=1) ss += __shfl_xor(ss, m);
    scl_w = 1.0f/sqrtf(ss*(1.0f/1024.0f)+1e-6f);
  }
  __syncthreads();   // aggyb + wbuf consumed

  // ---- phase 3: ybuf = bf16(x1*scl) into aggyb ----
  #pragma unroll
  for (int nt=0;nt<4;nt++){
    #pragma unroll
    for (int r=0;r<4;r++){
      aggyb[(w*16+lg*4+r)*72 + nt*16+lr] = (__bf16)(x1r[nt][r]*scl_w);
    }
  }
  __syncthreads();

  // ---- phase 3b: gate (8 nodes x 128 cols, 2 per thread) ----
  {
    int c = tid&127, grp = tid>>7;   // grp 0..3
    #pragma unroll
    for (int q=0;q<2;q++){
      int nd = grp*2+q;
      float acc = 0.0f;
      #pragma unroll 8
      for (int k=0;k<64;k++) acc += (float)aggyb[(nd*16)*72 + k] * Wg[k*128+c];
      gl[nd*128+c] = silu_f(acc);
    }
  }

  // ---- phases 4-5: FFN in two halves ----
  f32x4 o2[4];
  #pragma unroll
  for (int nt=0;nt<4;nt++) o2[nt] = (f32x4){0.f,0.f,0.f,0.f};
  #pragma unroll
  for (int hf=0; hf<2; hf++){
    __syncthreads();   // gl ready (hf=0) / prior wbuf reads done (hf=1)
    for (int i=tid;i<4096;i+=512){
      int k=i>>6, j=i&63;
      wbuf[j*72+k] = (__bf16)Wh[(size_t)k*128 + hf*64 + j];
    }
    __syncthreads();
    {
      bf16x8 a0 = *(const bf16x8*)&aggyb[(w*16+lr)*72 + lg*8];
      bf16x8 a1 = *(const bf16x8*)&aggyb[(w*16+lr)*72 + 32 + lg*8];
      #pragma unroll
      for (int nt=0;nt<4;nt++){
        f32x4 o = (f32x4){0.f,0.f,0.f,0.f};
        bf16x8 b0 = *(const bf16x8*)&wbuf[(nt*16+lr)*72 + lg*8];
        bf16x8 b1 = *(const bf16x8*)&wbuf[(nt*16+lr)*72 + 32 + lg*8];
        o = __builtin_amdgcn_mfma_f32_16x16x32_bf16(a0, b0, o, 0, 0, 0);
        o = __builtin_amdgcn_mfma_f32_16x16x32_bf16(a1, b1, o, 0, 0, 0);
        int col = nt*16+lr;
        float g = gl[w*128 + hf*64 + col];
        #pragma unroll
        for (int r=0;r<4;r++){
          hbuf[(w*16+lg*4+r)*72 + col] = (__bf16)(o[r]*g);
        }
      }
    }
    __syncthreads();
    for (int i=tid;i<4096;i+=512){
      int k=i>>6, j=i&63;
      wbuf[j*72+k] = (__bf16)Wf[(size_t)(hf*64+k)*64 + j];
    }
    __syncthreads();
    {
      bf16x8 a0 = *(const bf16x8*)&hbuf[(w*16+lr)*72 + lg*8];
      bf16x8 a1 = *(const bf16x8*)&hbuf[(w*16+lr)*72 + 32 + lg*8];
      #pragma unroll
      for (int nt=0;nt<4;nt++){
        bf16x8 b0 = *(const bf16x8*)&wbuf[(nt*16+lr)*72 + lg*8];
        bf16x8 b1 = *(const bf16x8*)&wbuf[(nt*16+lr)*72 + 32 + lg*8];
        o2[nt] = __builtin_amdgcn_mfma_f32_16x16x32_bf16(a0, b0, o2[nt], 0, 0, 0);
        o2[nt] = __builtin_amdgcn_mfma_f32_16x16x32_bf16(a1, b1, o2[nt], 0, 0, 0);
      }
    }
  }

  // ---- final store: out = x1 + o2 ----
  {
    float* outr = out + (size_t)(n0+w)*1024;
    #pragma unroll
    for (int nt=0;nt<4;nt++){
      #pragma unroll
      for (int r=0;r<4;r++){
        outr[(lg*4+r)*64 + nt*16+lr] = x1r[nt][r] + o2[nt][r];
      }
    }
  }
}

extern "C" void kernel_launch(void* const* d_in, const int* in_sizes, int n_in,
                              void* d_out, int out_size, void* d_ws, size_t ws_size,
                              hipStream_t stream) {
  (void)in_sizes; (void)n_in; (void)out_size; (void)ws_size;
  const float* pos = (const float*)d_in[0];
  const float* x   = (const float*)d_in[1];
  const float* Wsrc= (const float*)d_in[2];
  const float* Wdst= (const float*)d_in[3];
  const float* W1  = (const float*)d_in[4];
  const float* b1  = (const float*)d_in[5];
  const float* W2  = (const float*)d_in[6];
  const float* b2  = (const float*)d_in[7];
  const float* We  = (const float*)d_in[8];
  const float* Wa  = (const float*)d_in[9];
  const float* va  = (const float*)d_in[10];
  const float* Wv  = (const float*)d_in[11];
  const float* Wo  = (const float*)d_in[12];
  const float* Wg  = (const float*)d_in[13];
  const float* Wh  = (const float*)d_in[14];
  const float* Wf  = (const float*)d_in[15];
  const int*   ei  = (const int*)d_in[16];
  float* out = (float*)d_out;

  char* wp = (char*)d_ws;
  auto alloc = [&](size_t bytes)->char*{
    char* p = wp;
    wp += ((bytes + 255)/256)*256;
    return p;
  };
  __bf16* wsv = (__bf16*)alloc(4096*2);
  __bf16* wdv = (__bf16*)alloc(4096*2);
  float* xs0  = (float*)alloc((size_t)NN*64*4);
  float* xd0  = (float*)alloc((size_t)NN*64*4);
  __bf16* vs  = (__bf16*)alloc((size_t)NN*1024*2);
  __bf16* vd  = (__bf16*)alloc((size_t)NN*1024*2);
  __bf16* agg = (__bf16*)alloc((size_t)NN*1024*2);
  __bf16* e2g = (__bf16*)alloc((size_t)EE*ECH*2);
  __bf16* v0g = (__bf16*)alloc((size_t)EE*64*2);
  float* lgts = (float*)alloc((size_t)EE*HH*4);
  int* deg    = (int*)alloc((size_t)NN*4);
  int* cursor = (int*)alloc((size_t)NN*4);
  int* off    = (int*)alloc((size_t)(NN+1)*4);
  int* csr    = (int*)alloc((size_t)EE*4);

  hipMemsetAsync(deg, 0, NN*sizeof(int), stream);
  hipMemsetAsync(cursor, 0, NN*sizeof(int), stream);

  k_fusew<<<32,256,0,stream>>>(Wsrc,Wdst,Wv,wsv,wdv);
  k_pre<<<NN/4,256,0,stream>>>(x,Wsrc,Wdst,wsv,wdv,xs0,xd0,vs,vd);
  k_edgeA<<<EE/128,512,0,stream>>>(pos,ei,W1,b1,W2,b2,e2g);
  k_hist<<<EE/256,256,0,stream>>>(ei,deg);
  k_scan<<<1,1024,0,stream>>>(deg,off);
  k_fill<<<EE/256,256,0,stream>>>(ei,off,cursor,csr);
  k_edgeB<<<EE/128,512,0,stream>>>(e2g,ei,xs0,xd0,We,Wa,va,Wv,lgts,v0g);
  k_gather<<<NN,256,0,stream>>>(off,csr,ei,lgts,v0g,vs,vd,agg);
  k_woffn<<<NN/8,512,0,stream>>>(agg,x,Wo,Wg,Wh,Wf,out);
}

// Round 15
// 172.925 us; speedup vs baseline: 1.2835x; 1.0674x over previous
//
#include <hip/hip_runtime.h>
#include <math.h>

// Problem constants (match reference file)
#define NN 8000
#define EE 96000
#define HH 4
#define NBASIS 256
#define ECH 48
#define FFNH 128
#define CUTOFF_R 0.0792f
#define PI_F 3.14159265358979323846f
#define SPACING (CUTOFF_R/255.0f)
#define INV_STD (256.0f/CUTOFF_R)
#define MAXDEG 48

typedef __bf16 bf16x8 __attribute__((ext_vector_type(8)));
typedef __bf16 bf16x4 __attribute__((ext_vector_type(4)));
typedef __bf16 bf16x2 __attribute__((ext_vector_type(2)));
typedef float  f32x4  __attribute__((ext_vector_type(4)));

__device__ __forceinline__ float silu_f(float x){ return x/(1.0f+expf(-x)); }

// ---------- fused weights + zero deg/cursor (grid 32x256) ----------
__global__ void k_fusew(const float* __restrict__ Wsrc, const float* __restrict__ Wdst,
                        const float* __restrict__ Wv,
                        __bf16* __restrict__ wsv, __bf16* __restrict__ wdv,
                        int* __restrict__ deg, int* __restrict__ cursor){
  int gid = blockIdx.x*256 + threadIdx.x;
  if (gid < NN){ deg[gid]=0; cursor[gid]=0; }
  int which = gid >> 12;
  int idx = gid & 4095;
  int r = idx >> 6, c = idx & 63;
  const float* A = which ? Wdst : Wsrc;
  float acc = 0.0f;
  #pragma unroll
  for (int k=0;k<64;k++) acc += A[r*64+k]*Wv[k*64+c];
  (which ? wdv : wsv)[idx] = (__bf16)acc;
}

// ---------- fused pre: rms + xs0/xd0 + vs/vd MFMA. 4 nodes/block, grid 2000x256 ----------
__global__ void __launch_bounds__(256) k_pre(const float* __restrict__ x,
                        const float* __restrict__ Wsrc, const float* __restrict__ Wdst,
                        const __bf16* __restrict__ wsv, const __bf16* __restrict__ wdv,
                        float* __restrict__ xs0, float* __restrict__ xd0,
                        __bf16* __restrict__ vs, __bf16* __restrict__ vd){
  __shared__ __bf16 xbuf[64*72];   // 4 nodes x 16 l rows, rms-scaled bf16
  __shared__ float  xl0[4][64];    // fp32 l=0 rows (unscaled)
  __shared__ __bf16 wsb[64*72];    // wsvT [c][k]
  __shared__ __bf16 wdb[64*72];
  __shared__ float  red[16];       // [wave][q]
  int tid = threadIdx.x;
  int w = tid>>6, l = tid&63, lr = l&15, lg = l>>4;
  int n0 = blockIdx.x*4;
  const float4* xp = (const float4*)(x + (size_t)n0*1024);

  float4 v[4]; float ssq[4];
  #pragma unroll
  for (int q=0;q<4;q++){
    v[q] = xp[tid + q*256];
    ssq[q] = v[q].x*v[q].x + v[q].y*v[q].y + v[q].z*v[q].z + v[q].w*v[q].w;
  }
  #pragma unroll
  for (int q=0;q<4;q++){
    #pragma unroll
    for (int m=32;m>=1;m>>=1) ssq[q] += __shfl_xor(ssq[q], m);
  }
  if (l==0){
    #pragma unroll
    for (int q=0;q<4;q++) red[w*4+q] = ssq[q];
  }
  for (int i=tid;i<4096;i+=256){
    int k=i>>6, c=i&63;
    wsb[c*72+k] = wsv[i];
    wdb[c*72+k] = wdv[i];
  }
  if (tid < 16){
    #pragma unroll
    for (int q=0;q<4;q++){
      float4 t = v[q];
      float* p = &xl0[q][(tid&15)*4];
      p[0]=t.x; p[1]=t.y; p[2]=t.z; p[3]=t.w;
    }
  }
  __syncthreads();
  float scl[4];
  #pragma unroll
  for (int q=0;q<4;q++)
    scl[q] = 1.0f/sqrtf((red[q]+red[4+q]+red[8+q]+red[12+q])*(1.0f/1024.0f)+1e-6f);
  {
    int r = tid>>4, k4 = (tid&15)*4;
    #pragma unroll
    for (int q=0;q<4;q++){
      float s = scl[q];
      bf16x4 t = {(__bf16)(v[q].x*s),(__bf16)(v[q].y*s),(__bf16)(v[q].z*s),(__bf16)(v[q].w*s)};
      *(bf16x4*)&xbuf[(q*16+r)*72 + k4] = t;
    }
  }
  __syncthreads();

  {
    int nd = w, c = l;
    float s = scl[nd];
    float as=0.f, ad=0.f;
    #pragma unroll 8
    for (int k=0;k<64;k++){
      float xv = xl0[nd][k]*s;
      as += xv*Wsrc[k*64+c];
      ad += xv*Wdst[k*64+c];
    }
    xs0[(size_t)(n0+nd)*64 + c] = as;
    xd0[(size_t)(n0+nd)*64 + c] = ad;
  }

  {
    bf16x8 a0 = *(const bf16x8*)&xbuf[(w*16+lr)*72 + lg*8];
    bf16x8 a1 = *(const bf16x8*)&xbuf[(w*16+lr)*72 + 32 + lg*8];
    #pragma unroll
    for (int nt=0;nt<4;nt++){
      f32x4 os = (f32x4){0.f,0.f,0.f,0.f};
      f32x4 od = (f32x4){0.f,0.f,0.f,0.f};
      bf16x8 bs0 = *(const bf16x8*)&wsb[(nt*16+lr)*72 + lg*8];
      bf16x8 bs1 = *(const bf16x8*)&wsb[(nt*16+lr)*72 + 32 + lg*8];
      bf16x8 bd0 = *(const bf16x8*)&wdb[(nt*16+lr)*72 + lg*8];
      bf16x8 bd1 = *(const bf16x8*)&wdb[(nt*16+lr)*72 + 32 + lg*8];
      os = __builtin_amdgcn_mfma_f32_16x16x32_bf16(a0, bs0, os, 0, 0, 0);
      os = __builtin_amdgcn_mfma_f32_16x16x32_bf16(a1, bs1, os, 0, 0, 0);
      od = __builtin_amdgcn_mfma_f32_16x16x32_bf16(a0, bd0, od, 0, 0, 0);
      od = __builtin_amdgcn_mfma_f32_16x16x32_bf16(a1, bd1, od, 0, 0, 0);
      #pragma unroll
      for (int r=0;r<4;r++){
        size_t row = (size_t)(n0+w)*16 + lg*4 + r;
        vs[row*64 + nt*16 + lr] = (__bf16)os[r];
        vd[row*64 + nt*16 + lr] = (__bf16)od[r];
      }
    }
  }
}

// ---------- edge RBF + 2-layer MLP via MFMA + hist: 128 edges/block, 512 thr, grid 750 ----------
__global__ void __launch_bounds__(512) k_edgeA(const float* __restrict__ pos, const int* __restrict__ ei,
                        const float* __restrict__ W1, const float* __restrict__ b1,
                        const float* __restrict__ W2, const float* __restrict__ b2,
                        __bf16* __restrict__ e2g, int* __restrict__ deg){
  __shared__ __bf16 W1T[48*264];   // 25344B [j][k] stride 264
  __shared__ __bf16 W2T[64*72];    // 9216B  [j][k] stride 72 (k>=48 zero)
  __shared__ __bf16 e1s[128*72];   // 18432B [edge][k] stride 72 (k>=48 zeroed)
  __shared__ float dl[128], envl[128];
  int tid = threadIdx.x;
  int w = tid>>6, l = tid&63, lr = l&15, lg = l>>4;
  int eb = blockIdx.x*128;

  if (tid < 128){
    int s = ei[eb+tid], t = ei[EE+eb+tid];
    float dx = pos[3*s]-pos[3*t], dy = pos[3*s+1]-pos[3*t+1], dz = pos[3*s+2]-pos[3*t+2];
    float d = sqrtf(dx*dx+dy*dy+dz*dz+1e-12f);
    dl[tid] = d;
    envl[tid] = 0.5f*(cosf(PI_F*fminf(d*(1.0f/CUTOFF_R),1.0f))+1.0f);
    atomicAdd(&deg[t], 1);   // folded k_hist
  }
  for (int i=tid;i<48*128;i+=512){
    int kp = i/48, j = i - kp*48;
    bf16x2 p = {(__bf16)W1[(size_t)(2*kp)*48 + j], (__bf16)W1[(size_t)(2*kp+1)*48 + j]};
    *(bf16x2*)&W1T[j*264 + 2*kp] = p;
  }
  for (int i=tid;i<4096;i+=512){
    int k=i>>6, j=i&63;
    W2T[j*72+k] = (j<ECH && k<ECH) ? (__bf16)W2[(size_t)k*ECH+j] : (__bf16)0.f;
  }
  for (int i=tid;i<2048;i+=512){
    int r=i>>4, c=48+(i&15);
    e1s[r*72+c] = (__bf16)0.f;
  }
  __syncthreads();

  float d  = dl[w*16+lr];
  float ev = envl[w*16+lr];
  f32x4 acc[3];
  #pragma unroll
  for (int nt=0;nt<3;nt++) acc[nt] = (f32x4){0.f,0.f,0.f,0.f};
  #pragma unroll
  for (int c=0;c<8;c++){
    bf16x8 af;
    #pragma unroll
    for (int j=0;j<8;j++){
      float kk = (float)(c*32 + lg*8 + j);
      float del = (d - kk*SPACING)*INV_STD;
      af[j] = (__bf16)(exp2f(-0.72134752f*del*del)*ev);
    }
    #pragma unroll
    for (int nt=0;nt<3;nt++){
      bf16x8 bf_ = *(const bf16x8*)&W1T[(nt*16+lr)*264 + c*32 + lg*8];
      acc[nt] = __builtin_amdgcn_mfma_f32_16x16x32_bf16(af, bf_, acc[nt], 0, 0, 0);
    }
  }
  #pragma unroll
  for (int nt=0;nt<3;nt++){
    int col = nt*16+lr;
    float bb = b1[col];
    #pragma unroll
    for (int r=0;r<4;r++){
      int row = w*16 + lg*4 + r;
      e1s[row*72+col] = (__bf16)silu_f(acc[nt][r] + bb);
    }
  }
  __syncthreads();

  bf16x8 a0 = *(const bf16x8*)&e1s[(w*16+lr)*72 + lg*8];
  bf16x8 a1 = *(const bf16x8*)&e1s[(w*16+lr)*72 + 32 + lg*8];
  #pragma unroll
  for (int nt=0;nt<3;nt++){
    f32x4 o = (f32x4){0.f,0.f,0.f,0.f};
    bf16x8 b0 = *(const bf16x8*)&W2T[(nt*16+lr)*72 + lg*8];
    bf16x8 b1f= *(const bf16x8*)&W2T[(nt*16+lr)*72 + 32 + lg*8];
    o = __builtin_amdgcn_mfma_f32_16x16x32_bf16(a0, b0, o, 0, 0, 0);
    o = __builtin_amdgcn_mfma_f32_16x16x32_bf16(a1, b1f, o, 0, 0, 0);
    int col = nt*16+lr;
    float bb = b2[col];
    #pragma unroll
    for (int r=0;r<4;r++){
      int row = w*16 + lg*4 + r;
      e2g[(size_t)(eb+row)*ECH + col] = (__bf16)silu_f(o[r] + bb);
    }
  }
}

// ---------- CSR scan ----------
__global__ void __launch_bounds__(1024) k_scan(const int* __restrict__ deg, int* __restrict__ off){
  __shared__ int sums[1024];
  int t = threadIdx.x;
  int base = t*8;
  int loc[8]; int s=0;
  #pragma unroll
  for (int i=0;i<8;i++){ int idx=base+i; int v = (idx<NN)? deg[idx]:0; loc[i]=v; s+=v; }
  sums[t]=s;
  __syncthreads();
  for (int d=1; d<1024; d<<=1){
    int v = (t>=d)? sums[t-d]:0;
    __syncthreads();
    sums[t] += v;
    __syncthreads();
  }
  int run = sums[t]-s;
  #pragma unroll
  for (int i=0;i<8;i++){ int idx=base+i; if (idx<NN) off[idx]=run; run+=loc[i]; }
  if (t==1023) off[NN]=sums[1023];
}

// ---------- per-edge MFMA + csr fill: 128 edges/block, 512 thr, grid 750 ----------
__global__ void __launch_bounds__(512) k_edgeB(const __bf16* __restrict__ e2g, const int* __restrict__ ei,
                        const float* __restrict__ xs0, const float* __restrict__ xd0,
                        const float* __restrict__ W_edge, const float* __restrict__ W_alpha,
                        const float* __restrict__ v_alpha, const float* __restrict__ Wv,
                        const int* __restrict__ off, int* __restrict__ cursor, int* __restrict__ csr,
                        float* __restrict__ logits_g, __bf16* __restrict__ v0g){
  __shared__ __bf16 e2s[128*72];   // 18432B
  __shared__ __bf16 s0s[128*72];   // 18432B
  __shared__ __bf16 wbuf[128*72];  // 18432B: We -> Wa.h0 -> Wa.h1 -> Wv
  __shared__ float  va_l[256];
  __shared__ int    srcd[256];     // [0:128) src, [128:256) dst
  int tid = threadIdx.x;
  int w = tid >> 6, l = tid & 63;
  int lr = l & 15, lg = l >> 4;
  int eb = blockIdx.x * 128;

  for (int i=tid;i<8192;i+=512){
    int r=i>>6, k=i&63;
    e2s[r*72+k] = (k<ECH) ? e2g[(size_t)(eb+r)*ECH+k] : (__bf16)0.f;
  }
  for (int i=tid;i<4096;i+=512){
    int k=i>>6, c=i&63;
    wbuf[c*72+k] = (k<ECH) ? (__bf16)W_edge[(size_t)k*64+c] : (__bf16)0.f;
  }
  if (tid<256) va_l[tid] = v_alpha[tid];
  if (tid<128){
    int sI = ei[eb+tid], dI = ei[EE+eb+tid];
    srcd[tid]=sI; srcd[128+tid]=dI;
    int slot = off[dI] + atomicAdd(&cursor[dI],1);   // folded k_fill
    csr[slot] = eb + tid;
  }
  __syncthreads();

  bf16x8 ea0 = *(const bf16x8*)&e2s[(w*16+lr)*72 + lg*8];
  bf16x8 ea1 = *(const bf16x8*)&e2s[(w*16+lr)*72 + 32 + lg*8];
  f32x4 sacc[4];
  #pragma unroll
  for (int nt=0;nt<4;nt++){
    sacc[nt] = (f32x4){0.f,0.f,0.f,0.f};
    bf16x8 b0 = *(const bf16x8*)&wbuf[(nt*16+lr)*72 + lg*8];
    bf16x8 b1 = *(const bf16x8*)&wbuf[(nt*16+lr)*72 + 32 + lg*8];
    sacc[nt] = __builtin_amdgcn_mfma_f32_16x16x32_bf16(ea0, b0, sacc[nt], 0, 0, 0);
    sacc[nt] = __builtin_amdgcn_mfma_f32_16x16x32_bf16(ea1, b1, sacc[nt], 0, 0, 0);
  }
  #pragma unroll
  for (int reg=0;reg<4;reg++){
    int localrow = w*16 + lg*4 + reg;
    int sI = srcd[localrow], dI = srcd[128+localrow];
    #pragma unroll
    for (int nt=0;nt<4;nt++){
      int col = nt*16 + lr;
      float m = xs0[(size_t)sI*64+col] + xd0[(size_t)dI*64+col];
      s0s[localrow*72+col] = (__bf16)(sacc[nt][reg]*m);
    }
  }
  __syncthreads();

  bf16x8 sa0 = *(const bf16x8*)&s0s[(w*16+lr)*72 + lg*8];
  bf16x8 sa1 = *(const bf16x8*)&s0s[(w*16+lr)*72 + 32 + lg*8];

  #pragma unroll
  for (int half=0;half<2;half++){
    for (int i=tid;i<8192;i+=512){
      int k=i>>7, j=i&127;
      wbuf[j*72+k] = (__bf16)W_alpha[(size_t)k*256 + half*128 + j];
    }
    __syncthreads();
    float lg0[4]={0.f,0.f,0.f,0.f}, lg1[4]={0.f,0.f,0.f,0.f};
    #pragma unroll
    for (int nt=0;nt<8;nt++){
      f32x4 tacc = (f32x4){0.f,0.f,0.f,0.f};
      bf16x8 b0 = *(const bf16x8*)&wbuf[(nt*16+lr)*72 + lg*8];
      bf16x8 b1 = *(const bf16x8*)&wbuf[(nt*16+lr)*72 + 32 + lg*8];
      tacc = __builtin_amdgcn_mfma_f32_16x16x32_bf16(sa0, b0, tacc, 0, 0, 0);
      tacc = __builtin_amdgcn_mfma_f32_16x16x32_bf16(sa1, b1, tacc, 0, 0, 0);
      int gj = half*128 + nt*16 + lr;
      float vaj = va_l[gj];
      #pragma unroll
      for (int reg=0;reg<4;reg++){
        float t = tacc[reg];
        t = (t>0.0f) ? t : 0.2f*t;
        if (nt<4) lg0[reg] += t*vaj; else lg1[reg] += t*vaj;
      }
    }
    #pragma unroll
    for (int reg=0;reg<4;reg++){
      #pragma unroll
      for (int m=1;m<16;m<<=1){
        lg0[reg] += __shfl_xor(lg0[reg], m);
        lg1[reg] += __shfl_xor(lg1[reg], m);
      }
    }
    if (lr==0){
      #pragma unroll
      for (int reg=0;reg<4;reg++){
        int e = eb + w*16 + lg*4 + reg;
        logits_g[(size_t)e*4 + half*2 + 0] = lg0[reg];
        logits_g[(size_t)e*4 + half*2 + 1] = lg1[reg];
      }
    }
    __syncthreads();
  }

  for (int i=tid;i<4096;i+=512){
    int k=i>>6, c=i&63;
    wbuf[c*72+k] = (__bf16)Wv[(size_t)k*64+c];
  }
  __syncthreads();
  #pragma unroll
  for (int nt=0;nt<4;nt++){
    f32x4 vacc = (f32x4){0.f,0.f,0.f,0.f};
    bf16x8 b0 = *(const bf16x8*)&wbuf[(nt*16+lr)*72 + lg*8];
    bf16x8 b1 = *(const bf16x8*)&wbuf[(nt*16+lr)*72 + 32 + lg*8];
    vacc = __builtin_amdgcn_mfma_f32_16x16x32_bf16(sa0, b0, vacc, 0, 0, 0);
    vacc = __builtin_amdgcn_mfma_f32_16x16x32_bf16(sa1, b1, vacc, 0, 0, 0);
    #pragma unroll
    for (int reg=0;reg<4;reg++){
      int e = eb + w*16 + lg*4 + reg;
      v0g[(size_t)e*64 + nt*16 + lr] = (__bf16)vacc[reg];
    }
  }
}

// ---------- gather-only: softmax + bf16 gather -> agg (1 node/block, grid 8000) ----------
__global__ void __launch_bounds__(256) k_gather(const int* __restrict__ off, const int* __restrict__ csr,
                       const int* __restrict__ ei,
                       const float* __restrict__ logits_g, const __bf16* __restrict__ v0g,
                       const __bf16* __restrict__ vs, const __bf16* __restrict__ vd,
                       __bf16* __restrict__ agg){
  __shared__ float alph[MAXDEG*HH];
  __shared__ int   eidl[MAXDEG];
  __shared__ int   srcl[MAXDEG];
  __shared__ float salpha[HH];
  int tid = threadIdx.x;
  int n = blockIdx.x;
  int o0 = off[n];
  int deg = off[n+1]-o0;
  if (deg > MAXDEG) deg = MAXDEG;
  if (tid < deg){
    int e = csr[o0+tid];
    eidl[tid]=e;
    srcl[tid]=ei[e];
    float4 lgv = *(const float4*)(logits_g + (size_t)e*4);
    float* ap = &alph[tid*4];
    ap[0]=lgv.x; ap[1]=lgv.y; ap[2]=lgv.z; ap[3]=lgv.w;
  }
  __syncthreads();
  if (tid < 64){
    int h = tid>>4, i0 = tid&15;
    float m = -1e30f;
    for (int i=i0;i<deg;i+=16) m = fmaxf(m, alph[i*4+h]);
    #pragma unroll
    for (int s=1;s<16;s<<=1) m = fmaxf(m, __shfl_xor(m, s));
    float ds = 0.0f;
    for (int i=i0;i<deg;i+=16){
      float wv = expf(alph[i*4+h]-m);
      alph[i*4+h]=wv; ds += wv;
    }
    #pragma unroll
    for (int s=1;s<16;s<<=1) ds += __shfl_xor(ds, s);
    float inv = 1.0f/(ds+1e-9f);
    for (int i=i0;i<deg;i+=16) alph[i*4+h] *= inv;
    if (i0==0) salpha[h] = ds*inv;
  }
  __syncthreads();
  {
    int l = tid>>4, quad = tid&15;
    int h = quad>>2;
    float a0=0.f,a1=0.f,a2=0.f,a3=0.f;
    if (l==0){
      int i=0;
      for (;i+1<deg;i+=2){
        float aA = alph[i*4+h], aB = alph[(i+1)*4+h];
        bf16x4 vA = *(const bf16x4*)(v0g + (size_t)eidl[i]*64 + quad*4);
        bf16x4 vB = *(const bf16x4*)(v0g + (size_t)eidl[i+1]*64 + quad*4);
        a0 += aA*(float)vA[0] + aB*(float)vB[0];
        a1 += aA*(float)vA[1] + aB*(float)vB[1];
        a2 += aA*(float)vA[2] + aB*(float)vB[2];
        a3 += aA*(float)vA[3] + aB*(float)vB[3];
      }
      if (i<deg){
        float a = alph[i*4+h];
        bf16x4 vv = *(const bf16x4*)(v0g + (size_t)eidl[i]*64 + quad*4);
        a0 += a*(float)vv[0]; a1 += a*(float)vv[1]; a2 += a*(float)vv[2]; a3 += a*(float)vv[3];
      }
    } else {
      int i=0;
      for (;i+1<deg;i+=2){
        float aA = alph[i*4+h], aB = alph[(i+1)*4+h];
        bf16x4 vA = *(const bf16x4*)(vs + (size_t)srcl[i]*1024 + tid*4);
        bf16x4 vB = *(const bf16x4*)(vs + (size_t)srcl[i+1]*1024 + tid*4);
        a0 += aA*(float)vA[0] + aB*(float)vB[0];
        a1 += aA*(float)vA[1] + aB*(float)vB[1];
        a2 += aA*(float)vA[2] + aB*(float)vB[2];
        a3 += aA*(float)vA[3] + aB*(float)vB[3];
      }
      if (i<deg){
        float a = alph[i*4+h];
        bf16x4 vv = *(const bf16x4*)(vs + (size_t)srcl[i]*1024 + tid*4);
        a0 += a*(float)vv[0]; a1 += a*(float)vv[1]; a2 += a*(float)vv[2]; a3 += a*(float)vv[3];
      }
      float sa = salpha[h];
      bf16x4 vv = *(const bf16x4*)(vd + (size_t)n*1024 + tid*4);
      a0 += sa*(float)vv[0]; a1 += sa*(float)vv[1]; a2 += sa*(float)vv[2]; a3 += sa*(float)vv[3];
    }
    bf16x4 t = {(__bf16)a0,(__bf16)a1,(__bf16)a2,(__bf16)a3};
    *(bf16x4*)(agg + (size_t)n*1024 + tid*4) = t;
  }
}

// ---------- Wo + residual + rms + gated FFN + out. 8 nodes/block, 512 thr, grid 1000 ----------
__global__ void __launch_bounds__(512) k_woffn(const __bf16* __restrict__ agg,
                       const float* __restrict__ x, const float* __restrict__ Wo,
                       const float* __restrict__ Wg, const float* __restrict__ Wh,
                       const float* __restrict__ Wf, float* __restrict__ out){
  __shared__ __bf16 wbuf[64*72];         // 9216B: WoT -> WhT.h -> WfT.h (rotating)
  __shared__ __bf16 aggyb[128*72];       // 18432B: agg -> ybuf (8 nodes x 16 rows)
  __shared__ __bf16 hbuf[128*72];        // 18432B
  __shared__ float  gl[1024];            // 4096B (8 nodes x 128)
  int tid = threadIdx.x;
  int w = tid>>6, lane = tid&63, lr = lane&15, lg = lane>>4;
  int n0 = blockIdx.x*8;

  // ---- T14-style prefetch: issue x loads first; latency hides under phase-1 staging ----
  const float* xr = x + (size_t)(n0+w)*1024;
  float xv[16];
  #pragma unroll
  for (int nt=0;nt<4;nt++){
    #pragma unroll
    for (int r=0;r<4;r++){
      xv[nt*4+r] = xr[(lg*4+r)*64 + nt*16 + lr];
    }
  }

  // ---- phase 1: stage WoT + load agg tile (8 nodes) ----
  for (int i=tid;i<4096;i+=512){
    int k=i>>6, c=i&63;
    wbuf[c*72+k] = (__bf16)Wo[i];
  }
  for (int i=tid;i<1024;i+=512){
    bf16x8 v = *(const bf16x8*)(agg + (size_t)n0*1024 + i*8);
    *(bf16x8*)&aggyb[(i>>3)*72 + (i&7)*8] = v;
  }
  __syncthreads();

  // ---- phase 2: x1 = x + agg@Wo (regs), wave w = node w (w in 0..7); rms (wave-local) ----
  f32x4 x1r[4];
  float scl_w;
  {
    bf16x8 a0 = *(const bf16x8*)&aggyb[(w*16+lr)*72 + lg*8];
    bf16x8 a1 = *(const bf16x8*)&aggyb[(w*16+lr)*72 + 32 + lg*8];
    float ss = 0.0f;
    #pragma unroll
    for (int nt=0;nt<4;nt++){
      f32x4 o = (f32x4){0.f,0.f,0.f,0.f};
      bf16x8 b0 = *(const bf16x8*)&wbuf[(nt*16+lr)*72 + lg*8];
      bf16x8 b1 = *(const bf16x8*)&wbuf[(nt*16+lr)*72 + 32 + lg*8];
      o = __builtin_amdgcn_mfma_f32_16x16x32_bf16(a0, b0, o, 0, 0, 0);
      o = __builtin_amdgcn_mfma_f32_16x16x32_bf16(a1, b1, o, 0, 0, 0);
      #pragma unroll
      for (int r=0;r<4;r++){
        float xvv = xv[nt*4+r] + o[r];
        o[r] = xvv;
        ss += xvv*xvv;
      }
      x1r[nt] = o;
    }
    #pragma unroll
    for (int m=32;m>=1;m>>=1) ss += __shfl_xor(ss, m);
    scl_w = 1.0f/sqrtf(ss*(1.0f/1024.0f)+1e-6f);
  }
  __syncthreads();   // aggyb + wbuf consumed

  // ---- phase 3: ybuf = bf16(x1*scl) into aggyb ----
  #pragma unroll
  for (int nt=0;nt<4;nt++){
    #pragma unroll
    for (int r=0;r<4;r++){
      aggyb[(w*16+lg*4+r)*72 + nt*16+lr] = (__bf16)(x1r[nt][r]*scl_w);
    }
  }
  __syncthreads();

  // ---- phase 3b: gate (8 nodes x 128 cols, 2 per thread) ----
  {
    int c = tid&127, grp = tid>>7;   // grp 0..3
    #pragma unroll
    for (int q=0;q<2;q++){
      int nd = grp*2+q;
      float acc = 0.0f;
      #pragma unroll 8
      for (int k=0;k<64;k++) acc += (float)aggyb[(nd*16)*72 + k] * Wg[k*128+c];
      gl[nd*128+c] = silu_f(acc);
    }
  }

  // ---- phases 4-5: FFN in two halves ----
  f32x4 o2[4];
  #pragma unroll
  for (int nt=0;nt<4;nt++) o2[nt] = (f32x4){0.f,0.f,0.f,0.f};
  #pragma unroll
  for (int hf=0; hf<2; hf++){
    __syncthreads();   // gl ready (hf=0) / prior wbuf reads done (hf=1)
    for (int i=tid;i<4096;i+=512){
      int k=i>>6, j=i&63;
      wbuf[j*72+k] = (__bf16)Wh[(size_t)k*128 + hf*64 + j];
    }
    __syncthreads();
    {
      bf16x8 a0 = *(const bf16x8*)&aggyb[(w*16+lr)*72 + lg*8];
      bf16x8 a1 = *(const bf16x8*)&aggyb[(w*16+lr)*72 + 32 + lg*8];
      #pragma unroll
      for (int nt=0;nt<4;nt++){
        f32x4 o = (f32x4){0.f,0.f,0.f,0.f};
        bf16x8 b0 = *(const bf16x8*)&wbuf[(nt*16+lr)*72 + lg*8];
        bf16x8 b1 = *(const bf16x8*)&wbuf[(nt*16+lr)*72 + 32 + lg*8];
        o = __builtin_amdgcn_mfma_f32_16x16x32_bf16(a0, b0, o, 0, 0, 0);
        o = __builtin_amdgcn_mfma_f32_16x16x32_bf16(a1, b1, o, 0, 0, 0);
        int col = nt*16+lr;
        float g = gl[w*128 + hf*64 + col];
        #pragma unroll
        for (int r=0;r<4;r++){
          hbuf[(w*16+lg*4+r)*72 + col] = (__bf16)(o[r]*g);
        }
      }
    }
    __syncthreads();
    for (int i=tid;i<4096;i+=512){
      int k=i>>6, j=i&63;
      wbuf[j*72+k] = (__bf16)Wf[(size_t)(hf*64+k)*64 + j];
    }
    __syncthreads();
    {
      bf16x8 a0 = *(const bf16x8*)&hbuf[(w*16+lr)*72 + lg*8];
      bf16x8 a1 = *(const bf16x8*)&hbuf[(w*16+lr)*72 + 32 + lg*8];
      #pragma unroll
      for (int nt=0;nt<4;nt++){
        bf16x8 b0 = *(const bf16x8*)&wbuf[(nt*16+lr)*72 + lg*8];
        bf16x8 b1 = *(const bf16x8*)&wbuf[(nt*16+lr)*72 + 32 + lg*8];
        o2[nt] = __builtin_amdgcn_mfma_f32_16x16x32_bf16(a0, b0, o2[nt], 0, 0, 0);
        o2[nt] = __builtin_amdgcn_mfma_f32_16x16x32_bf16(a1, b1, o2[nt], 0, 0, 0);
      }
    }
  }

  // ---- final store: out = x1 + o2 ----
  {
    float* outr = out + (size_t)(n0+w)*1024;
    #pragma unroll
    for (int nt=0;nt<4;nt++){
      #pragma unroll
      for (int r=0;r<4;r++){
        outr[(lg*4+r)*64 + nt*16+lr] = x1r[nt][r] + o2[nt][r];
      }
    }
  }
}

extern "C" void kernel_launch(void* const* d_in, const int* in_sizes, int n_in,
                              void* d_out, int out_size, void* d_ws, size_t ws_size,
                              hipStream_t stream) {
  (void)in_sizes; (void)n_in; (void)out_size; (void)ws_size;
  const float* pos = (const float*)d_in[0];
  const float* x   = (const float*)d_in[1];
  const float* Wsrc= (const float*)d_in[2];
  const float* Wdst= (const float*)d_in[3];
  const float* W1  = (const float*)d_in[4];
  const float* b1  = (const float*)d_in[5];
  const float* W2  = (const float*)d_in[6];
  const float* b2  = (const float*)d_in[7];
  const float* We  = (const float*)d_in[8];
  const float* Wa  = (const float*)d_in[9];
  const float* va  = (const float*)d_in[10];
  const float* Wv  = (const float*)d_in[11];
  const float* Wo  = (const float*)d_in[12];
  const float* Wg  = (const float*)d_in[13];
  const float* Wh  = (const float*)d_in[14];
  const float* Wf  = (const float*)d_in[15];
  const int*   ei  = (const int*)d_in[16];
  float* out = (float*)d_out;

  char* wp = (char*)d_ws;
  auto alloc = [&](size_t bytes)->char*{
    char* p = wp;
    wp += ((bytes + 255)/256)*256;
    return p;
  };
  __bf16* wsv = (__bf16*)alloc(4096*2);
  __bf16* wdv = (__bf16*)alloc(4096*2);
  float* xs0  = (float*)alloc((size_t)NN*64*4);
  float* xd0  = (float*)alloc((size_t)NN*64*4);
  __bf16* vs  = (__bf16*)alloc((size_t)NN*1024*2);
  __bf16* vd  = (__bf16*)alloc((size_t)NN*1024*2);
  __bf16* agg = (__bf16*)alloc((size_t)NN*1024*2);
  __bf16* e2g = (__bf16*)alloc((size_t)EE*ECH*2);
  __bf16* v0g = (__bf16*)alloc((size_t)EE*64*2);
  float* lgts = (float*)alloc((size_t)EE*HH*4);
  int* deg    = (int*)alloc((size_t)NN*4);
  int* cursor = (int*)alloc((size_t)NN*4);
  int* off    = (int*)alloc((size_t)(NN+1)*4);
  int* csr    = (int*)alloc((size_t)EE*4);

  k_fusew<<<32,256,0,stream>>>(Wsrc,Wdst,Wv,wsv,wdv,deg,cursor);
  k_pre<<<NN/4,256,0,stream>>>(x,Wsrc,Wdst,wsv,wdv,xs0,xd0,vs,vd);
  k_edgeA<<<EE/128,512,0,stream>>>(pos,ei,W1,b1,W2,b2,e2g,deg);
  k_scan<<<1,1024,0,stream>>>(deg,off);
  k_edgeB<<<EE/128,512,0,stream>>>(e2g,ei,xs0,xd0,We,Wa,va,Wv,off,cursor,csr,lgts,v0g);
  k_gather<<<NN,256,0,stream>>>(off,csr,ei,lgts,v0g,vs,vd,agg);
  k_woffn<<<NN/8,512,0,stream>>>(agg,x,Wo,Wg,Wh,Wf,out);
}

// Round 16
// 165.073 us; speedup vs baseline: 1.3446x; 1.0476x over previous
//
#include <hip/hip_runtime.h>
#include <math.h>

// Problem constants (match reference file)
#define NN 8000
#define EE 96000
#define HH 4
#define NBASIS 256
#define ECH 48
#define FFNH 128
#define CUTOFF_R 0.0792f
#define PI_F 3.14159265358979323846f
#define SPACING (CUTOFF_R/255.0f)
#define INV_STD (256.0f/CUTOFF_R)
#define MAXDEG 48

typedef __bf16 bf16x8 __attribute__((ext_vector_type(8)));
typedef __bf16 bf16x4 __attribute__((ext_vector_type(4)));
typedef __bf16 bf16x2 __attribute__((ext_vector_type(2)));
typedef float  f32x4  __attribute__((ext_vector_type(4)));

__device__ __forceinline__ float silu_f(float x){ return x/(1.0f+expf(-x)); }

// prepw layout (bf16 elements):
// 0      WeT  [c*64+k]   4096 (k>=48 zero)
// 4096   WvT  [c*64+k]   4096
// 8192   WoT  [c*64+k]   4096
// 12288  W2T  [j*64+k]   4096 (j,k>=48 zero)
// 16384  WhT  [n*64+k]   8192
// 24576  WfT  [j*128+k]  8192
// 32768  W1T  [j*256+k] 12288
// 45056  WaT  [j*64+k]  16384
#define PW_We 0
#define PW_Wv 4096
#define PW_Wo 8192
#define PW_W2 12288
#define PW_Wh 16384
#define PW_Wf 24576
#define PW_W1 32768
#define PW_Wa 45056
#define PW_TOTAL 61440

// ---------- prep: all weights -> bf16 transposed (grid 240x256) ----------
__global__ void k_prep(const float* __restrict__ We, const float* __restrict__ Wv,
                       const float* __restrict__ Wo, const float* __restrict__ W2,
                       const float* __restrict__ Wh, const float* __restrict__ Wf,
                       const float* __restrict__ W1, const float* __restrict__ Wa,
                       __bf16* __restrict__ pw){
  int gid = blockIdx.x*256 + threadIdx.x;
  if (gid < 4096){
    int c=gid>>6, k=gid&63;
    pw[PW_We+gid] = (k<ECH) ? (__bf16)We[(size_t)k*64+c] : (__bf16)0.f;
  } else if (gid < 8192){
    int g=gid-4096; int c=g>>6, k=g&63;
    pw[PW_Wv+g] = (__bf16)Wv[(size_t)k*64+c];
  } else if (gid < 12288){
    int g=gid-8192; int c=g>>6, k=g&63;
    pw[PW_Wo+g] = (__bf16)Wo[(size_t)k*64+c];
  } else if (gid < 16384){
    int g=gid-12288; int j=g>>6, k=g&63;
    pw[PW_W2+g] = (j<ECH && k<ECH) ? (__bf16)W2[(size_t)k*ECH+j] : (__bf16)0.f;
  } else if (gid < 24576){
    int g=gid-16384; int n=g>>6, k=g&63;
    pw[PW_Wh+g] = (__bf16)Wh[(size_t)k*128+n];
  } else if (gid < 32768){
    int g=gid-24576; int j=g>>7, k=g&127;
    pw[PW_Wf+g] = (__bf16)Wf[(size_t)k*64+j];
  } else if (gid < 45056){
    int g=gid-32768; int j=g>>8, k=g&255;
    pw[PW_W1+g] = (__bf16)W1[(size_t)k*ECH+j];
  } else if (gid < PW_TOTAL){
    int g=gid-45056; int j=g>>6, k=g&63;
    pw[PW_Wa+g] = (__bf16)Wa[(size_t)k*256+j];
  }
}

// ---------- fused weights (transposed bf16 out) + zero deg/cursor (grid 32x256) ----------
__global__ void k_fusew(const float* __restrict__ Wsrc, const float* __restrict__ Wdst,
                        const float* __restrict__ Wv,
                        __bf16* __restrict__ wsvT, __bf16* __restrict__ wdvT,
                        int* __restrict__ deg, int* __restrict__ cursor){
  int gid = blockIdx.x*256 + threadIdx.x;
  if (gid < NN){ deg[gid]=0; cursor[gid]=0; }
  int which = gid >> 12;
  int idx = gid & 4095;
  int r = idx >> 6, c = idx & 63;
  const float* A = which ? Wdst : Wsrc;
  float acc = 0.0f;
  #pragma unroll
  for (int k=0;k<64;k++) acc += A[r*64+k]*Wv[k*64+c];
  (which ? wdvT : wsvT)[c*64+r] = (__bf16)acc;   // store transposed [c][k]
}

// ---------- fused pre: rms + xs0/xd0 + vs/vd MFMA. 4 nodes/block, grid 2000x256 ----------
__global__ void __launch_bounds__(256) k_pre(const float* __restrict__ x,
                        const float* __restrict__ Wsrc, const float* __restrict__ Wdst,
                        const __bf16* __restrict__ wsvT, const __bf16* __restrict__ wdvT,
                        float* __restrict__ xs0, float* __restrict__ xd0,
                        __bf16* __restrict__ vs, __bf16* __restrict__ vd){
  __shared__ __bf16 xbuf[64*72];   // 4 nodes x 16 l rows, rms-scaled bf16
  __shared__ float  xl0[4][64];    // fp32 l=0 rows (unscaled)
  __shared__ __bf16 wsb[64*72];    // wsvT [c][k]
  __shared__ __bf16 wdb[64*72];
  __shared__ float  red[16];       // [wave][q]
  int tid = threadIdx.x;
  int w = tid>>6, l = tid&63, lr = l&15, lg = l>>4;
  int n0 = blockIdx.x*4;
  const float4* xp = (const float4*)(x + (size_t)n0*1024);

  float4 v[4]; float ssq[4];
  #pragma unroll
  for (int q=0;q<4;q++){
    v[q] = xp[tid + q*256];
    ssq[q] = v[q].x*v[q].x + v[q].y*v[q].y + v[q].z*v[q].z + v[q].w*v[q].w;
  }
  #pragma unroll
  for (int q=0;q<4;q++){
    #pragma unroll
    for (int m=32;m>=1;m>>=1) ssq[q] += __shfl_xor(ssq[q], m);
  }
  if (l==0){
    #pragma unroll
    for (int q=0;q<4;q++) red[w*4+q] = ssq[q];
  }
  for (int i=tid;i<512;i+=256){
    int row=i>>3, k8=(i&7)*8;
    *(bf16x8*)&wsb[row*72+k8] = *(const bf16x8*)(wsvT + row*64 + k8);
    *(bf16x8*)&wdb[row*72+k8] = *(const bf16x8*)(wdvT + row*64 + k8);
  }
  if (tid < 16){
    #pragma unroll
    for (int q=0;q<4;q++){
      float4 t = v[q];
      float* p = &xl0[q][(tid&15)*4];
      p[0]=t.x; p[1]=t.y; p[2]=t.z; p[3]=t.w;
    }
  }
  __syncthreads();
  float scl[4];
  #pragma unroll
  for (int q=0;q<4;q++)
    scl[q] = 1.0f/sqrtf((red[q]+red[4+q]+red[8+q]+red[12+q])*(1.0f/1024.0f)+1e-6f);
  {
    int r = tid>>4, k4 = (tid&15)*4;
    #pragma unroll
    for (int q=0;q<4;q++){
      float s = scl[q];
      bf16x4 t = {(__bf16)(v[q].x*s),(__bf16)(v[q].y*s),(__bf16)(v[q].z*s),(__bf16)(v[q].w*s)};
      *(bf16x4*)&xbuf[(q*16+r)*72 + k4] = t;
    }
  }
  __syncthreads();

  {
    int nd = w, c = l;
    float s = scl[nd];
    float as=0.f, ad=0.f;
    #pragma unroll 8
    for (int k=0;k<64;k++){
      float xv = xl0[nd][k]*s;
      as += xv*Wsrc[k*64+c];
      ad += xv*Wdst[k*64+c];
    }
    xs0[(size_t)(n0+nd)*64 + c] = as;
    xd0[(size_t)(n0+nd)*64 + c] = ad;
  }

  {
    bf16x8 a0 = *(const bf16x8*)&xbuf[(w*16+lr)*72 + lg*8];
    bf16x8 a1 = *(const bf16x8*)&xbuf[(w*16+lr)*72 + 32 + lg*8];
    #pragma unroll
    for (int nt=0;nt<4;nt++){
      f32x4 os = (f32x4){0.f,0.f,0.f,0.f};
      f32x4 od = (f32x4){0.f,0.f,0.f,0.f};
      bf16x8 bs0 = *(const bf16x8*)&wsb[(nt*16+lr)*72 + lg*8];
      bf16x8 bs1 = *(const bf16x8*)&wsb[(nt*16+lr)*72 + 32 + lg*8];
      bf16x8 bd0 = *(const bf16x8*)&wdb[(nt*16+lr)*72 + lg*8];
      bf16x8 bd1 = *(const bf16x8*)&wdb[(nt*16+lr)*72 + 32 + lg*8];
      os = __builtin_amdgcn_mfma_f32_16x16x32_bf16(a0, bs0, os, 0, 0, 0);
      os = __builtin_amdgcn_mfma_f32_16x16x32_bf16(a1, bs1, os, 0, 0, 0);
      od = __builtin_amdgcn_mfma_f32_16x16x32_bf16(a0, bd0, od, 0, 0, 0);
      od = __builtin_amdgcn_mfma_f32_16x16x32_bf16(a1, bd1, od, 0, 0, 0);
      #pragma unroll
      for (int r=0;r<4;r++){
        size_t row = (size_t)(n0+w)*16 + lg*4 + r;
        vs[row*64 + nt*16 + lr] = (__bf16)os[r];
        vd[row*64 + nt*16 + lr] = (__bf16)od[r];
      }
    }
  }
}

// ---------- edge RBF + 2-layer MLP via MFMA + hist: 128 edges/block, 512 thr, grid 750 ----------
__global__ void __launch_bounds__(512) k_edgeA(const float* __restrict__ pos, const int* __restrict__ ei,
                        const __bf16* __restrict__ pw,
                        const float* __restrict__ b1, const float* __restrict__ b2,
                        __bf16* __restrict__ e2g, int* __restrict__ deg){
  __shared__ __bf16 W1T[48*264];   // 25344B [j][k] stride 264
  __shared__ __bf16 W2T[64*72];    // 9216B  [j][k] stride 72 (k>=48 zero)
  __shared__ __bf16 e1s[128*72];   // 18432B [edge][k] stride 72 (k>=48 zeroed)
  __shared__ float dl[128], envl[128];
  int tid = threadIdx.x;
  int w = tid>>6, l = tid&63, lr = l&15, lg = l>>4;
  int eb = blockIdx.x*128;

  if (tid < 128){
    int s = ei[eb+tid], t = ei[EE+eb+tid];
    float dx = pos[3*s]-pos[3*t], dy = pos[3*s+1]-pos[3*t+1], dz = pos[3*s+2]-pos[3*t+2];
    float d = sqrtf(dx*dx+dy*dy+dz*dz+1e-12f);
    dl[tid] = d;
    envl[tid] = 0.5f*(cosf(PI_F*fminf(d*(1.0f/CUTOFF_R),1.0f))+1.0f);
    atomicAdd(&deg[t], 1);   // folded k_hist
  }
  for (int i=tid;i<1536;i+=512){
    int row=i>>5, k8=(i&31)*8;
    *(bf16x8*)&W1T[row*264+k8] = *(const bf16x8*)(pw + PW_W1 + row*256 + k8);
  }
  {
    int row=tid>>3, k8=(tid&7)*8;
    *(bf16x8*)&W2T[row*72+k8] = *(const bf16x8*)(pw + PW_W2 + row*64 + k8);
  }
  for (int i=tid;i<2048;i+=512){
    int r=i>>4, c=48+(i&15);
    e1s[r*72+c] = (__bf16)0.f;
  }
  __syncthreads();

  float d  = dl[w*16+lr];
  float ev = envl[w*16+lr];
  f32x4 acc[3];
  #pragma unroll
  for (int nt=0;nt<3;nt++) acc[nt] = (f32x4){0.f,0.f,0.f,0.f};
  #pragma unroll
  for (int c=0;c<8;c++){
    bf16x8 af;
    #pragma unroll
    for (int j=0;j<8;j++){
      float kk = (float)(c*32 + lg*8 + j);
      float del = (d - kk*SPACING)*INV_STD;
      af[j] = (__bf16)(exp2f(-0.72134752f*del*del)*ev);
    }
    #pragma unroll
    for (int nt=0;nt<3;nt++){
      bf16x8 bf_ = *(const bf16x8*)&W1T[(nt*16+lr)*264 + c*32 + lg*8];
      acc[nt] = __builtin_amdgcn_mfma_f32_16x16x32_bf16(af, bf_, acc[nt], 0, 0, 0);
    }
  }
  #pragma unroll
  for (int nt=0;nt<3;nt++){
    int col = nt*16+lr;
    float bb = b1[col];
    #pragma unroll
    for (int r=0;r<4;r++){
      int row = w*16 + lg*4 + r;
      e1s[row*72+col] = (__bf16)silu_f(acc[nt][r] + bb);
    }
  }
  __syncthreads();

  bf16x8 a0 = *(const bf16x8*)&e1s[(w*16+lr)*72 + lg*8];
  bf16x8 a1 = *(const bf16x8*)&e1s[(w*16+lr)*72 + 32 + lg*8];
  #pragma unroll
  for (int nt=0;nt<3;nt++){
    f32x4 o = (f32x4){0.f,0.f,0.f,0.f};
    bf16x8 b0 = *(const bf16x8*)&W2T[(nt*16+lr)*72 + lg*8];
    bf16x8 b1f= *(const bf16x8*)&W2T[(nt*16+lr)*72 + 32 + lg*8];
    o = __builtin_amdgcn_mfma_f32_16x16x32_bf16(a0, b0, o, 0, 0, 0);
    o = __builtin_amdgcn_mfma_f32_16x16x32_bf16(a1, b1f, o, 0, 0, 0);
    int col = nt*16+lr;
    float bb = b2[col];
    #pragma unroll
    for (int r=0;r<4;r++){
      int row = w*16 + lg*4 + r;
      e2g[(size_t)(eb+row)*ECH + col] = (__bf16)silu_f(o[r] + bb);
    }
  }
}

// ---------- CSR scan ----------
__global__ void __launch_bounds__(1024) k_scan(const int* __restrict__ deg, int* __restrict__ off){
  __shared__ int sums[1024];
  int t = threadIdx.x;
  int base = t*8;
  int loc[8]; int s=0;
  #pragma unroll
  for (int i=0;i<8;i++){ int idx=base+i; int v = (idx<NN)? deg[idx]:0; loc[i]=v; s+=v; }
  sums[t]=s;
  __syncthreads();
  for (int d=1; d<1024; d<<=1){
    int v = (t>=d)? sums[t-d]:0;
    __syncthreads();
    sums[t] += v;
    __syncthreads();
  }
  int run = sums[t]-s;
  #pragma unroll
  for (int i=0;i<8;i++){ int idx=base+i; if (idx<NN) off[idx]=run; run+=loc[i]; }
  if (t==1023) off[NN]=sums[1023];
}

// ---------- per-edge MFMA + csr fill: 128 edges/block, 512 thr, grid 750 ----------
__global__ void __launch_bounds__(512) k_edgeB(const __bf16* __restrict__ e2g, const int* __restrict__ ei,
                        const float* __restrict__ xs0, const float* __restrict__ xd0,
                        const __bf16* __restrict__ pw, const float* __restrict__ v_alpha,
                        const int* __restrict__ off, int* __restrict__ cursor, int* __restrict__ csr,
                        float* __restrict__ logits_g, __bf16* __restrict__ v0g){
  __shared__ __bf16 e2s[128*72];   // 18432B
  __shared__ __bf16 s0s[128*72];   // 18432B
  __shared__ __bf16 wbuf[128*72];  // 18432B: We -> Wa.h0 -> Wa.h1 -> Wv
  __shared__ float  va_l[256];
  __shared__ int    srcd[256];     // [0:128) src, [128:256) dst
  int tid = threadIdx.x;
  int w = tid >> 6, l = tid & 63;
  int lr = l & 15, lg = l >> 4;
  int eb = blockIdx.x * 128;

  for (int i=tid;i<8192;i+=512){
    int r=i>>6, k=i&63;
    e2s[r*72+k] = (k<ECH) ? e2g[(size_t)(eb+r)*ECH+k] : (__bf16)0.f;
  }
  {
    int row=tid>>3, k8=(tid&7)*8;
    *(bf16x8*)&wbuf[row*72+k8] = *(const bf16x8*)(pw + PW_We + row*64 + k8);
  }
  if (tid<256) va_l[tid] = v_alpha[tid];
  if (tid<128){
    int sI = ei[eb+tid], dI = ei[EE+eb+tid];
    srcd[tid]=sI; srcd[128+tid]=dI;
    int slot = off[dI] + atomicAdd(&cursor[dI],1);   // folded k_fill
    csr[slot] = eb + tid;
  }
  __syncthreads();

  bf16x8 ea0 = *(const bf16x8*)&e2s[(w*16+lr)*72 + lg*8];
  bf16x8 ea1 = *(const bf16x8*)&e2s[(w*16+lr)*72 + 32 + lg*8];
  f32x4 sacc[4];
  #pragma unroll
  for (int nt=0;nt<4;nt++){
    sacc[nt] = (f32x4){0.f,0.f,0.f,0.f};
    bf16x8 b0 = *(const bf16x8*)&wbuf[(nt*16+lr)*72 + lg*8];
    bf16x8 b1 = *(const bf16x8*)&wbuf[(nt*16+lr)*72 + 32 + lg*8];
    sacc[nt] = __builtin_amdgcn_mfma_f32_16x16x32_bf16(ea0, b0, sacc[nt], 0, 0, 0);
    sacc[nt] = __builtin_amdgcn_mfma_f32_16x16x32_bf16(ea1, b1, sacc[nt], 0, 0, 0);
  }
  #pragma unroll
  for (int reg=0;reg<4;reg++){
    int localrow = w*16 + lg*4 + reg;
    int sI = srcd[localrow], dI = srcd[128+localrow];
    #pragma unroll
    for (int nt=0;nt<4;nt++){
      int col = nt*16 + lr;
      float m = xs0[(size_t)sI*64+col] + xd0[(size_t)dI*64+col];
      s0s[localrow*72+col] = (__bf16)(sacc[nt][reg]*m);
    }
  }
  __syncthreads();

  bf16x8 sa0 = *(const bf16x8*)&s0s[(w*16+lr)*72 + lg*8];
  bf16x8 sa1 = *(const bf16x8*)&s0s[(w*16+lr)*72 + 32 + lg*8];

  #pragma unroll
  for (int half=0;half<2;half++){
    for (int i=tid;i<1024;i+=512){
      int row=i>>3, k8=(i&7)*8;   // row in [0,128)
      *(bf16x8*)&wbuf[row*72+k8] = *(const bf16x8*)(pw + PW_Wa + (half*128+row)*64 + k8);
    }
    __syncthreads();
    float lg0[4]={0.f,0.f,0.f,0.f}, lg1[4]={0.f,0.f,0.f,0.f};
    #pragma unroll
    for (int nt=0;nt<8;nt++){
      f32x4 tacc = (f32x4){0.f,0.f,0.f,0.f};
      bf16x8 b0 = *(const bf16x8*)&wbuf[(nt*16+lr)*72 + lg*8];
      bf16x8 b1 = *(const bf16x8*)&wbuf[(nt*16+lr)*72 + 32 + lg*8];
      tacc = __builtin_amdgcn_mfma_f32_16x16x32_bf16(sa0, b0, tacc, 0, 0, 0);
      tacc = __builtin_amdgcn_mfma_f32_16x16x32_bf16(sa1, b1, tacc, 0, 0, 0);
      int gj = half*128 + nt*16 + lr;
      float vaj = va_l[gj];
      #pragma unroll
      for (int reg=0;reg<4;reg++){
        float t = tacc[reg];
        t = (t>0.0f) ? t : 0.2f*t;
        if (nt<4) lg0[reg] += t*vaj; else lg1[reg] += t*vaj;
      }
    }
    #pragma unroll
    for (int reg=0;reg<4;reg++){
      #pragma unroll
      for (int m=1;m<16;m<<=1){
        lg0[reg] += __shfl_xor(lg0[reg], m);
        lg1[reg] += __shfl_xor(lg1[reg], m);
      }
    }
    if (lr==0){
      #pragma unroll
      for (int reg=0;reg<4;reg++){
        int e = eb + w*16 + lg*4 + reg;
        logits_g[(size_t)e*4 + half*2 + 0] = lg0[reg];
        logits_g[(size_t)e*4 + half*2 + 1] = lg1[reg];
      }
    }
    __syncthreads();
  }

  {
    int row=tid>>3, k8=(tid&7)*8;
    *(bf16x8*)&wbuf[row*72+k8] = *(const bf16x8*)(pw + PW_Wv + row*64 + k8);
  }
  __syncthreads();
  #pragma unroll
  for (int nt=0;nt<4;nt++){
    f32x4 vacc = (f32x4){0.f,0.f,0.f,0.f};
    bf16x8 b0 = *(const bf16x8*)&wbuf[(nt*16+lr)*72 + lg*8];
    bf16x8 b1 = *(const bf16x8*)&wbuf[(nt*16+lr)*72 + 32 + lg*8];
    vacc = __builtin_amdgcn_mfma_f32_16x16x32_bf16(sa0, b0, vacc, 0, 0, 0);
    vacc = __builtin_amdgcn_mfma_f32_16x16x32_bf16(sa1, b1, vacc, 0, 0, 0);
    #pragma unroll
    for (int reg=0;reg<4;reg++){
      int e = eb + w*16 + lg*4 + reg;
      v0g[(size_t)e*64 + nt*16 + lr] = (__bf16)vacc[reg];
    }
  }
}

// ---------- gather-only: softmax + bf16 gather -> agg (1 node/block, grid 8000) ----------
__global__ void __launch_bounds__(256) k_gather(const int* __restrict__ off, const int* __restrict__ csr,
                       const int* __restrict__ ei,
                       const float* __restrict__ logits_g, const __bf16* __restrict__ v0g,
                       const __bf16* __restrict__ vs, const __bf16* __restrict__ vd,
                       __bf16* __restrict__ agg){
  __shared__ float alph[MAXDEG*HH];
  __shared__ int   eidl[MAXDEG];
  __shared__ int   srcl[MAXDEG];
  __shared__ float salpha[HH];
  int tid = threadIdx.x;
  int n = blockIdx.x;
  int o0 = off[n];
  int deg = off[n+1]-o0;
  if (deg > MAXDEG) deg = MAXDEG;
  if (tid < deg){
    int e = csr[o0+tid];
    eidl[tid]=e;
    srcl[tid]=ei[e];
    float4 lgv = *(const float4*)(logits_g + (size_t)e*4);
    float* ap = &alph[tid*4];
    ap[0]=lgv.x; ap[1]=lgv.y; ap[2]=lgv.z; ap[3]=lgv.w;
  }
  __syncthreads();
  if (tid < 64){
    int h = tid>>4, i0 = tid&15;
    float m = -1e30f;
    for (int i=i0;i<deg;i+=16) m = fmaxf(m, alph[i*4+h]);
    #pragma unroll
    for (int s=1;s<16;s<<=1) m = fmaxf(m, __shfl_xor(m, s));
    float ds = 0.0f;
    for (int i=i0;i<deg;i+=16){
      float wv = expf(alph[i*4+h]-m);
      alph[i*4+h]=wv; ds += wv;
    }
    #pragma unroll
    for (int s=1;s<16;s<<=1) ds += __shfl_xor(ds, s);
    float inv = 1.0f/(ds+1e-9f);
    for (int i=i0;i<deg;i+=16) alph[i*4+h] *= inv;
    if (i0==0) salpha[h] = ds*inv;
  }
  __syncthreads();
  {
    int l = tid>>4, quad = tid&15;
    int h = quad>>2;
    float a0=0.f,a1=0.f,a2=0.f,a3=0.f;
    if (l==0){
      int i=0;
      for (;i+1<deg;i+=2){
        float aA = alph[i*4+h], aB = alph[(i+1)*4+h];
        bf16x4 vA = *(const bf16x4*)(v0g + (size_t)eidl[i]*64 + quad*4);
        bf16x4 vB = *(const bf16x4*)(v0g + (size_t)eidl[i+1]*64 + quad*4);
        a0 += aA*(float)vA[0] + aB*(float)vB[0];
        a1 += aA*(float)vA[1] + aB*(float)vB[1];
        a2 += aA*(float)vA[2] + aB*(float)vB[2];
        a3 += aA*(float)vA[3] + aB*(float)vB[3];
      }
      if (i<deg){
        float a = alph[i*4+h];
        bf16x4 vv = *(const bf16x4*)(v0g + (size_t)eidl[i]*64 + quad*4);
        a0 += a*(float)vv[0]; a1 += a*(float)vv[1]; a2 += a*(float)vv[2]; a3 += a*(float)vv[3];
      }
    } else {
      int i=0;
      for (;i+1<deg;i+=2){
        float aA = alph[i*4+h], aB = alph[(i+1)*4+h];
        bf16x4 vA = *(const bf16x4*)(vs + (size_t)srcl[i]*1024 + tid*4);
        bf16x4 vB = *(const bf16x4*)(vs + (size_t)srcl[i+1]*1024 + tid*4);
        a0 += aA*(float)vA[0] + aB*(float)vB[0];
        a1 += aA*(float)vA[1] + aB*(float)vB[1];
        a2 += aA*(float)vA[2] + aB*(float)vB[2];
        a3 += aA*(float)vA[3] + aB*(float)vB[3];
      }
      if (i<deg){
        float a = alph[i*4+h];
        bf16x4 vv = *(const bf16x4*)(vs + (size_t)srcl[i]*1024 + tid*4);
        a0 += a*(float)vv[0]; a1 += a*(float)vv[1]; a2 += a*(float)vv[2]; a3 += a*(float)vv[3];
      }
      float sa = salpha[h];
      bf16x4 vv = *(const bf16x4*)(vd + (size_t)n*1024 + tid*4);
      a0 += sa*(float)vv[0]; a1 += sa*(float)vv[1]; a2 += sa*(float)vv[2]; a3 += sa*(float)vv[3];
    }
    bf16x4 t = {(__bf16)a0,(__bf16)a1,(__bf16)a2,(__bf16)a3};
    *(bf16x4*)(agg + (size_t)n*1024 + tid*4) = t;
  }
}

// ---------- Wo + residual + rms + gated FFN + out. 8 nodes/block, 512 thr, grid 1000 ----------
__global__ void __launch_bounds__(512) k_woffn(const __bf16* __restrict__ agg,
                       const float* __restrict__ x, const __bf16* __restrict__ pw,
                       const float* __restrict__ Wg, float* __restrict__ out){
  __shared__ __bf16 wbuf[64*72];         // 9216B: WoT -> WhT.h -> WfT.h (rotating)
  __shared__ __bf16 aggyb[128*72];       // 18432B: agg -> ybuf (8 nodes x 16 rows)
  __shared__ __bf16 hbuf[128*72];        // 18432B
  __shared__ float  gl[1024];            // 4096B (8 nodes x 128)
  int tid = threadIdx.x;
  int w = tid>>6, lane = tid&63, lr = lane&15, lg = lane>>4;
  int n0 = blockIdx.x*8;

  // ---- T14-style prefetch: issue x loads first ----
  const float* xr = x + (size_t)(n0+w)*1024;
  float xv[16];
  #pragma unroll
  for (int nt=0;nt<4;nt++){
    #pragma unroll
    for (int r=0;r<4;r++){
      xv[nt*4+r] = xr[(lg*4+r)*64 + nt*16 + lr];
    }
  }

  // ---- phase 1: stage WoT + load agg tile (8 nodes) ----
  {
    int row=tid>>3, k8=(tid&7)*8;
    if (tid < 512) *(bf16x8*)&wbuf[row*72+k8] = *(const bf16x8*)(pw + PW_Wo + row*64 + k8);
  }
  for (int i=tid;i<1024;i+=512){
    bf16x8 v = *(const bf16x8*)(agg + (size_t)n0*1024 + i*8);
    *(bf16x8*)&aggyb[(i>>3)*72 + (i&7)*8] = v;
  }
  __syncthreads();

  // ---- phase 2: x1 = x + agg@Wo (regs); rms (wave-local) ----
  f32x4 x1r[4];
  float scl_w;
  {
    bf16x8 a0 = *(const bf16x8*)&aggyb[(w*16+lr)*72 + lg*8];
    bf16x8 a1 = *(const bf16x8*)&aggyb[(w*16+lr)*72 + 32 + lg*8];
    float ss = 0.0f;
    #pragma unroll
    for (int nt=0;nt<4;nt++){
      f32x4 o = (f32x4){0.f,0.f,0.f,0.f};
      bf16x8 b0 = *(const bf16x8*)&wbuf[(nt*16+lr)*72 + lg*8];
      bf16x8 b1 = *(const bf16x8*)&wbuf[(nt*16+lr)*72 + 32 + lg*8];
      o = __builtin_amdgcn_mfma_f32_16x16x32_bf16(a0, b0, o, 0, 0, 0);
      o = __builtin_amdgcn_mfma_f32_16x16x32_bf16(a1, b1, o, 0, 0, 0);
      #pragma unroll
      for (int r=0;r<4;r++){
        float xvv = xv[nt*4+r] + o[r];
        o[r] = xvv;
        ss += xvv*xvv;
      }
      x1r[nt] = o;
    }
    #pragma unroll
    for (int m=32;m>=1;m>>=1) ss += __shfl_xor(ss, m);
    scl_w = 1.0f/sqrtf(ss*(1.0f/1024.0f)+1e-6f);
  }
  __syncthreads();   // aggyb + wbuf consumed

  // ---- phase 3: ybuf = bf16(x1*scl) into aggyb ----
  #pragma unroll
  for (int nt=0;nt<4;nt++){
    #pragma unroll
    for (int r=0;r<4;r++){
      aggyb[(w*16+lg*4+r)*72 + nt*16+lr] = (__bf16)(x1r[nt][r]*scl_w);
    }
  }
  __syncthreads();

  // ---- phase 3b: gate (8 nodes x 128 cols, 2 per thread) ----
  {
    int c = tid&127, grp = tid>>7;   // grp 0..3
    #pragma unroll
    for (int q=0;q<2;q++){
      int nd = grp*2+q;
      float acc = 0.0f;
      #pragma unroll 8
      for (int k=0;k<64;k++) acc += (float)aggyb[(nd*16)*72 + k] * Wg[k*128+c];
      gl[nd*128+c] = silu_f(acc);
    }
  }

  // ---- phases 4-5: FFN in two halves ----
  f32x4 o2[4];
  #pragma unroll
  for (int nt=0;nt<4;nt++) o2[nt] = (f32x4){0.f,0.f,0.f,0.f};
  #pragma unroll
  for (int hf=0; hf<2; hf++){
    __syncthreads();   // gl ready (hf=0) / prior wbuf reads done (hf=1)
    {
      int row=tid>>3, k8=(tid&7)*8;
      *(bf16x8*)&wbuf[row*72+k8] = *(const bf16x8*)(pw + PW_Wh + (hf*64+row)*64 + k8);
    }
    __syncthreads();
    {
      bf16x8 a0 = *(const bf16x8*)&aggyb[(w*16+lr)*72 + lg*8];
      bf16x8 a1 = *(const bf16x8*)&aggyb[(w*16+lr)*72 + 32 + lg*8];
      #pragma unroll
      for (int nt=0;nt<4;nt++){
        f32x4 o = (f32x4){0.f,0.f,0.f,0.f};
        bf16x8 b0 = *(const bf16x8*)&wbuf[(nt*16+lr)*72 + lg*8];
        bf16x8 b1 = *(const bf16x8*)&wbuf[(nt*16+lr)*72 + 32 + lg*8];
        o = __builtin_amdgcn_mfma_f32_16x16x32_bf16(a0, b0, o, 0, 0, 0);
        o = __builtin_amdgcn_mfma_f32_16x16x32_bf16(a1, b1, o, 0, 0, 0);
        int col = nt*16+lr;
        float g = gl[w*128 + hf*64 + col];
        #pragma unroll
        for (int r=0;r<4;r++){
          hbuf[(w*16+lg*4+r)*72 + col] = (__bf16)(o[r]*g);
        }
      }
    }
    __syncthreads();
    {
      int row=tid>>3, k8=(tid&7)*8;
      *(bf16x8*)&wbuf[row*72+k8] = *(const bf16x8*)(pw + PW_Wf + row*128 + hf*64 + k8);
    }
    __syncthreads();
    {
      bf16x8 a0 = *(const bf16x8*)&hbuf[(w*16+lr)*72 + lg*8];
      bf16x8 a1 = *(const bf16x8*)&hbuf[(w*16+lr)*72 + 32 + lg*8];
      #pragma unroll
      for (int nt=0;nt<4;nt++){
        bf16x8 b0 = *(const bf16x8*)&wbuf[(nt*16+lr)*72 + lg*8];
        bf16x8 b1 = *(const bf16x8*)&wbuf[(nt*16+lr)*72 + 32 + lg*8];
        o2[nt] = __builtin_amdgcn_mfma_f32_16x16x32_bf16(a0, b0, o2[nt], 0, 0, 0);
        o2[nt] = __builtin_amdgcn_mfma_f32_16x16x32_bf16(a1, b1, o2[nt], 0, 0, 0);
      }
    }
  }

  // ---- final store: out = x1 + o2 ----
  {
    float* outr = out + (size_t)(n0+w)*1024;
    #pragma unroll
    for (int nt=0;nt<4;nt++){
      #pragma unroll
      for (int r=0;r<4;r++){
        outr[(lg*4+r)*64 + nt*16+lr] = x1r[nt][r] + o2[nt][r];
      }
    }
  }
}

extern "C" void kernel_launch(void* const* d_in, const int* in_sizes, int n_in,
                              void* d_out, int out_size, void* d_ws, size_t ws_size,
                              hipStream_t stream) {
  (void)in_sizes; (void)n_in; (void)out_size; (void)ws_size;
  const float* pos = (const float*)d_in[0];
  const float* x   = (const float*)d_in[1];
  const float* Wsrc= (const float*)d_in[2];
  const float* Wdst= (const float*)d_in[3];
  const float* W1  = (const float*)d_in[4];
  const float* b1  = (const float*)d_in[5];
  const float* W2  = (const float*)d_in[6];
  const float* b2  = (const float*)d_in[7];
  const float* We  = (const float*)d_in[8];
  const float* Wa  = (const float*)d_in[9];
  const float* va  = (const float*)d_in[10];
  const float* Wv  = (const float*)d_in[11];
  const float* Wo  = (const float*)d_in[12];
  const float* Wg  = (const float*)d_in[13];
  const float* Wh  = (const float*)d_in[14];
  const float* Wf  = (const float*)d_in[15];
  const int*   ei  = (const int*)d_in[16];
  float* out = (float*)d_out;

  char* wp = (char*)d_ws;
  auto alloc = [&](size_t bytes)->char*{
    char* p = wp;
    wp += ((bytes + 255)/256)*256;
    return p;
  };
  __bf16* pwb  = (__bf16*)alloc((size_t)PW_TOTAL*2);
  __bf16* wsvT = (__bf16*)alloc(4096*2);
  __bf16* wdvT = (__bf16*)alloc(4096*2);
  float* xs0  = (float*)alloc((size_t)NN*64*4);
  float* xd0  = (float*)alloc((size_t)NN*64*4);
  __bf16* vs  = (__bf16*)alloc((size_t)NN*1024*2);
  __bf16* vd  = (__bf16*)alloc((size_t)NN*1024*2);
  __bf16* agg = (__bf16*)alloc((size_t)NN*1024*2);
  __bf16* e2g = (__bf16*)alloc((size_t)EE*ECH*2);
  __bf16* v0g = (__bf16*)alloc((size_t)EE*64*2);
  float* lgts = (float*)alloc((size_t)EE*HH*4);
  int* deg    = (int*)alloc((size_t)NN*4);
  int* cursor = (int*)alloc((size_t)NN*4);
  int* off    = (int*)alloc((size_t)(NN+1)*4);
  int* csr    = (int*)alloc((size_t)EE*4);

  k_prep<<<PW_TOTAL/256,256,0,stream>>>(We,Wv,Wo,W2,Wh,Wf,W1,Wa,pwb);
  k_fusew<<<32,256,0,stream>>>(Wsrc,Wdst,Wv,wsvT,wdvT,deg,cursor);
  k_pre<<<NN/4,256,0,stream>>>(x,Wsrc,Wdst,wsvT,wdvT,xs0,xd0,vs,vd);
  k_edgeA<<<EE/128,512,0,stream>>>(pos,ei,pwb,b1,b2,e2g,deg);
  k_scan<<<1,1024,0,stream>>>(deg,off);
  k_edgeB<<<EE/128,512,0,stream>>>(e2g,ei,xs0,xd0,pwb,va,off,cursor,csr,lgts,v0g);
  k_gather<<<NN,256,0,stream>>>(off,csr,ei,lgts,v0g,vs,vd,agg);
  k_woffn<<<NN/8,512,0,stream>>>(agg,x,pwb,Wg,out);
}

// Round 17
// 159.213 us; speedup vs baseline: 1.3941x; 1.0368x over previous
//
#include <hip/hip_runtime.h>
#include <hip/hip_fp8.h>
#include <math.h>

// Problem constants (match reference file)
#define NN 8000
#define EE 96000
#define HH 4
#define NBASIS 256
#define ECH 48
#define FFNH 128
#define CUTOFF_R 0.0792f
#define PI_F 3.14159265358979323846f
#define SPACING (CUTOFF_R/255.0f)
#define INV_STD (256.0f/CUTOFF_R)
#define MAXDEG 48

typedef __bf16 bf16x8 __attribute__((ext_vector_type(8)));
typedef __bf16 bf16x4 __attribute__((ext_vector_type(4)));
typedef __bf16 bf16x2 __attribute__((ext_vector_type(2)));
typedef float  f32x4  __attribute__((ext_vector_type(4)));

__device__ __forceinline__ float silu_f(float x){ return x/(1.0f+expf(-x)); }

__device__ __forceinline__ unsigned char ff8(float v){
  __hip_fp8_e4m3 t(v); return (unsigned char)t.__x;
}
__device__ __forceinline__ float f8f(unsigned char b){
  __hip_fp8_e4m3 t; t.__x = (__hip_fp8_storage_t)b; return (float)t;
}

// prepw layout (bf16 elements):
#define PW_We 0
#define PW_Wv 4096
#define PW_Wo 8192
#define PW_W2 12288
#define PW_Wh 16384
#define PW_Wf 24576
#define PW_W1 32768
#define PW_Wa 45056
#define PW_TOTAL 61440

// ---------- prep: all weights -> bf16 transposed (grid 240x256) ----------
__global__ void k_prep(const float* __restrict__ We, const float* __restrict__ Wv,
                       const float* __restrict__ Wo, const float* __restrict__ W2,
                       const float* __restrict__ Wh, const float* __restrict__ Wf,
                       const float* __restrict__ W1, const float* __restrict__ Wa,
                       __bf16* __restrict__ pw){
  int gid = blockIdx.x*256 + threadIdx.x;
  if (gid < 4096){
    int c=gid>>6, k=gid&63;
    pw[PW_We+gid] = (k<ECH) ? (__bf16)We[(size_t)k*64+c] : (__bf16)0.f;
  } else if (gid < 8192){
    int g=gid-4096; int c=g>>6, k=g&63;
    pw[PW_Wv+g] = (__bf16)Wv[(size_t)k*64+c];
  } else if (gid < 12288){
    int g=gid-8192; int c=g>>6, k=g&63;
    pw[PW_Wo+g] = (__bf16)Wo[(size_t)k*64+c];
  } else if (gid < 16384){
    int g=gid-12288; int j=g>>6, k=g&63;
    pw[PW_W2+g] = (j<ECH && k<ECH) ? (__bf16)W2[(size_t)k*ECH+j] : (__bf16)0.f;
  } else if (gid < 24576){
    int g=gid-16384; int n=g>>6, k=g&63;
    pw[PW_Wh+g] = (__bf16)Wh[(size_t)k*128+n];
  } else if (gid < 32768){
    int g=gid-24576; int j=g>>7, k=g&127;
    pw[PW_Wf+g] = (__bf16)Wf[(size_t)k*64+j];
  } else if (gid < 45056){
    int g=gid-32768; int j=g>>8, k=g&255;
    pw[PW_W1+g] = (__bf16)W1[(size_t)k*ECH+j];
  } else if (gid < PW_TOTAL){
    int g=gid-45056; int j=g>>6, k=g&63;
    pw[PW_Wa+g] = (__bf16)Wa[(size_t)k*256+j];
  }
}

// ---------- fused weights (transposed bf16 out) + zero deg/cursor (grid 32x256) ----------
__global__ void k_fusew(const float* __restrict__ Wsrc, const float* __restrict__ Wdst,
                        const float* __restrict__ Wv,
                        __bf16* __restrict__ wsvT, __bf16* __restrict__ wdvT,
                        int* __restrict__ deg, int* __restrict__ cursor){
  int gid = blockIdx.x*256 + threadIdx.x;
  if (gid < NN){ deg[gid]=0; cursor[gid]=0; }
  int which = gid >> 12;
  int idx = gid & 4095;
  int r = idx >> 6, c = idx & 63;
  const float* A = which ? Wdst : Wsrc;
  float acc = 0.0f;
  #pragma unroll
  for (int k=0;k<64;k++) acc += A[r*64+k]*Wv[k*64+c];
  (which ? wdvT : wsvT)[c*64+r] = (__bf16)acc;   // store transposed [c][k]
}

// ---------- fused pre: rms + xs0/xd0 + vs/vd MFMA (fp8 out). 4 nodes/block, grid 2000x256 ----------
__global__ void __launch_bounds__(256) k_pre(const float* __restrict__ x,
                        const float* __restrict__ Wsrc, const float* __restrict__ Wdst,
                        const __bf16* __restrict__ wsvT, const __bf16* __restrict__ wdvT,
                        float* __restrict__ xs0, float* __restrict__ xd0,
                        unsigned char* __restrict__ vs, unsigned char* __restrict__ vd){
  __shared__ __bf16 xbuf[64*72];   // 4 nodes x 16 l rows, rms-scaled bf16
  __shared__ float  xl0[4][64];    // fp32 l=0 rows (unscaled)
  __shared__ __bf16 wsb[64*72];    // wsvT [c][k]
  __shared__ __bf16 wdb[64*72];
  __shared__ float  red[16];       // [wave][q]
  int tid = threadIdx.x;
  int w = tid>>6, l = tid&63, lr = l&15, lg = l>>4;
  int n0 = blockIdx.x*4;
  const float4* xp = (const float4*)(x + (size_t)n0*1024);

  float4 v[4]; float ssq[4];
  #pragma unroll
  for (int q=0;q<4;q++){
    v[q] = xp[tid + q*256];
    ssq[q] = v[q].x*v[q].x + v[q].y*v[q].y + v[q].z*v[q].z + v[q].w*v[q].w;
  }
  #pragma unroll
  for (int q=0;q<4;q++){
    #pragma unroll
    for (int m=32;m>=1;m>>=1) ssq[q] += __shfl_xor(ssq[q], m);
  }
  if (l==0){
    #pragma unroll
    for (int q=0;q<4;q++) red[w*4+q] = ssq[q];
  }
  for (int i=tid;i<512;i+=256){
    int row=i>>3, k8=(i&7)*8;
    *(bf16x8*)&wsb[row*72+k8] = *(const bf16x8*)(wsvT + row*64 + k8);
    *(bf16x8*)&wdb[row*72+k8] = *(const bf16x8*)(wdvT + row*64 + k8);
  }
  if (tid < 16){
    #pragma unroll
    for (int q=0;q<4;q++){
      float4 t = v[q];
      float* p = &xl0[q][(tid&15)*4];
      p[0]=t.x; p[1]=t.y; p[2]=t.z; p[3]=t.w;
    }
  }
  __syncthreads();
  float scl[4];
  #pragma unroll
  for (int q=0;q<4;q++)
    scl[q] = 1.0f/sqrtf((red[q]+red[4+q]+red[8+q]+red[12+q])*(1.0f/1024.0f)+1e-6f);
  {
    int r = tid>>4, k4 = (tid&15)*4;
    #pragma unroll
    for (int q=0;q<4;q++){
      float s = scl[q];
      bf16x4 t = {(__bf16)(v[q].x*s),(__bf16)(v[q].y*s),(__bf16)(v[q].z*s),(__bf16)(v[q].w*s)};
      *(bf16x4*)&xbuf[(q*16+r)*72 + k4] = t;
    }
  }
  __syncthreads();

  {
    int nd = w, c = l;
    float s = scl[nd];
    float as=0.f, ad=0.f;
    #pragma unroll 8
    for (int k=0;k<64;k++){
      float xv = xl0[nd][k]*s;
      as += xv*Wsrc[k*64+c];
      ad += xv*Wdst[k*64+c];
    }
    xs0[(size_t)(n0+nd)*64 + c] = as;
    xd0[(size_t)(n0+nd)*64 + c] = ad;
  }

  {
    bf16x8 a0 = *(const bf16x8*)&xbuf[(w*16+lr)*72 + lg*8];
    bf16x8 a1 = *(const bf16x8*)&xbuf[(w*16+lr)*72 + 32 + lg*8];
    #pragma unroll
    for (int nt=0;nt<4;nt++){
      f32x4 os = (f32x4){0.f,0.f,0.f,0.f};
      f32x4 od = (f32x4){0.f,0.f,0.f,0.f};
      bf16x8 bs0 = *(const bf16x8*)&wsb[(nt*16+lr)*72 + lg*8];
      bf16x8 bs1 = *(const bf16x8*)&wsb[(nt*16+lr)*72 + 32 + lg*8];
      bf16x8 bd0 = *(const bf16x8*)&wdb[(nt*16+lr)*72 + lg*8];
      bf16x8 bd1 = *(const bf16x8*)&wdb[(nt*16+lr)*72 + 32 + lg*8];
      os = __builtin_amdgcn_mfma_f32_16x16x32_bf16(a0, bs0, os, 0, 0, 0);
      os = __builtin_amdgcn_mfma_f32_16x16x32_bf16(a1, bs1, os, 0, 0, 0);
      od = __builtin_amdgcn_mfma_f32_16x16x32_bf16(a0, bd0, od, 0, 0, 0);
      od = __builtin_amdgcn_mfma_f32_16x16x32_bf16(a1, bd1, od, 0, 0, 0);
      #pragma unroll
      for (int r=0;r<4;r++){
        size_t row = (size_t)(n0+w)*16 + lg*4 + r;
        vs[row*64 + nt*16 + lr] = ff8(os[r]);
        vd[row*64 + nt*16 + lr] = ff8(od[r]);
      }
    }
  }
}

// ---------- edge RBF + 2-layer MLP via MFMA + hist: 128 edges/block, 512 thr, grid 750 ----------
__global__ void __launch_bounds__(512) k_edgeA(const float* __restrict__ pos, const int* __restrict__ ei,
                        const __bf16* __restrict__ pw,
                        const float* __restrict__ b1, const float* __restrict__ b2,
                        __bf16* __restrict__ e2g, int* __restrict__ deg){
  __shared__ __bf16 W1T[48*264];   // 25344B [j][k] stride 264
  __shared__ __bf16 W2T[64*72];    // 9216B
  __shared__ __bf16 e1s[128*72];   // 18432B
  __shared__ float dl[128], envl[128];
  int tid = threadIdx.x;
  int w = tid>>6, l = tid&63, lr = l&15, lg = l>>4;
  int eb = blockIdx.x*128;

  if (tid < 128){
    int s = ei[eb+tid], t = ei[EE+eb+tid];
    float dx = pos[3*s]-pos[3*t], dy = pos[3*s+1]-pos[3*t+1], dz = pos[3*s+2]-pos[3*t+2];
    float d = sqrtf(dx*dx+dy*dy+dz*dz+1e-12f);
    dl[tid] = d;
    envl[tid] = 0.5f*(cosf(PI_F*fminf(d*(1.0f/CUTOFF_R),1.0f))+1.0f);
    atomicAdd(&deg[t], 1);   // folded k_hist
  }
  for (int i=tid;i<1536;i+=512){
    int row=i>>5, k8=(i&31)*8;
    *(bf16x8*)&W1T[row*264+k8] = *(const bf16x8*)(pw + PW_W1 + row*256 + k8);
  }
  {
    int row=tid>>3, k8=(tid&7)*8;
    *(bf16x8*)&W2T[row*72+k8] = *(const bf16x8*)(pw + PW_W2 + row*64 + k8);
  }
  for (int i=tid;i<2048;i+=512){
    int r=i>>4, c=48+(i&15);
    e1s[r*72+c] = (__bf16)0.f;
  }
  __syncthreads();

  float d  = dl[w*16+lr];
  float ev = envl[w*16+lr];
  f32x4 acc[3];
  #pragma unroll
  for (int nt=0;nt<3;nt++) acc[nt] = (f32x4){0.f,0.f,0.f,0.f};
  #pragma unroll
  for (int c=0;c<8;c++){
    bf16x8 af;
    #pragma unroll
    for (int j=0;j<8;j++){
      float kk = (float)(c*32 + lg*8 + j);
      float del = (d - kk*SPACING)*INV_STD;
      af[j] = (__bf16)(exp2f(-0.72134752f*del*del)*ev);
    }
    #pragma unroll
    for (int nt=0;nt<3;nt++){
      bf16x8 bf_ = *(const bf16x8*)&W1T[(nt*16+lr)*264 + c*32 + lg*8];
      acc[nt] = __builtin_amdgcn_mfma_f32_16x16x32_bf16(af, bf_, acc[nt], 0, 0, 0);
    }
  }
  #pragma unroll
  for (int nt=0;nt<3;nt++){
    int col = nt*16+lr;
    float bb = b1[col];
    #pragma unroll
    for (int r=0;r<4;r++){
      int row = w*16 + lg*4 + r;
      e1s[row*72+col] = (__bf16)silu_f(acc[nt][r] + bb);
    }
  }
  __syncthreads();

  bf16x8 a0 = *(const bf16x8*)&e1s[(w*16+lr)*72 + lg*8];
  bf16x8 a1 = *(const bf16x8*)&e1s[(w*16+lr)*72 + 32 + lg*8];
  #pragma unroll
  for (int nt=0;nt<3;nt++){
    f32x4 o = (f32x4){0.f,0.f,0.f,0.f};
    bf16x8 b0 = *(const bf16x8*)&W2T[(nt*16+lr)*72 + lg*8];
    bf16x8 b1f= *(const bf16x8*)&W2T[(nt*16+lr)*72 + 32 + lg*8];
    o = __builtin_amdgcn_mfma_f32_16x16x32_bf16(a0, b0, o, 0, 0, 0);
    o = __builtin_amdgcn_mfma_f32_16x16x32_bf16(a1, b1f, o, 0, 0, 0);
    int col = nt*16+lr;
    float bb = b2[col];
    #pragma unroll
    for (int r=0;r<4;r++){
      int row = w*16 + lg*4 + r;
      e2g[(size_t)(eb+row)*ECH + col] = (__bf16)silu_f(o[r] + bb);
    }
  }
}

// ---------- CSR scan ----------
__global__ void __launch_bounds__(1024) k_scan(const int* __restrict__ deg, int* __restrict__ off){
  __shared__ int sums[1024];
  int t = threadIdx.x;
  int base = t*8;
  int loc[8]; int s=0;
  #pragma unroll
  for (int i=0;i<8;i++){ int idx=base+i; int v = (idx<NN)? deg[idx]:0; loc[i]=v; s+=v; }
  sums[t]=s;
  __syncthreads();
  for (int d=1; d<1024; d<<=1){
    int v = (t>=d)? sums[t-d]:0;
    __syncthreads();
    sums[t] += v;
    __syncthreads();
  }
  int run = sums[t]-s;
  #pragma unroll
  for (int i=0;i<8;i++){ int idx=base+i; if (idx<NN) off[idx]=run; run+=loc[i]; }
  if (t==1023) off[NN]=sums[1023];
}

// ---------- per-edge MFMA + csr fill: 128 edges/block, 512 thr, grid 750 ----------
__global__ void __launch_bounds__(512) k_edgeB(const __bf16* __restrict__ e2g, const int* __restrict__ ei,
                        const float* __restrict__ xs0, const float* __restrict__ xd0,
                        const __bf16* __restrict__ pw, const float* __restrict__ v_alpha,
                        const int* __restrict__ off, int* __restrict__ cursor, int* __restrict__ csr,
                        float* __restrict__ logits_g, unsigned char* __restrict__ v0g){
  __shared__ __bf16 e2s[128*72];   // 18432B
  __shared__ __bf16 s0s[128*72];   // 18432B
  __shared__ __bf16 wbuf[128*72];  // 18432B: We -> Wa.h0 -> Wa.h1 -> Wv
  __shared__ float  va_l[256];
  __shared__ int    srcd[256];
  int tid = threadIdx.x;
  int w = tid >> 6, l = tid & 63;
  int lr = l & 15, lg = l >> 4;
  int eb = blockIdx.x * 128;

  for (int i=tid;i<8192;i+=512){
    int r=i>>6, k=i&63;
    e2s[r*72+k] = (k<ECH) ? e2g[(size_t)(eb+r)*ECH+k] : (__bf16)0.f;
  }
  {
    int row=tid>>3, k8=(tid&7)*8;
    *(bf16x8*)&wbuf[row*72+k8] = *(const bf16x8*)(pw + PW_We + row*64 + k8);
  }
  if (tid<256) va_l[tid] = v_alpha[tid];
  if (tid<128){
    int sI = ei[eb+tid], dI = ei[EE+eb+tid];
    srcd[tid]=sI; srcd[128+tid]=dI;
    int slot = off[dI] + atomicAdd(&cursor[dI],1);   // folded k_fill
    csr[slot] = eb + tid;
  }
  __syncthreads();

  bf16x8 ea0 = *(const bf16x8*)&e2s[(w*16+lr)*72 + lg*8];
  bf16x8 ea1 = *(const bf16x8*)&e2s[(w*16+lr)*72 + 32 + lg*8];
  f32x4 sacc[4];
  #pragma unroll
  for (int nt=0;nt<4;nt++){
    sacc[nt] = (f32x4){0.f,0.f,0.f,0.f};
    bf16x8 b0 = *(const bf16x8*)&wbuf[(nt*16+lr)*72 + lg*8];
    bf16x8 b1 = *(const bf16x8*)&wbuf[(nt*16+lr)*72 + 32 + lg*8];
    sacc[nt] = __builtin_amdgcn_mfma_f32_16x16x32_bf16(ea0, b0, sacc[nt], 0, 0, 0);
    sacc[nt] = __builtin_amdgcn_mfma_f32_16x16x32_bf16(ea1, b1, sacc[nt], 0, 0, 0);
  }
  #pragma unroll
  for (int reg=0;reg<4;reg++){
    int localrow = w*16 + lg*4 + reg;
    int sI = srcd[localrow], dI = srcd[128+localrow];
    #pragma unroll
    for (int nt=0;nt<4;nt++){
      int col = nt*16 + lr;
      float m = xs0[(size_t)sI*64+col] + xd0[(size_t)dI*64+col];
      s0s[localrow*72+col] = (__bf16)(sacc[nt][reg]*m);
    }
  }
  __syncthreads();

  bf16x8 sa0 = *(const bf16x8*)&s0s[(w*16+lr)*72 + lg*8];
  bf16x8 sa1 = *(const bf16x8*)&s0s[(w*16+lr)*72 + 32 + lg*8];

  #pragma unroll
  for (int half=0;half<2;half++){
    for (int i=tid;i<1024;i+=512){
      int row=i>>3, k8=(i&7)*8;
      *(bf16x8*)&wbuf[row*72+k8] = *(const bf16x8*)(pw + PW_Wa + (half*128+row)*64 + k8);
    }
    __syncthreads();
    float lg0[4]={0.f,0.f,0.f,0.f}, lg1[4]={0.f,0.f,0.f,0.f};
    #pragma unroll
    for (int nt=0;nt<8;nt++){
      f32x4 tacc = (f32x4){0.f,0.f,0.f,0.f};
      bf16x8 b0 = *(const bf16x8*)&wbuf[(nt*16+lr)*72 + lg*8];
      bf16x8 b1 = *(const bf16x8*)&wbuf[(nt*16+lr)*72 + 32 + lg*8];
      tacc = __builtin_amdgcn_mfma_f32_16x16x32_bf16(sa0, b0, tacc, 0, 0, 0);
      tacc = __builtin_amdgcn_mfma_f32_16x16x32_bf16(sa1, b1, tacc, 0, 0, 0);
      int gj = half*128 + nt*16 + lr;
      float vaj = va_l[gj];
      #pragma unroll
      for (int reg=0;reg<4;reg++){
        float t = tacc[reg];
        t = (t>0.0f) ? t : 0.2f*t;
        if (nt<4) lg0[reg] += t*vaj; else lg1[reg] += t*vaj;
      }
    }
    #pragma unroll
    for (int reg=0;reg<4;reg++){
      #pragma unroll
      for (int m=1;m<16;m<<=1){
        lg0[reg] += __shfl_xor(lg0[reg], m);
        lg1[reg] += __shfl_xor(lg1[reg], m);
      }
    }
    if (lr==0){
      #pragma unroll
      for (int reg=0;reg<4;reg++){
        int e = eb + w*16 + lg*4 + reg;
        logits_g[(size_t)e*4 + half*2 + 0] = lg0[reg];
        logits_g[(size_t)e*4 + half*2 + 1] = lg1[reg];
      }
    }
    __syncthreads();
  }

  {
    int row=tid>>3, k8=(tid&7)*8;
    *(bf16x8*)&wbuf[row*72+k8] = *(const bf16x8*)(pw + PW_Wv + row*64 + k8);
  }
  __syncthreads();
  #pragma unroll
  for (int nt=0;nt<4;nt++){
    f32x4 vacc = (f32x4){0.f,0.f,0.f,0.f};
    bf16x8 b0 = *(const bf16x8*)&wbuf[(nt*16+lr)*72 + lg*8];
    bf16x8 b1 = *(const bf16x8*)&wbuf[(nt*16+lr)*72 + 32 + lg*8];
    vacc = __builtin_amdgcn_mfma_f32_16x16x32_bf16(sa0, b0, vacc, 0, 0, 0);
    vacc = __builtin_amdgcn_mfma_f32_16x16x32_bf16(sa1, b1, vacc, 0, 0, 0);
    #pragma unroll
    for (int reg=0;reg<4;reg++){
      int e = eb + w*16 + lg*4 + reg;
      v0g[(size_t)e*64 + nt*16 + lr] = ff8(vacc[reg]);
    }
  }
}

// ---------- gather-only: softmax + fp8 gather -> agg (1 node/block, grid 8000) ----------
__global__ void __launch_bounds__(256) k_gather(const int* __restrict__ off, const int* __restrict__ csr,
                       const int* __restrict__ ei,
                       const float* __restrict__ logits_g, const unsigned char* __restrict__ v0g,
                       const unsigned char* __restrict__ vs, const unsigned char* __restrict__ vd,
                       __bf16* __restrict__ agg){
  __shared__ float alph[MAXDEG*HH];
  __shared__ int   eidl[MAXDEG];
  __shared__ int   srcl[MAXDEG];
  __shared__ float salpha[HH];
  int tid = threadIdx.x;
  int n = blockIdx.x;
  int o0 = off[n];
  int deg = off[n+1]-o0;
  if (deg > MAXDEG) deg = MAXDEG;
  if (tid < deg){
    int e = csr[o0+tid];
    eidl[tid]=e;
    srcl[tid]=ei[e];
    float4 lgv = *(const float4*)(logits_g + (size_t)e*4);
    float* ap = &alph[tid*4];
    ap[0]=lgv.x; ap[1]=lgv.y; ap[2]=lgv.z; ap[3]=lgv.w;
  }
  __syncthreads();
  if (tid < 64){
    int h = tid>>4, i0 = tid&15;
    float m = -1e30f;
    for (int i=i0;i<deg;i+=16) m = fmaxf(m, alph[i*4+h]);
    #pragma unroll
    for (int s=1;s<16;s<<=1) m = fmaxf(m, __shfl_xor(m, s));
    float ds = 0.0f;
    for (int i=i0;i<deg;i+=16){
      float wv = expf(alph[i*4+h]-m);
      alph[i*4+h]=wv; ds += wv;
    }
    #pragma unroll
    for (int s=1;s<16;s<<=1) ds += __shfl_xor(ds, s);
    float inv = 1.0f/(ds+1e-9f);
    for (int i=i0;i<deg;i+=16) alph[i*4+h] *= inv;
    if (i0==0) salpha[h] = ds*inv;
  }
  __syncthreads();
  {
    int l = tid>>4, quad = tid&15;
    int h = quad>>2;
    float a0=0.f,a1=0.f,a2=0.f,a3=0.f;
    if (l==0){
      int i=0;
      for (;i+1<deg;i+=2){
        float aA = alph[i*4+h], aB = alph[(i+1)*4+h];
        unsigned int uA = *(const unsigned int*)(v0g + (size_t)eidl[i]*64 + quad*4);
        unsigned int uB = *(const unsigned int*)(v0g + (size_t)eidl[i+1]*64 + quad*4);
        a0 += aA*f8f(uA&255) + aB*f8f(uB&255);
        a1 += aA*f8f((uA>>8)&255) + aB*f8f((uB>>8)&255);
        a2 += aA*f8f((uA>>16)&255) + aB*f8f((uB>>16)&255);
        a3 += aA*f8f(uA>>24) + aB*f8f(uB>>24);
      }
      if (i<deg){
        float a = alph[i*4+h];
        unsigned int u = *(const unsigned int*)(v0g + (size_t)eidl[i]*64 + quad*4);
        a0 += a*f8f(u&255); a1 += a*f8f((u>>8)&255); a2 += a*f8f((u>>16)&255); a3 += a*f8f(u>>24);
      }
    } else {
      int i=0;
      for (;i+1<deg;i+=2){
        float aA = alph[i*4+h], aB = alph[(i+1)*4+h];
        unsigned int uA = *(const unsigned int*)(vs + (size_t)srcl[i]*1024 + tid*4);
        unsigned int uB = *(const unsigned int*)(vs + (size_t)srcl[i+1]*1024 + tid*4);
        a0 += aA*f8f(uA&255) + aB*f8f(uB&255);
        a1 += aA*f8f((uA>>8)&255) + aB*f8f((uB>>8)&255);
        a2 += aA*f8f((uA>>16)&255) + aB*f8f((uB>>16)&255);
        a3 += aA*f8f(uA>>24) + aB*f8f(uB>>24);
      }
      if (i<deg){
        float a = alph[i*4+h];
        unsigned int u = *(const unsigned int*)(vs + (size_t)srcl[i]*1024 + tid*4);
        a0 += a*f8f(u&255); a1 += a*f8f((u>>8)&255); a2 += a*f8f((u>>16)&255); a3 += a*f8f(u>>24);
      }
      float sa = salpha[h];
      unsigned int u = *(const unsigned int*)(vd + (size_t)n*1024 + tid*4);
      a0 += sa*f8f(u&255); a1 += sa*f8f((u>>8)&255); a2 += sa*f8f((u>>16)&255); a3 += sa*f8f(u>>24);
    }
    bf16x4 t = {(__bf16)a0,(__bf16)a1,(__bf16)a2,(__bf16)a3};
    *(bf16x4*)(agg + (size_t)n*1024 + tid*4) = t;
  }
}

// ---------- Wo + residual + rms + gated FFN + out. 8 nodes/block, 512 thr, grid 1000 ----------
__global__ void __launch_bounds__(512) k_woffn(const __bf16* __restrict__ agg,
                       const float* __restrict__ x, const __bf16* __restrict__ pw,
                       const float* __restrict__ Wg, float* __restrict__ out){
  __shared__ __bf16 wbuf[64*72];         // 9216B: WoT -> WhT.h -> WfT.h (rotating)
  __shared__ __bf16 aggyb[128*72];       // 18432B
  __shared__ __bf16 hbuf[128*72];        // 18432B
  __shared__ float  gl[1024];            // 4096B
  int tid = threadIdx.x;
  int w = tid>>6, lane = tid&63, lr = lane&15, lg = lane>>4;
  int n0 = blockIdx.x*8;

  // ---- T14-style prefetch: issue x loads first ----
  const float* xr = x + (size_t)(n0+w)*1024;
  float xv[16];
  #pragma unroll
  for (int nt=0;nt<4;nt++){
    #pragma unroll
    for (int r=0;r<4;r++){
      xv[nt*4+r] = xr[(lg*4+r)*64 + nt*16 + lr];
    }
  }

  // ---- phase 1: stage WoT + load agg tile (8 nodes) ----
  {
    int row=tid>>3, k8=(tid&7)*8;
    if (tid < 512) *(bf16x8*)&wbuf[row*72+k8] = *(const bf16x8*)(pw + PW_Wo + row*64 + k8);
  }
  for (int i=tid;i<1024;i+=512){
    bf16x8 v = *(const bf16x8*)(agg + (size_t)n0*1024 + i*8);
    *(bf16x8*)&aggyb[(i>>3)*72 + (i&7)*8] = v;
  }
  __syncthreads();

  // ---- phase 2: x1 = x + agg@Wo (regs); rms (wave-local) ----
  f32x4 x1r[4];
  float scl_w;
  {
    bf16x8 a0 = *(const bf16x8*)&aggyb[(w*16+lr)*72 + lg*8];
    bf16x8 a1 = *(const bf16x8*)&aggyb[(w*16+lr)*72 + 32 + lg*8];
    float ss = 0.0f;
    #pragma unroll
    for (int nt=0;nt<4;nt++){
      f32x4 o = (f32x4){0.f,0.f,0.f,0.f};
      bf16x8 b0 = *(const bf16x8*)&wbuf[(nt*16+lr)*72 + lg*8];
      bf16x8 b1 = *(const bf16x8*)&wbuf[(nt*16+lr)*72 + 32 + lg*8];
      o = __builtin_amdgcn_mfma_f32_16x16x32_bf16(a0, b0, o, 0, 0, 0);
      o = __builtin_amdgcn_mfma_f32_16x16x32_bf16(a1, b1, o, 0, 0, 0);
      #pragma unroll
      for (int r=0;r<4;r++){
        float xvv = xv[nt*4+r] + o[r];
        o[r] = xvv;
        ss += xvv*xvv;
      }
      x1r[nt] = o;
    }
    #pragma unroll
    for (int m=32;m>=1;m>>=1) ss += __shfl_xor(ss, m);
    scl_w = 1.0f/sqrtf(ss*(1.0f/1024.0f)+1e-6f);
  }
  __syncthreads();

  // ---- phase 3: ybuf = bf16(x1*scl) into aggyb ----
  #pragma unroll
  for (int nt=0;nt<4;nt++){
    #pragma unroll
    for (int r=0;r<4;r++){
      aggyb[(w*16+lg*4+r)*72 + nt*16+lr] = (__bf16)(x1r[nt][r]*scl_w);
    }
  }
  __syncthreads();

  // ---- phase 3b: gate ----
  {
    int c = tid&127, grp = tid>>7;
    #pragma unroll
    for (int q=0;q<2;q++){
      int nd = grp*2+q;
      float acc = 0.0f;
      #pragma unroll 8
      for (int k=0;k<64;k++) acc += (float)aggyb[(nd*16)*72 + k] * Wg[k*128+c];
      gl[nd*128+c] = silu_f(acc);
    }
  }

  // ---- phases 4-5: FFN in two halves ----
  f32x4 o2[4];
  #pragma unroll
  for (int nt=0;nt<4;nt++) o2[nt] = (f32x4){0.f,0.f,0.f,0.f};
  #pragma unroll
  for (int hf=0; hf<2; hf++){
    __syncthreads();
    {
      int row=tid>>3, k8=(tid&7)*8;
      *(bf16x8*)&wbuf[row*72+k8] = *(const bf16x8*)(pw + PW_Wh + (hf*64+row)*64 + k8);
    }
    __syncthreads();
    {
      bf16x8 a0 = *(const bf16x8*)&aggyb[(w*16+lr)*72 + lg*8];
      bf16x8 a1 = *(const bf16x8*)&aggyb[(w*16+lr)*72 + 32 + lg*8];
      #pragma unroll
      for (int nt=0;nt<4;nt++){
        f32x4 o = (f32x4){0.f,0.f,0.f,0.f};
        bf16x8 b0 = *(const bf16x8*)&wbuf[(nt*16+lr)*72 + lg*8];
        bf16x8 b1 = *(const bf16x8*)&wbuf[(nt*16+lr)*72 + 32 + lg*8];
        o = __builtin_amdgcn_mfma_f32_16x16x32_bf16(a0, b0, o, 0, 0, 0);
        o = __builtin_amdgcn_mfma_f32_16x16x32_bf16(a1, b1, o, 0, 0, 0);
        int col = nt*16+lr;
        float g = gl[w*128 + hf*64 + col];
        #pragma unroll
        for (int r=0;r<4;r++){
          hbuf[(w*16+lg*4+r)*72 + col] = (__bf16)(o[r]*g);
        }
      }
    }
    __syncthreads();
    {
      int row=tid>>3, k8=(tid&7)*8;
      *(bf16x8*)&wbuf[row*72+k8] = *(const bf16x8*)(pw + PW_Wf + row*128 + hf*64 + k8);
    }
    __syncthreads();
    {
      bf16x8 a0 = *(const bf16x8*)&hbuf[(w*16+lr)*72 + lg*8];
      bf16x8 a1 = *(const bf16x8*)&hbuf[(w*16+lr)*72 + 32 + lg*8];
      #pragma unroll
      for (int nt=0;nt<4;nt++){
        bf16x8 b0 = *(const bf16x8*)&wbuf[(nt*16+lr)*72 + lg*8];
        bf16x8 b1 = *(const bf16x8*)&wbuf[(nt*16+lr)*72 + 32 + lg*8];
        o2[nt] = __builtin_amdgcn_mfma_f32_16x16x32_bf16(a0, b0, o2[nt], 0, 0, 0);
        o2[nt] = __builtin_amdgcn_mfma_f32_16x16x32_bf16(a1, b1, o2[nt], 0, 0, 0);
      }
    }
  }

  // ---- final store: out = x1 + o2 ----
  {
    float* outr = out + (size_t)(n0+w)*1024;
    #pragma unroll
    for (int nt=0;nt<4;nt++){
      #pragma unroll
      for (int r=0;r<4;r++){
        outr[(lg*4+r)*64 + nt*16+lr] = x1r[nt][r] + o2[nt][r];
      }
    }
  }
}

extern "C" void kernel_launch(void* const* d_in, const int* in_sizes, int n_in,
                              void* d_out, int out_size, void* d_ws, size_t ws_size,
                              hipStream_t stream) {
  (void)in_sizes; (void)n_in; (void)out_size; (void)ws_size;
  const float* pos = (const float*)d_in[0];
  const float* x   = (const float*)d_in[1];
  const float* Wsrc= (const float*)d_in[2];
  const float* Wdst= (const float*)d_in[3];
  const float* W1  = (const float*)d_in[4];
  const float* b1  = (const float*)d_in[5];
  const float* W2  = (const float*)d_in[6];
  const float* b2  = (const float*)d_in[7];
  const float* We  = (const float*)d_in[8];
  const float* Wa  = (const float*)d_in[9];
  const float* va  = (const float*)d_in[10];
  const float* Wv  = (const float*)d_in[11];
  const float* Wo  = (const float*)d_in[12];
  const float* Wg  = (const float*)d_in[13];
  const float* Wh  = (const float*)d_in[14];
  const float* Wf  = (const float*)d_in[15];
  const int*   ei  = (const int*)d_in[16];
  float* out = (float*)d_out;

  char* wp = (char*)d_ws;
  auto alloc = [&](size_t bytes)->char*{
    char* p = wp;
    wp += ((bytes + 255)/256)*256;
    return p;
  };
  __bf16* pwb  = (__bf16*)alloc((size_t)PW_TOTAL*2);
  __bf16* wsvT = (__bf16*)alloc(4096*2);
  __bf16* wdvT = (__bf16*)alloc(4096*2);
  float* xs0  = (float*)alloc((size_t)NN*64*4);
  float* xd0  = (float*)alloc((size_t)NN*64*4);
  unsigned char* vs  = (unsigned char*)alloc((size_t)NN*1024);
  unsigned char* vd  = (unsigned char*)alloc((size_t)NN*1024);
  __bf16* agg = (__bf16*)alloc((size_t)NN*1024*2);
  __bf16* e2g = (__bf16*)alloc((size_t)EE*ECH*2);
  unsigned char* v0g = (unsigned char*)alloc((size_t)EE*64);
  float* lgts = (float*)alloc((size_t)EE*HH*4);
  int* deg    = (int*)alloc((size_t)NN*4);
  int* cursor = (int*)alloc((size_t)NN*4);
  int* off    = (int*)alloc((size_t)(NN+1)*4);
  int* csr    = (int*)alloc((size_t)EE*4);

  k_prep<<<PW_TOTAL/256,256,0,stream>>>(We,Wv,Wo,W2,Wh,Wf,W1,Wa,pwb);
  k_fusew<<<32,256,0,stream>>>(Wsrc,Wdst,Wv,wsvT,wdvT,deg,cursor);
  k_pre<<<NN/4,256,0,stream>>>(x,Wsrc,Wdst,wsvT,wdvT,xs0,xd0,vs,vd);
  k_edgeA<<<EE/128,512,0,stream>>>(pos,ei,pwb,b1,b2,e2g,deg);
  k_scan<<<1,1024,0,stream>>>(deg,off);
  k_edgeB<<<EE/128,512,0,stream>>>(e2g,ei,xs0,xd0,pwb,va,off,cursor,csr,lgts,v0g);
  k_gather<<<NN,256,0,stream>>>(off,csr,ei,lgts,v0g,vs,vd,agg);
  k_woffn<<<NN/8,512,0,stream>>>(agg,x,pwb,Wg,out);
}